// Round 1
// baseline (4034.884 us; speedup 1.0000x reference)
//
#include <hip/hip_runtime.h>
#include <hip/hip_bf16.h>
#include <cstdint>
#include <cstddef>

#define HWPIX 65536
#define IMGW 256
#define CDIM 192
#define C3 576
#define NBATCH 4
#define NHEADS 8
#define CPH 24

using bf16 = __hip_bfloat16;

__device__ __forceinline__ float b2f(bf16 v) { return __bfloat162float(v); }
__device__ __forceinline__ bf16 f2b(float v) { return __float2bfloat16(v); }

__device__ __forceinline__ void storef(float* p, float v) { *p = v; }
__device__ __forceinline__ void storef(bf16* p, float v) { *p = f2b(v); }

// ---------------------------------------------------------------------------
// 1x1 conv as tiled GEMM: Y[b,co,p] = sum_ci W[co,ci]*X[b,ci,p] + bias[co]
// 64 co x 64 p tile, K=192 fully staged in LDS, 4x4 register micro-tile.
// ---------------------------------------------------------------------------
template <typename OutT>
__global__ __launch_bounds__(256) void conv1x1_kernel(
    const float* __restrict__ X, const float* __restrict__ W,
    const float* __restrict__ bias, OutT* __restrict__ Y, int Cout)
{
    __shared__ float sW[CDIM][68];
    __shared__ float sX[CDIM][68];
    const int b   = blockIdx.z;
    const int co0 = blockIdx.y * 64;
    const int p0  = blockIdx.x * 64;
    const int tid = threadIdx.x;

    for (int idx = tid; idx < CDIM * 64; idx += 256) {
        int k = idx % CDIM, i = idx / CDIM;
        sW[k][i] = W[(size_t)(co0 + i) * CDIM + k];
    }
    for (int idx = tid; idx < CDIM * 64; idx += 256) {
        int j = idx & 63, k = idx >> 6;
        sX[k][j] = X[((size_t)b * CDIM + k) * HWPIX + p0 + j];
    }
    __syncthreads();

    const int tx = tid & 15, ty = tid >> 4;
    float acc[4][4] = {};
#pragma unroll 4
    for (int k = 0; k < CDIM; ++k) {
        float4 av4 = *reinterpret_cast<const float4*>(&sW[k][ty * 4]);
        float4 bv4 = *reinterpret_cast<const float4*>(&sX[k][tx * 4]);
        float av[4] = {av4.x, av4.y, av4.z, av4.w};
        float bv[4] = {bv4.x, bv4.y, bv4.z, bv4.w};
#pragma unroll
        for (int i = 0; i < 4; ++i)
#pragma unroll
            for (int j = 0; j < 4; ++j) acc[i][j] = fmaf(av[i], bv[j], acc[i][j]);
    }

#pragma unroll
    for (int i = 0; i < 4; ++i) {
        const int co = co0 + ty * 4 + i;
        const float bs = bias[co];
        const size_t base = ((size_t)b * Cout + co) * HWPIX + p0 + tx * 4;
#pragma unroll
        for (int j = 0; j < 4; ++j) storef(&Y[base + j], acc[i][j] + bs);
    }
}

// ---------------------------------------------------------------------------
// Depthwise 3x3 SAME conv, bf16 in -> bf16 out
// ---------------------------------------------------------------------------
__global__ __launch_bounds__(256) void dwconv_kernel(
    const bf16* __restrict__ In, const float* __restrict__ Wd,
    const float* __restrict__ bd, bf16* __restrict__ Out)
{
    const int bc = blockIdx.y;            // b*576 + c
    const int c = bc % C3;
    const size_t base = (size_t)bc * HWPIX;
    const int p = blockIdx.x * 256 + threadIdx.x;
    const int h = p >> 8, w = p & 255;

    float wg[9];
#pragma unroll
    for (int t = 0; t < 9; ++t) wg[t] = Wd[c * 9 + t];

    float acc = bd[c];
#pragma unroll
    for (int dy = 0; dy < 3; ++dy) {
        const int hh = h + dy - 1;
        if ((unsigned)hh >= IMGW) continue;
#pragma unroll
        for (int dx = 0; dx < 3; ++dx) {
            const int ww = w + dx - 1;
            if ((unsigned)ww >= IMGW) continue;
            acc = fmaf(b2f(In[base + hh * IMGW + ww]), wg[dy * 3 + dx], acc);
        }
    }
    Out[base + p] = f2b(acc);
}

// ---------------------------------------------------------------------------
// Local (windowed 8x8) channel attention. One block (64 thr) per (window,head).
// Writes o1 into Osum (f32) — every element written exactly once.
// ---------------------------------------------------------------------------
__global__ __launch_bounds__(64) void local_attn_kernel(
    const bf16* __restrict__ QKV, const float* __restrict__ temp,
    float* __restrict__ Osum)
{
    __shared__ float sq[CPH][65];
    __shared__ float sk[CPH][65];
    __shared__ float sv[CPH][64];
    __shared__ float sA[CPH][CPH];
    __shared__ float sinq[CPH], sink[CPH];

    const int wi = blockIdx.x;           // 0..1023
    const int head = blockIdx.y;
    const int b = blockIdx.z;
    const int wy = wi >> 5, wx = wi & 31;
    const int d = threadIdx.x;           // 0..63
    const int pr = (wy * 8 + (d >> 3)) * IMGW + wx * 8 + (d & 7);
    const size_t qb = ((size_t)b * C3 + head * CPH) * HWPIX;

    for (int c = 0; c < CPH; ++c) {
        sq[c][d] = b2f(QKV[qb + (size_t)c * HWPIX + pr]);
        sk[c][d] = b2f(QKV[qb + (size_t)(CDIM + c) * HWPIX + pr]);
        sv[c][d] = b2f(QKV[qb + (size_t)(2 * CDIM + c) * HWPIX + pr]);
    }
    __syncthreads();

    if (d < CPH) {
        float s = 0.f;
        for (int j = 0; j < 64; ++j) s = fmaf(sq[d][j], sq[d][j], s);
        sinq[d] = 1.f / fmaxf(sqrtf(s), 1e-12f);
    } else if (d >= 32 && d < 32 + CPH) {
        const int c = d - 32;
        float s = 0.f;
        for (int j = 0; j < 64; ++j) s = fmaf(sk[c][j], sk[c][j], s);
        sink[c] = 1.f / fmaxf(sqrtf(s), 1e-12f);
    }
    __syncthreads();

    const float t = temp[head];
    for (int idx = d; idx < CPH * CPH; idx += 64) {
        const int c = idx / CPH, e = idx % CPH;
        float s = 0.f;
        for (int j = 0; j < 64; ++j) s = fmaf(sq[c][j], sk[e][j], s);
        sA[c][e] = s * sinq[c] * sink[e] * t;
    }
    __syncthreads();

    if (d < CPH) {
        float m = -1e30f;
        for (int e = 0; e < CPH; ++e) m = fmaxf(m, sA[d][e]);
        float ex[CPH]; float s = 0.f;
        for (int e = 0; e < CPH; ++e) { ex[e] = expf(sA[d][e] - m); s += ex[e]; }
        const float inv = 1.f / s;
        for (int e = 0; e < CPH; ++e) sA[d][e] = ex[e] * inv;
    }
    __syncthreads();

    const size_t ob = ((size_t)b * CDIM + head * CPH) * HWPIX;
    for (int c = 0; c < CPH; ++c) {
        float acc = 0.f;
        for (int e = 0; e < CPH; ++e) acc = fmaf(sA[c][e], sv[e][d], acc);
        Osum[ob + (size_t)c * HWPIX + pr] = acc;
    }
}

// ---------------------------------------------------------------------------
// Global branch stats: per (b,head): partial Gram G[24][24], |q|^2, |k|^2
// over a 2048-d chunk. Deterministic: each (bh,chunk) writes its own slot.
// Gp layout: [bh][chunk][624]  (576 = G, 24 = nq2, 24 = nk2)
// ---------------------------------------------------------------------------
__global__ __launch_bounds__(256) void gstats_kernel(
    const bf16* __restrict__ QKV, float* __restrict__ Gp)
{
    __shared__ float sq[CPH][260];
    __shared__ float sk[CPH][260];
    const int chunk = blockIdx.x;        // 0..31  (2048 d each)
    const int bh = blockIdx.y;           // 0..31
    const int b = bh >> 3, head = bh & 7;
    const int tid = threadIdx.x;
    const size_t qb = ((size_t)b * C3 + head * CPH) * HWPIX;
    const size_t kb = qb + (size_t)CDIM * HWPIX;

    float a00 = 0.f, a01 = 0.f, a10 = 0.f, a11 = 0.f;

    for (int sub = 0; sub < 8; ++sub) {
        const int d0 = chunk * 2048 + sub * 256;
        for (int idx = tid; idx < CPH * 256; idx += 256) {
            const int dd = idx & 255, c = idx >> 8;
            sq[c][dd] = b2f(QKV[qb + (size_t)c * HWPIX + d0 + dd]);
            sk[c][dd] = b2f(QKV[kb + (size_t)c * HWPIX + d0 + dd]);
        }
        __syncthreads();

        if (tid < 144) {                 // 2x2 Gram tile
            const int c0 = (tid / 12) * 2, e0 = (tid % 12) * 2;
            const float* q0 = sq[c0]; const float* q1 = sq[c0 + 1];
            const float* k0 = sk[e0]; const float* k1 = sk[e0 + 1];
#pragma unroll 4
            for (int dd = 0; dd < 256; ++dd) {
                const float x0 = q0[dd], x1 = q1[dd];
                const float y0 = k0[dd], y1 = k1[dd];
                a00 = fmaf(x0, y0, a00); a01 = fmaf(x0, y1, a01);
                a10 = fmaf(x1, y0, a10); a11 = fmaf(x1, y1, a11);
            }
        } else if (tid < 168) {          // q norms
            const float* r = sq[tid - 144];
#pragma unroll 4
            for (int dd = 0; dd < 256; ++dd) a00 = fmaf(r[dd], r[dd], a00);
        } else if (tid < 192) {          // k norms
            const float* r = sk[tid - 168];
#pragma unroll 4
            for (int dd = 0; dd < 256; ++dd) a00 = fmaf(r[dd], r[dd], a00);
        }
        __syncthreads();
    }

    float* dst = Gp + ((size_t)bh * 32 + chunk) * 624;
    if (tid < 144) {
        const int c0 = (tid / 12) * 2, e0 = (tid % 12) * 2;
        dst[(c0    ) * CPH + e0    ] = a00;
        dst[(c0    ) * CPH + e0 + 1] = a01;
        dst[(c0 + 1) * CPH + e0    ] = a10;
        dst[(c0 + 1) * CPH + e0 + 1] = a11;
    } else if (tid < 168) {
        dst[576 + (tid - 144)] = a00;
    } else if (tid < 192) {
        dst[600 + (tid - 168)] = a00;
    }
}

// ---------------------------------------------------------------------------
// Reduce chunk partials, build softmax attention matrices A[bh][24][24]
// ---------------------------------------------------------------------------
__global__ __launch_bounds__(64) void gsoftmax_kernel(
    const float* __restrict__ Gp, const float* __restrict__ temp,
    float* __restrict__ A)
{
    __shared__ float red[624];
    const int bh = blockIdx.x, head = bh & 7;
    const int tid = threadIdx.x;

    for (int jj = tid; jj < 624; jj += 64) {
        float s = 0.f;
        for (int ch = 0; ch < 32; ++ch) s += Gp[((size_t)bh * 32 + ch) * 624 + jj];
        red[jj] = s;
    }
    __syncthreads();

    if (tid < CPH) {
        const int c = tid;
        const float t = temp[head];
        const float inq = 1.f / fmaxf(sqrtf(red[576 + c]), 1e-12f);
        float l[CPH]; float m = -1e30f;
        for (int e = 0; e < CPH; ++e) {
            const float ink = 1.f / fmaxf(sqrtf(red[600 + e]), 1e-12f);
            l[e] = red[c * CPH + e] * inq * ink * t;
            m = fmaxf(m, l[e]);
        }
        float s = 0.f;
        for (int e = 0; e < CPH; ++e) { l[e] = expf(l[e] - m); s += l[e]; }
        const float inv = 1.f / s;
        for (int e = 0; e < CPH; ++e) A[(size_t)bh * 576 + c * CPH + e] = l[e] * inv;
    }
}

// ---------------------------------------------------------------------------
// Global apply: Osum[b,head*24+c,d] += sum_e A[c,e] * v[e,d]
// ---------------------------------------------------------------------------
__global__ __launch_bounds__(256) void gapply_kernel(
    const bf16* __restrict__ QKV, const float* __restrict__ A,
    float* __restrict__ Osum)
{
    __shared__ float sA[576];
    const int bh = blockIdx.y;
    const int b = bh >> 3, head = bh & 7;
    const int d = blockIdx.x * 256 + threadIdx.x;

    for (int idx = threadIdx.x; idx < 576; idx += 256) sA[idx] = A[(size_t)bh * 576 + idx];
    __syncthreads();

    const size_t vb = ((size_t)b * C3 + 2 * CDIM + head * CPH) * HWPIX;
    const size_t ob = ((size_t)b * CDIM + head * CPH) * HWPIX;

    float v[CPH];
#pragma unroll
    for (int e = 0; e < CPH; ++e) v[e] = b2f(QKV[vb + (size_t)e * HWPIX + d]);

#pragma unroll 4
    for (int c = 0; c < CPH; ++c) {
        float acc = Osum[ob + (size_t)c * HWPIX + d];
        const float* Ar = &sA[c * CPH];
#pragma unroll
        for (int e = 0; e < CPH; ++e) acc = fmaf(Ar[e], v[e], acc);
        Osum[ob + (size_t)c * HWPIX + d] = acc;
    }
}

// ---------------------------------------------------------------------------
extern "C" void kernel_launch(void* const* d_in, const int* in_sizes, int n_in,
                              void* d_out, int out_size, void* d_ws, size_t ws_size,
                              hipStream_t stream) {
    const float* x           = (const float*)d_in[0];
    const float* temperature = (const float*)d_in[1];
    const float* qkv_w       = (const float*)d_in[2];
    const float* qkv_b       = (const float*)d_in[3];
    const float* dw_w        = (const float*)d_in[4];
    const float* dw_b        = (const float*)d_in[5];
    const float* proj_w      = (const float*)d_in[6];
    const float* proj_b      = (const float*)d_in[7];
    float* out = (float*)d_out;

    char* ws = (char*)d_ws;
    constexpr size_t QKV_ELEMS = (size_t)NBATCH * C3 * HWPIX;   // 150,994,944
    constexpr size_t QKV_BYTES = QKV_ELEMS * sizeof(bf16);      // 301,989,888

    bf16* qkv1 = (bf16*)ws;                       // conv1x1 out (bf16)
    bf16* qkv2 = (bf16*)(ws + QKV_BYTES);         // q,k,v after depthwise (bf16)
    float* osum = (float*)ws;                     // overlays qkv1 (dead after dw)
    float* Gp   = (float*)(ws + 2 * QKV_BYTES);   // 32*32*624 f32 partials
    float* Amat = Gp + (size_t)32 * 32 * 624;     // 32*576 f32

    // 1. qkv = 1x1 conv (f32 -> bf16)
    conv1x1_kernel<bf16><<<dim3(HWPIX / 64, C3 / 64, NBATCH), 256, 0, stream>>>(
        x, qkv_w, qkv_b, qkv1, C3);

    // 2. depthwise 3x3
    dwconv_kernel<<<dim3(HWPIX / 256, NBATCH * C3), 256, 0, stream>>>(
        qkv1, dw_w, dw_b, qkv2);

    // 3. local windowed attention -> writes all of osum (o1)
    local_attn_kernel<<<dim3(1024, NHEADS, NBATCH), 64, 0, stream>>>(
        qkv2, temperature, osum);

    // 4. global Gram/norm partials
    gstats_kernel<<<dim3(32, 32), 256, 0, stream>>>(qkv2, Gp);

    // 5. reduce + softmax -> A
    gsoftmax_kernel<<<32, 64, 0, stream>>>(Gp, temperature, Amat);

    // 6. apply global attention, add into osum
    gapply_kernel<<<dim3(HWPIX / 256, 32), 256, 0, stream>>>(qkv2, Amat, osum);

    // 7. proj 1x1 conv (f32 -> f32 out)
    conv1x1_kernel<float><<<dim3(HWPIX / 64, CDIM / 64, NBATCH), 256, 0, stream>>>(
        osum, proj_w, proj_b, out, CDIM);
}

// Round 2
// 2600.387 us; speedup vs baseline: 1.5516x; 1.5516x over previous
//
#include <hip/hip_runtime.h>
#include <hip/hip_bf16.h>
#include <cstdint>
#include <cstddef>

#define HWPIX 65536
#define IMGW 256
#define CDIM 192
#define C3 576
#define NBATCH 4
#define NHEADS 8
#define CPH 24
#define KP 104   // padded K pitch (bf16 elems) for MFMA LDS tiles

using bf16 = __hip_bfloat16;
typedef __attribute__((ext_vector_type(8))) short short8;
typedef __attribute__((ext_vector_type(4))) float f32x4;
typedef unsigned int u32;
typedef unsigned short u16;

__device__ __forceinline__ float b2f(bf16 v) { return __bfloat162float(v); }
__device__ __forceinline__ bf16 f2b(float v) { return __float2bfloat16(v); }
__device__ __forceinline__ u16 f2bu(float x) {
    bf16 h = __float2bfloat16(x);
    return *reinterpret_cast<u16*>(&h);
}
__device__ __forceinline__ u32 pack2(float a, float b) {
    return (u32)f2bu(a) | ((u32)f2bu(b) << 16);
}

// ---------------------------------------------------------------------------
// Convert qkv weights f32 -> bf16 (u16) once per launch.
// ---------------------------------------------------------------------------
__global__ __launch_bounds__(256) void prep_weights(
    const float* __restrict__ W, u16* __restrict__ Wb, int n)
{
    int i = blockIdx.x * 256 + threadIdx.x;
    if (i < n) Wb[i] = f2bu(W[i]);
}

// ---------------------------------------------------------------------------
// qkv 1x1 conv as bf16 MFMA GEMM.  Y[b,co,p] = sum_k W[co,k] X[b,k,p] + bias
// Tile: 64 co x 128 p, K=192 in 2 chunks of 96. 4 waves, each wave 64x32.
// LDS: sA[64][KP] + sB[128][KP] bf16 = 39936 B.
// ---------------------------------------------------------------------------
__global__ __launch_bounds__(256) void conv_qkv_mfma(
    const float* __restrict__ X, const u16* __restrict__ Wb,
    const float* __restrict__ bias, bf16* __restrict__ Y)
{
    __shared__ u16 sA[64 * KP];
    __shared__ u16 sB[128 * KP];

    // XCD-chunked remap (nwg = 18432, co fastest -> 9 co-tiles share X slab in L2)
    int lin = blockIdx.x;
    lin = (lin & 7) * (18432 / 8) + (lin >> 3);
    const int co_t = lin % 9;
    const int rest = lin / 9;
    const int p_t = rest & 511;
    const int b   = rest >> 9;
    const int co0 = co_t * 64;
    const int p0  = p_t * 128;

    const int tid  = threadIdx.x;
    const int wave = tid >> 6;
    const int lane = tid & 63;
    const int r  = lane & 15;   // fragment row/col within 16
    const int hk = lane >> 4;   // k-group 0..3

    f32x4 acc[4][2];
#pragma unroll
    for (int i = 0; i < 4; ++i)
#pragma unroll
        for (int j = 0; j < 2; ++j) acc[i][j] = (f32x4){0.f, 0.f, 0.f, 0.f};

#pragma unroll
    for (int c = 0; c < 2; ++c) {
        // ---- stage A: 64 rows x 96 k of bf16 weights (12 x 16B chunks/row)
        {
            int idx = tid;
#pragma unroll
            for (int i = 0; i < 3; ++i, idx += 256) {
                const int row = idx / 12, cv = idx % 12;
                const uint4 v = *reinterpret_cast<const uint4*>(
                    Wb + (size_t)(co0 + row) * CDIM + c * 96 + cv * 8);
                *reinterpret_cast<uint4*>(&sA[row * KP + cv * 8]) = v;
            }
        }
        // ---- stage B: 128 p x 96 k, f32 -> bf16 transpose
        {
            const int pl   = wave * 32 + (lane & 31);
            const int koff = lane >> 5;
            const float* Xp = X + ((size_t)b * CDIM + c * 96) * HWPIX + p0 + pl;
#pragma unroll
            for (int i = 0; i < 24; ++i) {
                const int k = i * 4 + koff * 2;
                const float v0 = Xp[(size_t)k * HWPIX];
                const float v1 = Xp[(size_t)(k + 1) * HWPIX];
                *reinterpret_cast<u32*>(&sB[pl * KP + k]) = pack2(v0, v1);
            }
        }
        __syncthreads();

#pragma unroll
        for (int ks = 0; ks < 3; ++ks) {
            const int kof = ks * 32 + hk * 8;
            const u16* pA = &sA[r * KP + kof];
            const u16* pB = &sB[(wave * 32 + r) * KP + kof];
            const short8 a0 = *reinterpret_cast<const short8*>(pA);
            const short8 a1 = *reinterpret_cast<const short8*>(pA + 16 * KP);
            const short8 a2 = *reinterpret_cast<const short8*>(pA + 32 * KP);
            const short8 a3 = *reinterpret_cast<const short8*>(pA + 48 * KP);
            const short8 b0 = *reinterpret_cast<const short8*>(pB);
            const short8 b1 = *reinterpret_cast<const short8*>(pB + 16 * KP);
            acc[0][0] = __builtin_amdgcn_mfma_f32_16x16x32_bf16(a0, b0, acc[0][0], 0, 0, 0);
            acc[1][0] = __builtin_amdgcn_mfma_f32_16x16x32_bf16(a1, b0, acc[1][0], 0, 0, 0);
            acc[2][0] = __builtin_amdgcn_mfma_f32_16x16x32_bf16(a2, b0, acc[2][0], 0, 0, 0);
            acc[3][0] = __builtin_amdgcn_mfma_f32_16x16x32_bf16(a3, b0, acc[3][0], 0, 0, 0);
            acc[0][1] = __builtin_amdgcn_mfma_f32_16x16x32_bf16(a0, b1, acc[0][1], 0, 0, 0);
            acc[1][1] = __builtin_amdgcn_mfma_f32_16x16x32_bf16(a1, b1, acc[1][1], 0, 0, 0);
            acc[2][1] = __builtin_amdgcn_mfma_f32_16x16x32_bf16(a2, b1, acc[2][1], 0, 0, 0);
            acc[3][1] = __builtin_amdgcn_mfma_f32_16x16x32_bf16(a3, b1, acc[3][1], 0, 0, 0);
        }
        __syncthreads();
    }

    // ---- epilogue: C/D layout col = lane&15, row = (lane>>4)*4 + j
#pragma unroll
    for (int mf = 0; mf < 4; ++mf) {
#pragma unroll
        for (int j = 0; j < 4; ++j) {
            const int co = co0 + mf * 16 + hk * 4 + j;
            const float bs = bias[co];
            const size_t base = ((size_t)b * C3 + co) * HWPIX + p0 + wave * 32 + r;
            Y[base]      = f2b(acc[mf][0][j] + bs);
            Y[base + 16] = f2b(acc[mf][1][j] + bs);
        }
    }
}

// ---------------------------------------------------------------------------
// proj 1x1 conv, f32 vector GEMM (kept f32: its rounding hits the output
// directly).  Tile 64co x 128p, BK=64 (3 chunks), 51 KB LDS -> 3 blocks/CU.
// ---------------------------------------------------------------------------
__global__ __launch_bounds__(256) void conv_proj_f32(
    const float* __restrict__ X, const float* __restrict__ W,
    const float* __restrict__ bias, float* __restrict__ Y)
{
    __shared__ float sW[64][68];    // [k][co]  (transposed)
    __shared__ float sX[64][132];   // [k][p]

    int lin = blockIdx.x;                       // nwg = 6144
    lin = (lin & 7) * (6144 / 8) + (lin >> 3);
    const int co_t = lin % 3;
    const int rest = lin / 3;
    const int p_t = rest & 511;
    const int b   = rest >> 9;
    const int co0 = co_t * 64;
    const int p0  = p_t * 128;

    const int tid = threadIdx.x;
    const int tx = tid & 15, ty = tid >> 4;

    float acc[4][8] = {};

    for (int c = 0; c < 3; ++c) {
        // stage W^T chunk: 64 co x 64 k
        {
            int idx = tid;
#pragma unroll
            for (int i = 0; i < 4; ++i, idx += 256) {
                const int co_l = idx >> 4, kq = idx & 15;
                const float4 v = *reinterpret_cast<const float4*>(
                    &W[(size_t)(co0 + co_l) * CDIM + c * 64 + kq * 4]);
                sW[kq * 4 + 0][co_l] = v.x;
                sW[kq * 4 + 1][co_l] = v.y;
                sW[kq * 4 + 2][co_l] = v.z;
                sW[kq * 4 + 3][co_l] = v.w;
            }
        }
        // stage X chunk: 64 k x 128 p
        {
            int idx = tid;
#pragma unroll
            for (int i = 0; i < 8; ++i, idx += 256) {
                const int row = idx >> 5, cq = idx & 31;
                const float4 v = *reinterpret_cast<const float4*>(
                    &X[((size_t)b * CDIM + c * 64 + row) * HWPIX + p0 + cq * 4]);
                *reinterpret_cast<float4*>(&sX[row][cq * 4]) = v;
            }
        }
        __syncthreads();

#pragma unroll 4
        for (int k = 0; k < 64; ++k) {
            const float4 w4 = *reinterpret_cast<const float4*>(&sW[k][ty * 4]);
            const float4 xa = *reinterpret_cast<const float4*>(&sX[k][tx * 4]);
            const float4 xb = *reinterpret_cast<const float4*>(&sX[k][64 + tx * 4]);
            const float wv[4] = {w4.x, w4.y, w4.z, w4.w};
            const float xv[8] = {xa.x, xa.y, xa.z, xa.w, xb.x, xb.y, xb.z, xb.w};
#pragma unroll
            for (int i = 0; i < 4; ++i)
#pragma unroll
                for (int j = 0; j < 8; ++j) acc[i][j] = fmaf(wv[i], xv[j], acc[i][j]);
        }
        __syncthreads();
    }

#pragma unroll
    for (int i = 0; i < 4; ++i) {
        const int co = co0 + ty * 4 + i;
        const float bs = bias[co];
        const size_t base = ((size_t)b * CDIM + co) * HWPIX + p0;
        float4 o0 = {acc[i][0] + bs, acc[i][1] + bs, acc[i][2] + bs, acc[i][3] + bs};
        float4 o1 = {acc[i][4] + bs, acc[i][5] + bs, acc[i][6] + bs, acc[i][7] + bs};
        *reinterpret_cast<float4*>(&Y[base + tx * 4]) = o0;
        *reinterpret_cast<float4*>(&Y[base + 64 + tx * 4]) = o1;
    }
}

// ---------------------------------------------------------------------------
// Depthwise 3x3 SAME conv, bf16 in -> bf16 out
// ---------------------------------------------------------------------------
__global__ __launch_bounds__(256) void dwconv_kernel(
    const bf16* __restrict__ In, const float* __restrict__ Wd,
    const float* __restrict__ bd, bf16* __restrict__ Out)
{
    const int bc = blockIdx.y;            // b*576 + c
    const int c = bc % C3;
    const size_t base = (size_t)bc * HWPIX;
    const int p = blockIdx.x * 256 + threadIdx.x;
    const int h = p >> 8, w = p & 255;

    float wg[9];
#pragma unroll
    for (int t = 0; t < 9; ++t) wg[t] = Wd[c * 9 + t];

    float acc = bd[c];
#pragma unroll
    for (int dy = 0; dy < 3; ++dy) {
        const int hh = h + dy - 1;
        if ((unsigned)hh >= IMGW) continue;
#pragma unroll
        for (int dx = 0; dx < 3; ++dx) {
            const int ww = w + dx - 1;
            if ((unsigned)ww >= IMGW) continue;
            acc = fmaf(b2f(In[base + hh * IMGW + ww]), wg[dy * 3 + dx], acc);
        }
    }
    Out[base + p] = f2b(acc);
}

// ---------------------------------------------------------------------------
// Local (windowed 8x8) channel attention. One block (64 thr) per (window,head).
// ---------------------------------------------------------------------------
__global__ __launch_bounds__(64) void local_attn_kernel(
    const bf16* __restrict__ QKV, const float* __restrict__ temp,
    float* __restrict__ Osum)
{
    __shared__ float sq[CPH][65];
    __shared__ float sk[CPH][65];
    __shared__ float sv[CPH][64];
    __shared__ float sA[CPH][CPH];
    __shared__ float sinq[CPH], sink[CPH];

    const int wi = blockIdx.x;
    const int head = blockIdx.y;
    const int b = blockIdx.z;
    const int wy = wi >> 5, wx = wi & 31;
    const int d = threadIdx.x;
    const int pr = (wy * 8 + (d >> 3)) * IMGW + wx * 8 + (d & 7);
    const size_t qb = ((size_t)b * C3 + head * CPH) * HWPIX;

    for (int c = 0; c < CPH; ++c) {
        sq[c][d] = b2f(QKV[qb + (size_t)c * HWPIX + pr]);
        sk[c][d] = b2f(QKV[qb + (size_t)(CDIM + c) * HWPIX + pr]);
        sv[c][d] = b2f(QKV[qb + (size_t)(2 * CDIM + c) * HWPIX + pr]);
    }
    __syncthreads();

    if (d < CPH) {
        float s = 0.f;
        for (int j = 0; j < 64; ++j) s = fmaf(sq[d][j], sq[d][j], s);
        sinq[d] = 1.f / fmaxf(sqrtf(s), 1e-12f);
    } else if (d >= 32 && d < 32 + CPH) {
        const int c = d - 32;
        float s = 0.f;
        for (int j = 0; j < 64; ++j) s = fmaf(sk[c][j], sk[c][j], s);
        sink[c] = 1.f / fmaxf(sqrtf(s), 1e-12f);
    }
    __syncthreads();

    const float t = temp[head];
    for (int idx = d; idx < CPH * CPH; idx += 64) {
        const int c = idx / CPH, e = idx % CPH;
        float s = 0.f;
        for (int j = 0; j < 64; ++j) s = fmaf(sq[c][j], sk[e][j], s);
        sA[c][e] = s * sinq[c] * sink[e] * t;
    }
    __syncthreads();

    if (d < CPH) {
        float m = -1e30f;
        for (int e = 0; e < CPH; ++e) m = fmaxf(m, sA[d][e]);
        float ex[CPH]; float s = 0.f;
        for (int e = 0; e < CPH; ++e) { ex[e] = expf(sA[d][e] - m); s += ex[e]; }
        const float inv = 1.f / s;
        for (int e = 0; e < CPH; ++e) sA[d][e] = ex[e] * inv;
    }
    __syncthreads();

    const size_t ob = ((size_t)b * CDIM + head * CPH) * HWPIX;
    for (int c = 0; c < CPH; ++c) {
        float acc = 0.f;
        for (int e = 0; e < CPH; ++e) acc = fmaf(sA[c][e], sv[e][d], acc);
        Osum[ob + (size_t)c * HWPIX + pr] = acc;
    }
}

// ---------------------------------------------------------------------------
// Global branch stats: per (b,head) partial Gram + norms over 2048-d chunks.
// ---------------------------------------------------------------------------
__global__ __launch_bounds__(256) void gstats_kernel(
    const bf16* __restrict__ QKV, float* __restrict__ Gp)
{
    __shared__ float sq[CPH][260];
    __shared__ float sk[CPH][260];
    const int chunk = blockIdx.x;
    const int bh = blockIdx.y;
    const int b = bh >> 3, head = bh & 7;
    const int tid = threadIdx.x;
    const size_t qb = ((size_t)b * C3 + head * CPH) * HWPIX;
    const size_t kb = qb + (size_t)CDIM * HWPIX;

    float a00 = 0.f, a01 = 0.f, a10 = 0.f, a11 = 0.f;

    for (int sub = 0; sub < 8; ++sub) {
        const int d0 = chunk * 2048 + sub * 256;
        for (int idx = tid; idx < CPH * 256; idx += 256) {
            const int dd = idx & 255, c = idx >> 8;
            sq[c][dd] = b2f(QKV[qb + (size_t)c * HWPIX + d0 + dd]);
            sk[c][dd] = b2f(QKV[kb + (size_t)c * HWPIX + d0 + dd]);
        }
        __syncthreads();

        if (tid < 144) {
            const int c0 = (tid / 12) * 2, e0 = (tid % 12) * 2;
            const float* q0 = sq[c0]; const float* q1 = sq[c0 + 1];
            const float* k0 = sk[e0]; const float* k1 = sk[e0 + 1];
#pragma unroll 4
            for (int dd = 0; dd < 256; ++dd) {
                const float x0 = q0[dd], x1 = q1[dd];
                const float y0 = k0[dd], y1 = k1[dd];
                a00 = fmaf(x0, y0, a00); a01 = fmaf(x0, y1, a01);
                a10 = fmaf(x1, y0, a10); a11 = fmaf(x1, y1, a11);
            }
        } else if (tid < 168) {
            const float* r = sq[tid - 144];
#pragma unroll 4
            for (int dd = 0; dd < 256; ++dd) a00 = fmaf(r[dd], r[dd], a00);
        } else if (tid < 192) {
            const float* r = sk[tid - 168];
#pragma unroll 4
            for (int dd = 0; dd < 256; ++dd) a00 = fmaf(r[dd], r[dd], a00);
        }
        __syncthreads();
    }

    float* dst = Gp + ((size_t)bh * 32 + chunk) * 624;
    if (tid < 144) {
        const int c0 = (tid / 12) * 2, e0 = (tid % 12) * 2;
        dst[(c0    ) * CPH + e0    ] = a00;
        dst[(c0    ) * CPH + e0 + 1] = a01;
        dst[(c0 + 1) * CPH + e0    ] = a10;
        dst[(c0 + 1) * CPH + e0 + 1] = a11;
    } else if (tid < 168) {
        dst[576 + (tid - 144)] = a00;
    } else if (tid < 192) {
        dst[600 + (tid - 168)] = a00;
    }
}

// ---------------------------------------------------------------------------
__global__ __launch_bounds__(64) void gsoftmax_kernel(
    const float* __restrict__ Gp, const float* __restrict__ temp,
    float* __restrict__ A)
{
    __shared__ float red[624];
    const int bh = blockIdx.x, head = bh & 7;
    const int tid = threadIdx.x;

    for (int jj = tid; jj < 624; jj += 64) {
        float s = 0.f;
        for (int ch = 0; ch < 32; ++ch) s += Gp[((size_t)bh * 32 + ch) * 624 + jj];
        red[jj] = s;
    }
    __syncthreads();

    if (tid < CPH) {
        const int c = tid;
        const float t = temp[head];
        const float inq = 1.f / fmaxf(sqrtf(red[576 + c]), 1e-12f);
        float l[CPH]; float m = -1e30f;
        for (int e = 0; e < CPH; ++e) {
            const float ink = 1.f / fmaxf(sqrtf(red[600 + e]), 1e-12f);
            l[e] = red[c * CPH + e] * inq * ink * t;
            m = fmaxf(m, l[e]);
        }
        float s = 0.f;
        for (int e = 0; e < CPH; ++e) { l[e] = expf(l[e] - m); s += l[e]; }
        const float inv = 1.f / s;
        for (int e = 0; e < CPH; ++e) A[(size_t)bh * 576 + c * CPH + e] = l[e] * inv;
    }
}

// ---------------------------------------------------------------------------
__global__ __launch_bounds__(256) void gapply_kernel(
    const bf16* __restrict__ QKV, const float* __restrict__ A,
    float* __restrict__ Osum)
{
    __shared__ float sA[576];
    const int bh = blockIdx.y;
    const int b = bh >> 3, head = bh & 7;
    const int d = blockIdx.x * 256 + threadIdx.x;

    for (int idx = threadIdx.x; idx < 576; idx += 256) sA[idx] = A[(size_t)bh * 576 + idx];
    __syncthreads();

    const size_t vb = ((size_t)b * C3 + 2 * CDIM + head * CPH) * HWPIX;
    const size_t ob = ((size_t)b * CDIM + head * CPH) * HWPIX;

    float v[CPH];
#pragma unroll
    for (int e = 0; e < CPH; ++e) v[e] = b2f(QKV[vb + (size_t)e * HWPIX + d]);

#pragma unroll 4
    for (int c = 0; c < CPH; ++c) {
        float acc = Osum[ob + (size_t)c * HWPIX + d];
        const float* Ar = &sA[c * CPH];
#pragma unroll
        for (int e = 0; e < CPH; ++e) acc = fmaf(Ar[e], v[e], acc);
        Osum[ob + (size_t)c * HWPIX + d] = acc;
    }
}

// ---------------------------------------------------------------------------
extern "C" void kernel_launch(void* const* d_in, const int* in_sizes, int n_in,
                              void* d_out, int out_size, void* d_ws, size_t ws_size,
                              hipStream_t stream) {
    const float* x           = (const float*)d_in[0];
    const float* temperature = (const float*)d_in[1];
    const float* qkv_w       = (const float*)d_in[2];
    const float* qkv_b       = (const float*)d_in[3];
    const float* dw_w        = (const float*)d_in[4];
    const float* dw_b        = (const float*)d_in[5];
    const float* proj_w      = (const float*)d_in[6];
    const float* proj_b      = (const float*)d_in[7];
    float* out = (float*)d_out;

    char* ws = (char*)d_ws;
    constexpr size_t QKV_ELEMS = (size_t)NBATCH * C3 * HWPIX;
    constexpr size_t QKV_BYTES = QKV_ELEMS * sizeof(bf16);

    bf16* qkv1 = (bf16*)ws;                       // conv1x1 out (bf16)
    bf16* qkv2 = (bf16*)(ws + QKV_BYTES);         // q,k,v after depthwise (bf16)
    float* osum = (float*)ws;                     // overlays qkv1 (dead after dw)
    float* Gp   = (float*)(ws + 2 * QKV_BYTES);   // 32*32*624 f32 partials
    float* Amat = Gp + (size_t)32 * 32 * 624;     // 32*576 f32
    u16*  Wb    = (u16*)Gp;                       // bf16 weights; dead before gstats

    // 0. weights f32 -> bf16
    prep_weights<<<(C3 * CDIM + 255) / 256, 256, 0, stream>>>(qkv_w, Wb, C3 * CDIM);

    // 1. qkv = 1x1 conv via MFMA (f32 in, bf16 out)
    conv_qkv_mfma<<<9 * 512 * NBATCH, 256, 0, stream>>>(x, Wb, qkv_b, qkv1);

    // 2. depthwise 3x3
    dwconv_kernel<<<dim3(HWPIX / 256, NBATCH * C3), 256, 0, stream>>>(
        qkv1, dw_w, dw_b, qkv2);

    // 3. local windowed attention -> writes all of osum (o1)
    local_attn_kernel<<<dim3(1024, NHEADS, NBATCH), 64, 0, stream>>>(
        qkv2, temperature, osum);

    // 4. global Gram/norm partials (overwrites Wb region — Wb is dead now)
    gstats_kernel<<<dim3(32, 32), 256, 0, stream>>>(qkv2, Gp);

    // 5. reduce + softmax -> A
    gsoftmax_kernel<<<32, 64, 0, stream>>>(Gp, temperature, Amat);

    // 6. apply global attention, add into osum
    gapply_kernel<<<dim3(HWPIX / 256, 32), 256, 0, stream>>>(qkv2, Amat, osum);

    // 7. proj 1x1 conv (f32 -> f32 out)
    conv_proj_f32<<<3 * 512 * NBATCH, 256, 0, stream>>>(osum, proj_w, proj_b, out);
}

// Round 4
// 1589.585 us; speedup vs baseline: 2.5383x; 1.6359x over previous
//
#include <hip/hip_runtime.h>
#include <hip/hip_bf16.h>
#include <cstdint>
#include <cstddef>

#define HWPIX 65536
#define IMGW 256
#define CDIM 192
#define C3 576
#define NBATCH 4
#define NHEADS 8
#define CPH 24
#define KP 104   // padded K pitch (bf16 elems) for qkv MFMA LDS tiles

using bf16 = __hip_bfloat16;
typedef __attribute__((ext_vector_type(8))) short short8;
typedef __attribute__((ext_vector_type(4))) float f32x4;
typedef unsigned int u32;
typedef unsigned short u16;

__device__ __forceinline__ float b2f(bf16 v) { return __bfloat162float(v); }
__device__ __forceinline__ bf16 f2b(float v) { return __float2bfloat16(v); }
__device__ __forceinline__ float bu2f(u16 h) { return __uint_as_float((u32)h << 16); }
__device__ __forceinline__ u16 f2bu(float x) {
    bf16 h = __float2bfloat16(x);
    return *reinterpret_cast<u16*>(&h);
}
__device__ __forceinline__ u32 pack2(float a, float b) {
    return (u32)f2bu(a) | ((u32)f2bu(b) << 16);
}

// ---------------------------------------------------------------------------
// Convert qkv weights f32 -> bf16 (u16) once per launch.
// ---------------------------------------------------------------------------
__global__ __launch_bounds__(256) void prep_weights(
    const float* __restrict__ W, u16* __restrict__ Wb, int n)
{
    int i = blockIdx.x * 256 + threadIdx.x;
    if (i < n) Wb[i] = f2bu(W[i]);
}

// ---------------------------------------------------------------------------
// qkv 1x1 conv as bf16 MFMA GEMM (unchanged — verified).
// ---------------------------------------------------------------------------
__global__ __launch_bounds__(256) void conv_qkv_mfma(
    const float* __restrict__ X, const u16* __restrict__ Wb,
    const float* __restrict__ bias, bf16* __restrict__ Y)
{
    __shared__ u16 sA[64 * KP];
    __shared__ u16 sB[128 * KP];

    int lin = blockIdx.x;
    lin = (lin & 7) * (18432 / 8) + (lin >> 3);
    const int co_t = lin % 9;
    const int rest = lin / 9;
    const int p_t = rest & 511;
    const int b   = rest >> 9;
    const int co0 = co_t * 64;
    const int p0  = p_t * 128;

    const int tid  = threadIdx.x;
    const int wave = tid >> 6;
    const int lane = tid & 63;
    const int r  = lane & 15;
    const int hk = lane >> 4;

    f32x4 acc[4][2];
#pragma unroll
    for (int i = 0; i < 4; ++i)
#pragma unroll
        for (int j = 0; j < 2; ++j) acc[i][j] = (f32x4){0.f, 0.f, 0.f, 0.f};

#pragma unroll
    for (int c = 0; c < 2; ++c) {
        {
            int idx = tid;
#pragma unroll
            for (int i = 0; i < 3; ++i, idx += 256) {
                const int row = idx / 12, cv = idx % 12;
                const uint4 v = *reinterpret_cast<const uint4*>(
                    Wb + (size_t)(co0 + row) * CDIM + c * 96 + cv * 8);
                *reinterpret_cast<uint4*>(&sA[row * KP + cv * 8]) = v;
            }
        }
        {
            const int pl   = wave * 32 + (lane & 31);
            const int koff = lane >> 5;
            const float* Xp = X + ((size_t)b * CDIM + c * 96) * HWPIX + p0 + pl;
#pragma unroll
            for (int i = 0; i < 24; ++i) {
                const int k = i * 4 + koff * 2;
                const float v0 = Xp[(size_t)k * HWPIX];
                const float v1 = Xp[(size_t)(k + 1) * HWPIX];
                *reinterpret_cast<u32*>(&sB[pl * KP + k]) = pack2(v0, v1);
            }
        }
        __syncthreads();

#pragma unroll
        for (int ks = 0; ks < 3; ++ks) {
            const int kof = ks * 32 + hk * 8;
            const u16* pA = &sA[r * KP + kof];
            const u16* pB = &sB[(wave * 32 + r) * KP + kof];
            const short8 a0 = *reinterpret_cast<const short8*>(pA);
            const short8 a1 = *reinterpret_cast<const short8*>(pA + 16 * KP);
            const short8 a2 = *reinterpret_cast<const short8*>(pA + 32 * KP);
            const short8 a3 = *reinterpret_cast<const short8*>(pA + 48 * KP);
            const short8 b0 = *reinterpret_cast<const short8*>(pB);
            const short8 b1 = *reinterpret_cast<const short8*>(pB + 16 * KP);
            acc[0][0] = __builtin_amdgcn_mfma_f32_16x16x32_bf16(a0, b0, acc[0][0], 0, 0, 0);
            acc[1][0] = __builtin_amdgcn_mfma_f32_16x16x32_bf16(a1, b0, acc[1][0], 0, 0, 0);
            acc[2][0] = __builtin_amdgcn_mfma_f32_16x16x32_bf16(a2, b0, acc[2][0], 0, 0, 0);
            acc[3][0] = __builtin_amdgcn_mfma_f32_16x16x32_bf16(a3, b0, acc[3][0], 0, 0, 0);
            acc[0][1] = __builtin_amdgcn_mfma_f32_16x16x32_bf16(a0, b1, acc[0][1], 0, 0, 0);
            acc[1][1] = __builtin_amdgcn_mfma_f32_16x16x32_bf16(a1, b1, acc[1][1], 0, 0, 0);
            acc[2][1] = __builtin_amdgcn_mfma_f32_16x16x32_bf16(a2, b1, acc[2][1], 0, 0, 0);
            acc[3][1] = __builtin_amdgcn_mfma_f32_16x16x32_bf16(a3, b1, acc[3][1], 0, 0, 0);
        }
        __syncthreads();
    }

#pragma unroll
    for (int mf = 0; mf < 4; ++mf) {
#pragma unroll
        for (int j = 0; j < 4; ++j) {
            const int co = co0 + mf * 16 + hk * 4 + j;
            const float bs = bias[co];
            const size_t base = ((size_t)b * C3 + co) * HWPIX + p0 + wave * 32 + r;
            Y[base]      = f2b(acc[mf][0][j] + bs);
            Y[base + 16] = f2b(acc[mf][1][j] + bs);
        }
    }
}

// ---------------------------------------------------------------------------
// proj 1x1 conv, f32 vector GEMM (unchanged).
// ---------------------------------------------------------------------------
__global__ __launch_bounds__(256) void conv_proj_f32(
    const float* __restrict__ X, const float* __restrict__ W,
    const float* __restrict__ bias, float* __restrict__ Y)
{
    __shared__ float sW[64][68];
    __shared__ float sX[64][132];

    int lin = blockIdx.x;
    lin = (lin & 7) * (6144 / 8) + (lin >> 3);
    const int co_t = lin % 3;
    const int rest = lin / 3;
    const int p_t = rest & 511;
    const int b   = rest >> 9;
    const int co0 = co_t * 64;
    const int p0  = p_t * 128;

    const int tid = threadIdx.x;
    const int tx = tid & 15, ty = tid >> 4;

    float acc[4][8] = {};

    for (int c = 0; c < 3; ++c) {
        {
            int idx = tid;
#pragma unroll
            for (int i = 0; i < 4; ++i, idx += 256) {
                const int co_l = idx >> 4, kq = idx & 15;
                const float4 v = *reinterpret_cast<const float4*>(
                    &W[(size_t)(co0 + co_l) * CDIM + c * 64 + kq * 4]);
                sW[kq * 4 + 0][co_l] = v.x;
                sW[kq * 4 + 1][co_l] = v.y;
                sW[kq * 4 + 2][co_l] = v.z;
                sW[kq * 4 + 3][co_l] = v.w;
            }
        }
        {
            int idx = tid;
#pragma unroll
            for (int i = 0; i < 8; ++i, idx += 256) {
                const int row = idx >> 5, cq = idx & 31;
                const float4 v = *reinterpret_cast<const float4*>(
                    &X[((size_t)b * CDIM + c * 64 + row) * HWPIX + p0 + cq * 4]);
                *reinterpret_cast<float4*>(&sX[row][cq * 4]) = v;
            }
        }
        __syncthreads();

#pragma unroll 4
        for (int k = 0; k < 64; ++k) {
            const float4 w4 = *reinterpret_cast<const float4*>(&sW[k][ty * 4]);
            const float4 xa = *reinterpret_cast<const float4*>(&sX[k][tx * 4]);
            const float4 xb = *reinterpret_cast<const float4*>(&sX[k][64 + tx * 4]);
            const float wv[4] = {w4.x, w4.y, w4.z, w4.w};
            const float xv[8] = {xa.x, xa.y, xa.z, xa.w, xb.x, xb.y, xb.z, xb.w};
#pragma unroll
            for (int i = 0; i < 4; ++i)
#pragma unroll
                for (int j = 0; j < 8; ++j) acc[i][j] = fmaf(wv[i], xv[j], acc[i][j]);
        }
        __syncthreads();
    }

#pragma unroll
    for (int i = 0; i < 4; ++i) {
        const int co = co0 + ty * 4 + i;
        const float bs = bias[co];
        const size_t base = ((size_t)b * CDIM + co) * HWPIX + p0;
        float4 o0 = {acc[i][0] + bs, acc[i][1] + bs, acc[i][2] + bs, acc[i][3] + bs};
        float4 o1 = {acc[i][4] + bs, acc[i][5] + bs, acc[i][6] + bs, acc[i][7] + bs};
        *reinterpret_cast<float4*>(&Y[base + tx * 4]) = o0;
        *reinterpret_cast<float4*>(&Y[base + 64 + tx * 4]) = o1;
    }
}

// ---------------------------------------------------------------------------
// Depthwise 3x3 SAME conv — vectorized.
// ---------------------------------------------------------------------------
__global__ __launch_bounds__(256) void dwconv_kernel(
    const bf16* __restrict__ In, const float* __restrict__ Wd,
    const float* __restrict__ bd, bf16* __restrict__ Out)
{
    __shared__ alignas(16) u16 sIn[10 * 256];
    const int bc = blockIdx.y;            // b*576 + c
    const int c = bc % C3;
    const size_t base = (size_t)bc * HWPIX;
    const int r0 = blockIdx.x * 8;
    const int tid = threadIdx.x;

    for (int idx = tid; idx < 320; idx += 256) {
        const int lr = idx >> 5, ch = idx & 31;
        const int gr = r0 + lr - 1;
        uint4 v = {0u, 0u, 0u, 0u};
        if ((unsigned)gr < IMGW)
            v = *reinterpret_cast<const uint4*>(&In[base + (size_t)gr * IMGW + ch * 8]);
        *reinterpret_cast<uint4*>(&sIn[lr * 256 + ch * 8]) = v;
    }
    __syncthreads();

    float wg[9];
#pragma unroll
    for (int t = 0; t < 9; ++t) wg[t] = Wd[c * 9 + t];

    const int rr = tid >> 5;
    const int px0 = (tid & 31) * 8;
    const float bias = bd[c];
    float acc[8];
#pragma unroll
    for (int j = 0; j < 8; ++j) acc[j] = bias;

#pragma unroll
    for (int dy = 0; dy < 3; ++dy) {
        const int row = rr + dy;
        const u16* rp = &sIn[row * 256];
        const short8 mv = *reinterpret_cast<const short8*>(&rp[px0]);
        float m[8];
#pragma unroll
        for (int j = 0; j < 8; ++j) m[j] = bu2f((u16)mv[j]);
        const float lft = (px0 > 0) ? bu2f(rp[px0 - 1]) : 0.f;
        const float rgt = (px0 + 8 < 256) ? bu2f(rp[px0 + 8]) : 0.f;
        const float w0 = wg[dy * 3], w1 = wg[dy * 3 + 1], w2 = wg[dy * 3 + 2];

        acc[0] = fmaf(w0, lft, acc[0]);
        acc[0] = fmaf(w1, m[0], acc[0]);
        acc[0] = fmaf(w2, m[1], acc[0]);
#pragma unroll
        for (int j = 1; j < 7; ++j) {
            acc[j] = fmaf(w0, m[j - 1], acc[j]);
            acc[j] = fmaf(w1, m[j], acc[j]);
            acc[j] = fmaf(w2, m[j + 1], acc[j]);
        }
        acc[7] = fmaf(w0, m[6], acc[7]);
        acc[7] = fmaf(w1, m[7], acc[7]);
        acc[7] = fmaf(w2, rgt, acc[7]);
    }

    uint4 ov;
    ov.x = pack2(acc[0], acc[1]);
    ov.y = pack2(acc[2], acc[3]);
    ov.z = pack2(acc[4], acc[5]);
    ov.w = pack2(acc[6], acc[7]);
    *reinterpret_cast<uint4*>(&Out[base + (size_t)(r0 + rr) * IMGW + px0]) = ov;
}

// ---------------------------------------------------------------------------
// Local (windowed 8x8) channel attention — MFMA version.
// ---------------------------------------------------------------------------
#define CS 328          // c-row stride (u16) for sQ/sK/sV
#define PS 40           // row stride (u16) for sP

__global__ __launch_bounds__(256) void local_attn_kernel(
    const bf16* __restrict__ QKV, const float* __restrict__ temp,
    float* __restrict__ Osum)
{
    __shared__ alignas(16) u16 sQ[32 * CS];
    __shared__ alignas(16) u16 sK[32 * CS];
    __shared__ alignas(16) u16 sV[32 * CS];
    __shared__ alignas(16) u16 sP[4 * 32 * PS];
    __shared__ float snq[4 * 32], snk[4 * 32];

    const int wy    = blockIdx.x >> 3;     // window row 0..31
    const int strip = blockIdx.x & 7;      // 4-window strip 0..7
    const int head  = blockIdx.y;
    const int b     = blockIdx.z;
    const int x0    = strip * 32;
    const int tid   = threadIdx.x;
    const int w     = tid >> 6;            // wave = window 0..3
    const int lane  = tid & 63;
    const int r     = lane & 15;
    const int hk    = lane >> 4;

    // ---- stage q,k,v: 24c x 8r x 32px each, uint4 chunks, coalesced rows.
    // (no LDS-pointer array: runtime ternary select — pointer arrays of
    //  __shared__ hit an addrspacecast static-initializer error on hipcc)
#pragma unroll
    for (int i = 0; i < 9; ++i) {
        const int idx = tid + i * 256;       // 0..2303
        const int tensor = idx / 768;
        const int rem = idx - tensor * 768;
        const int c  = rem >> 5;
        const int rw = (rem >> 2) & 7;
        const int ch = rem & 3;
        const size_t g = ((size_t)b * C3 + tensor * CDIM + head * CPH + c) * HWPIX
                       + (size_t)(wy * 8 + rw) * IMGW + x0 + ch * 8;
        const uint4 v = *reinterpret_cast<const uint4*>(&QKV[g]);
        u16* dst = (tensor == 0) ? sQ : ((tensor == 1) ? sK : sV);
        *reinterpret_cast<uint4*>(&dst[c * CS + rw * 40 + ch * 8]) = v;
    }
    __syncthreads();

    // ---- per-window q,k inverse norms (threads 0..191)
    if (tid < 192) {
        const int qk = tid / 96;
        const int rem = tid - qk * 96;
        const int ww = rem / 24, c = rem % 24;
        const u16* sT = qk ? sK : sQ;
        const int off = c * CS + ww * 8;
        float s = 0.f;
#pragma unroll
        for (int rw = 0; rw < 8; ++rw) {
            const short8 v = *reinterpret_cast<const short8*>(&sT[off + rw * 40]);
#pragma unroll
            for (int j = 0; j < 8; ++j) {
                const float f = bu2f((u16)v[j]);
                s = fmaf(f, f, s);
            }
        }
        const float inv = 1.f / fmaxf(sqrtf(s), 1e-12f);
        if (qk) snk[ww * 32 + c] = inv; else snq[ww * 32 + c] = inv;
    }
    __syncthreads();

    // ---- Gram via MFMA: G[c][e], 2x2 tiles of 16, K=64 px in 2 steps
    f32x4 accg[2][2];
#pragma unroll
    for (int i = 0; i < 2; ++i)
#pragma unroll
        for (int j = 0; j < 2; ++j) accg[i][j] = (f32x4){0.f, 0.f, 0.f, 0.f};

#pragma unroll
    for (int kk = 0; kk < 2; ++kk) {
        const int colA = (kk * 4 + hk) * 40 + w * 8;
        const short8 aq0 = *reinterpret_cast<const short8*>(&sQ[(r     ) * CS + colA]);
        const short8 aq1 = *reinterpret_cast<const short8*>(&sQ[(16 + r) * CS + colA]);
        const short8 bk0 = *reinterpret_cast<const short8*>(&sK[(r     ) * CS + colA]);
        const short8 bk1 = *reinterpret_cast<const short8*>(&sK[(16 + r) * CS + colA]);
        accg[0][0] = __builtin_amdgcn_mfma_f32_16x16x32_bf16(aq0, bk0, accg[0][0], 0, 0, 0);
        accg[0][1] = __builtin_amdgcn_mfma_f32_16x16x32_bf16(aq0, bk1, accg[0][1], 0, 0, 0);
        accg[1][0] = __builtin_amdgcn_mfma_f32_16x16x32_bf16(aq1, bk0, accg[1][0], 0, 0, 0);
        accg[1][1] = __builtin_amdgcn_mfma_f32_16x16x32_bf16(aq1, bk1, accg[1][1], 0, 0, 0);
    }

    // ---- softmax over e (24 valid), D layout: col=lane&15 (e), row=hk*4+j (c)
    const float t = temp[head];
    const int e0 = lane & 15;
    const bool v1 = e0 < 8;
    const float ink0 = snk[w * 32 + e0];
    const float ink1 = snk[w * 32 + 16 + e0];

#pragma unroll
    for (int ct = 0; ct < 2; ++ct) {
#pragma unroll
        for (int j = 0; j < 4; ++j) {
            const int cidx = ct * 16 + hk * 4 + j;
            const float inq = snq[w * 32 + cidx];
            const float g0 = accg[ct][0][j] * inq * ink0 * t;
            const float g1 = v1 ? accg[ct][1][j] * inq * ink1 * t : -1e30f;
            float m = fmaxf(g0, g1);
#pragma unroll
            for (int mk = 8; mk >= 1; mk >>= 1) m = fmaxf(m, __shfl_xor(m, mk));
            const float p0 = __expf(g0 - m);
            const float p1 = v1 ? __expf(g1 - m) : 0.f;
            float s = p0 + p1;
#pragma unroll
            for (int mk = 8; mk >= 1; mk >>= 1) s += __shfl_xor(s, mk);
            const float inv = 1.f / s;
            if (cidx < CPH) {
                sP[w * 32 * PS + cidx * PS + e0] = f2bu(p0 * inv);
                if (v1) sP[w * 32 * PS + cidx * PS + 16 + e0] = f2bu(p1 * inv);
            }
        }
    }
    __syncthreads();

    // ---- PV via MFMA: O[c][px] = sum_e P[c][e] V[e][px], K=32 (e>=24 zeroed)
    f32x4 acco[2][4];
#pragma unroll
    for (int i = 0; i < 2; ++i)
#pragma unroll
        for (int j = 0; j < 4; ++j) acco[i][j] = (f32x4){0.f, 0.f, 0.f, 0.f};

    short8 afr[2];
#pragma unroll
    for (int ct = 0; ct < 2; ++ct) {
        if (hk < 3)
            afr[ct] = *reinterpret_cast<const short8*>(
                &sP[w * 32 * PS + (ct * 16 + r) * PS + hk * 8]);
        else
            afr[ct] = (short8){0, 0, 0, 0, 0, 0, 0, 0};
    }
#pragma unroll
    for (int nt = 0; nt < 4; ++nt) {
        const int px = nt * 16 + r;
        const int colV = (px >> 3) * 40 + w * 8 + (px & 7);
        short8 bfr;
        if (hk < 3) {
#pragma unroll
            for (int j = 0; j < 8; ++j)
                bfr[j] = (short)sV[(hk * 8 + j) * CS + colV];
        } else {
            bfr = (short8){0, 0, 0, 0, 0, 0, 0, 0};
        }
        acco[0][nt] = __builtin_amdgcn_mfma_f32_16x16x32_bf16(afr[0], bfr, acco[0][nt], 0, 0, 0);
        acco[1][nt] = __builtin_amdgcn_mfma_f32_16x16x32_bf16(afr[1], bfr, acco[1][nt], 0, 0, 0);
    }

    // ---- store o1 (f32)
    const size_t ob = ((size_t)b * CDIM + head * CPH) * HWPIX;
#pragma unroll
    for (int ct = 0; ct < 2; ++ct) {
#pragma unroll
        for (int j = 0; j < 4; ++j) {
            const int cidx = ct * 16 + hk * 4 + j;
            if (cidx >= CPH) continue;
#pragma unroll
            for (int nt = 0; nt < 4; ++nt) {
                const int px = nt * 16 + r;
                const int rpx = px >> 3, pxl = px & 7;
                Osum[ob + (size_t)cidx * HWPIX
                     + (size_t)(wy * 8 + rpx) * IMGW + x0 + w * 8 + pxl] = acco[ct][nt][j];
            }
        }
    }
}

// ---------------------------------------------------------------------------
// Global branch stats (staging vectorized).
// ---------------------------------------------------------------------------
__global__ __launch_bounds__(256) void gstats_kernel(
    const bf16* __restrict__ QKV, float* __restrict__ Gp)
{
    __shared__ float sq[CPH][260];
    __shared__ float sk[CPH][260];
    const int chunk = blockIdx.x;
    const int bh = blockIdx.y;
    const int b = bh >> 3, head = bh & 7;
    const int tid = threadIdx.x;
    const size_t qb = ((size_t)b * C3 + head * CPH) * HWPIX;
    const size_t kb = qb + (size_t)CDIM * HWPIX;

    float a00 = 0.f, a01 = 0.f, a10 = 0.f, a11 = 0.f;

    for (int sub = 0; sub < 8; ++sub) {
        const int d0 = chunk * 2048 + sub * 256;
        for (int idx = tid; idx < 768; idx += 256) {
            const int c = idx >> 5, ch = idx & 31;
            const uint4 vq = *reinterpret_cast<const uint4*>(&QKV[qb + (size_t)c * HWPIX + d0 + ch * 8]);
            const uint4 vk = *reinterpret_cast<const uint4*>(&QKV[kb + (size_t)c * HWPIX + d0 + ch * 8]);
            float4 q0 = {bu2f((u16)(vq.x & 0xffff)), bu2f((u16)(vq.x >> 16)),
                         bu2f((u16)(vq.y & 0xffff)), bu2f((u16)(vq.y >> 16))};
            float4 q1 = {bu2f((u16)(vq.z & 0xffff)), bu2f((u16)(vq.z >> 16)),
                         bu2f((u16)(vq.w & 0xffff)), bu2f((u16)(vq.w >> 16))};
            float4 k0 = {bu2f((u16)(vk.x & 0xffff)), bu2f((u16)(vk.x >> 16)),
                         bu2f((u16)(vk.y & 0xffff)), bu2f((u16)(vk.y >> 16))};
            float4 k1 = {bu2f((u16)(vk.z & 0xffff)), bu2f((u16)(vk.z >> 16)),
                         bu2f((u16)(vk.w & 0xffff)), bu2f((u16)(vk.w >> 16))};
            *reinterpret_cast<float4*>(&sq[c][ch * 8]) = q0;
            *reinterpret_cast<float4*>(&sq[c][ch * 8 + 4]) = q1;
            *reinterpret_cast<float4*>(&sk[c][ch * 8]) = k0;
            *reinterpret_cast<float4*>(&sk[c][ch * 8 + 4]) = k1;
        }
        __syncthreads();

        if (tid < 144) {
            const int c0 = (tid / 12) * 2, e0 = (tid % 12) * 2;
            const float* q0 = sq[c0]; const float* q1 = sq[c0 + 1];
            const float* k0 = sk[e0]; const float* k1 = sk[e0 + 1];
#pragma unroll 4
            for (int dd = 0; dd < 256; ++dd) {
                const float x0 = q0[dd], x1 = q1[dd];
                const float y0 = k0[dd], y1 = k1[dd];
                a00 = fmaf(x0, y0, a00); a01 = fmaf(x0, y1, a01);
                a10 = fmaf(x1, y0, a10); a11 = fmaf(x1, y1, a11);
            }
        } else if (tid < 168) {
            const float* rr = sq[tid - 144];
#pragma unroll 4
            for (int dd = 0; dd < 256; ++dd) a00 = fmaf(rr[dd], rr[dd], a00);
        } else if (tid < 192) {
            const float* rr = sk[tid - 168];
#pragma unroll 4
            for (int dd = 0; dd < 256; ++dd) a00 = fmaf(rr[dd], rr[dd], a00);
        }
        __syncthreads();
    }

    float* dst = Gp + ((size_t)bh * 32 + chunk) * 624;
    if (tid < 144) {
        const int c0 = (tid / 12) * 2, e0 = (tid % 12) * 2;
        dst[(c0    ) * CPH + e0    ] = a00;
        dst[(c0    ) * CPH + e0 + 1] = a01;
        dst[(c0 + 1) * CPH + e0    ] = a10;
        dst[(c0 + 1) * CPH + e0 + 1] = a11;
    } else if (tid < 168) {
        dst[576 + (tid - 144)] = a00;
    } else if (tid < 192) {
        dst[600 + (tid - 168)] = a00;
    }
}

// ---------------------------------------------------------------------------
__global__ __launch_bounds__(64) void gsoftmax_kernel(
    const float* __restrict__ Gp, const float* __restrict__ temp,
    float* __restrict__ A)
{
    __shared__ float red[624];
    const int bh = blockIdx.x, head = bh & 7;
    const int tid = threadIdx.x;

    for (int jj = tid; jj < 624; jj += 64) {
        float s = 0.f;
        for (int ch = 0; ch < 32; ++ch) s += Gp[((size_t)bh * 32 + ch) * 624 + jj];
        red[jj] = s;
    }
    __syncthreads();

    if (tid < CPH) {
        const int c = tid;
        const float t = temp[head];
        const float inq = 1.f / fmaxf(sqrtf(red[576 + c]), 1e-12f);
        float l[CPH]; float m = -1e30f;
        for (int e = 0; e < CPH; ++e) {
            const float ink = 1.f / fmaxf(sqrtf(red[600 + e]), 1e-12f);
            l[e] = red[c * CPH + e] * inq * ink * t;
            m = fmaxf(m, l[e]);
        }
        float s = 0.f;
        for (int e = 0; e < CPH; ++e) { l[e] = expf(l[e] - m); s += l[e]; }
        const float inv = 1.f / s;
        for (int e = 0; e < CPH; ++e) A[(size_t)bh * 576 + c * CPH + e] = l[e] * inv;
    }
}

// ---------------------------------------------------------------------------
__global__ __launch_bounds__(256) void gapply_kernel(
    const bf16* __restrict__ QKV, const float* __restrict__ A,
    float* __restrict__ Osum)
{
    __shared__ float sA[576];
    const int bh = blockIdx.y;
    const int b = bh >> 3, head = bh & 7;
    const int d = blockIdx.x * 256 + threadIdx.x;

    for (int idx = threadIdx.x; idx < 576; idx += 256) sA[idx] = A[(size_t)bh * 576 + idx];
    __syncthreads();

    const size_t vb = ((size_t)b * C3 + 2 * CDIM + head * CPH) * HWPIX;
    const size_t ob = ((size_t)b * CDIM + head * CPH) * HWPIX;

    float v[CPH];
#pragma unroll
    for (int e = 0; e < CPH; ++e) v[e] = b2f(QKV[vb + (size_t)e * HWPIX + d]);

#pragma unroll 4
    for (int c = 0; c < CPH; ++c) {
        float acc = Osum[ob + (size_t)c * HWPIX + d];
        const float* Ar = &sA[c * CPH];
#pragma unroll
        for (int e = 0; e < CPH; ++e) acc = fmaf(Ar[e], v[e], acc);
        Osum[ob + (size_t)c * HWPIX + d] = acc;
    }
}

// ---------------------------------------------------------------------------
extern "C" void kernel_launch(void* const* d_in, const int* in_sizes, int n_in,
                              void* d_out, int out_size, void* d_ws, size_t ws_size,
                              hipStream_t stream) {
    const float* x           = (const float*)d_in[0];
    const float* temperature = (const float*)d_in[1];
    const float* qkv_w       = (const float*)d_in[2];
    const float* qkv_b       = (const float*)d_in[3];
    const float* dw_w        = (const float*)d_in[4];
    const float* dw_b        = (const float*)d_in[5];
    const float* proj_w      = (const float*)d_in[6];
    const float* proj_b      = (const float*)d_in[7];
    float* out = (float*)d_out;

    char* ws = (char*)d_ws;
    constexpr size_t QKV_ELEMS = (size_t)NBATCH * C3 * HWPIX;
    constexpr size_t QKV_BYTES = QKV_ELEMS * sizeof(bf16);

    bf16* qkv1 = (bf16*)ws;                       // conv1x1 out (bf16)
    bf16* qkv2 = (bf16*)(ws + QKV_BYTES);         // q,k,v after depthwise (bf16)
    float* osum = (float*)ws;                     // overlays qkv1 (dead after dw)
    float* Gp   = (float*)(ws + 2 * QKV_BYTES);   // 32*32*624 f32 partials
    float* Amat = Gp + (size_t)32 * 32 * 624;     // 32*576 f32
    u16*  Wb    = (u16*)Gp;                       // bf16 weights; dead before gstats

    // 0. weights f32 -> bf16
    prep_weights<<<(C3 * CDIM + 255) / 256, 256, 0, stream>>>(qkv_w, Wb, C3 * CDIM);

    // 1. qkv = 1x1 conv via MFMA (f32 in, bf16 out)
    conv_qkv_mfma<<<9 * 512 * NBATCH, 256, 0, stream>>>(x, Wb, qkv_b, qkv1);

    // 2. depthwise 3x3 (vectorized)
    dwconv_kernel<<<dim3(32, NBATCH * C3), 256, 0, stream>>>(
        qkv1, dw_w, dw_b, qkv2);

    // 3. local windowed attention (MFMA) -> writes all of osum (o1)
    local_attn_kernel<<<dim3(256, NHEADS, NBATCH), 256, 0, stream>>>(
        qkv2, temperature, osum);

    // 4. global Gram/norm partials
    gstats_kernel<<<dim3(32, 32), 256, 0, stream>>>(qkv2, Gp);

    // 5. reduce + softmax -> A
    gsoftmax_kernel<<<32, 64, 0, stream>>>(Gp, temperature, Amat);

    // 6. apply global attention, add into osum
    gapply_kernel<<<dim3(HWPIX / 256, 32), 256, 0, stream>>>(qkv2, Amat, osum);

    // 7. proj 1x1 conv (f32 -> f32 out)
    conv_proj_f32<<<3 * 512 * NBATCH, 256, 0, stream>>>(osum, proj_w, proj_b, out);
}

// Round 5
// 1125.606 us; speedup vs baseline: 3.5846x; 1.4122x over previous
//
#include <hip/hip_runtime.h>
#include <hip/hip_bf16.h>
#include <cstdint>
#include <cstddef>

#define HWPIX 65536
#define IMGW 256
#define CDIM 192
#define C3 576
#define NBATCH 4
#define NHEADS 8
#define CPH 24
#define KP 104   // padded K pitch (bf16 elems) for qkv MFMA LDS tiles

using bf16 = __hip_bfloat16;
typedef __attribute__((ext_vector_type(8))) short short8;
typedef __attribute__((ext_vector_type(4))) float f32x4;
typedef unsigned int u32;
typedef unsigned short u16;

__device__ __forceinline__ float b2f(bf16 v) { return __bfloat162float(v); }
__device__ __forceinline__ bf16 f2b(float v) { return __float2bfloat16(v); }
__device__ __forceinline__ float bu2f(u16 h) { return __uint_as_float((u32)h << 16); }
__device__ __forceinline__ u16 f2bu(float x) {
    bf16 h = __float2bfloat16(x);
    return *reinterpret_cast<u16*>(&h);
}
__device__ __forceinline__ u32 pack2(float a, float b) {
    return (u32)f2bu(a) | ((u32)f2bu(b) << 16);
}

// ---------------------------------------------------------------------------
// Convert qkv weights f32 -> bf16 (u16) once per launch.
// ---------------------------------------------------------------------------
__global__ __launch_bounds__(256) void prep_weights(
    const float* __restrict__ W, u16* __restrict__ Wb, int n)
{
    int i = blockIdx.x * 256 + threadIdx.x;
    if (i < n) Wb[i] = f2bu(W[i]);
}

// ---------------------------------------------------------------------------
// qkv 1x1 conv as bf16 MFMA GEMM.  Y[b,co,p] = sum_k W[co,k] X[b,k,p] + bias
// Tile 64co x 128p, K=192 in 2 chunks of 96.
// R4 fixes (latency-stall bound at 766us, MfmaUtil 3%):
//  - B-stage: float4 global loads (12/thread/chunk vs 48 scalars), lanes
//    arranged so each channel row gets a 128B contiguous segment.
//  - sB 16B-block XOR swizzle (bk ^= (row>>2)&3): write banks exactly 2-way
//    (free); read fragments stay 16B-contiguous, row & row+16 share swizzle.
//  - Epilogue: acc -> LDS bf16 tile -> uint4 stores (vs 32 scalar 2B stores).
//  - launch_bounds(256,4): VGPR cap 128 for deeper load pipelining.
// ---------------------------------------------------------------------------
__global__ __launch_bounds__(256, 4) void conv_qkv_mfma(
    const float* __restrict__ X, const u16* __restrict__ Wb,
    const float* __restrict__ bias, bf16* __restrict__ Y)
{
    __shared__ alignas(16) u16 sA[64 * KP];
    __shared__ alignas(16) u16 sB[128 * KP];
    __shared__ float sBias[64];

    int lin = blockIdx.x;
    lin = (lin & 7) * (18432 / 8) + (lin >> 3);
    const int co_t = lin % 9;
    const int rest = lin / 9;
    const int p_t = rest & 511;
    const int b   = rest >> 9;
    const int co0 = co_t * 64;
    const int p0  = p_t * 128;

    const int tid  = threadIdx.x;
    const int wave = tid >> 6;
    const int lane = tid & 63;
    const int r  = lane & 15;
    const int hk = lane >> 4;

    if (tid < 64) sBias[tid] = bias[co0 + tid];

    f32x4 acc[4][2];
#pragma unroll
    for (int i = 0; i < 4; ++i)
#pragma unroll
        for (int j = 0; j < 2; ++j) acc[i][j] = (f32x4){0.f, 0.f, 0.f, 0.f};

    const int kp_lane = tid & 7;    // k-pair sub-index (lanes 0-7 -> 8 channels)
    const int p4      = tid >> 3;   // p-quad 0..31

#pragma unroll
    for (int c = 0; c < 2; ++c) {
        // ---- stage A: 64 rows x 96 k of bf16 weights (12 x 16B chunks/row)
        {
            int idx = tid;
#pragma unroll
            for (int i = 0; i < 3; ++i, idx += 256) {
                const int row = idx / 12, cv = idx % 12;
                const uint4 v = *reinterpret_cast<const uint4*>(
                    Wb + (size_t)(co0 + row) * CDIM + c * 96 + cv * 8);
                *reinterpret_cast<uint4*>(&sA[row * KP + cv * 8]) = v;
            }
        }
        // ---- stage B: 96 k x 128 p, float4 loads, swizzled bf16 LDS writes
        {
            const float* Xc = X + ((size_t)b * CDIM + c * 96) * HWPIX + p0;
#pragma unroll
            for (int i = 0; i < 6; ++i) {
                const int kp = kp_lane + i * 8;       // 0..47
                const int k  = kp * 2;                // even 0..94
                const float4 va = *reinterpret_cast<const float4*>(
                    Xc + (size_t)k * HWPIX + p4 * 4);
                const float4 vb = *reinterpret_cast<const float4*>(
                    Xc + (size_t)(k + 1) * HWPIX + p4 * 4);
                // col: XOR 16B-block index with (row>>2)&3 == p4&3
                const int col = (((k >> 3) ^ (p4 & 3)) << 3) | (k & 7);
                const float av[4] = {va.x, va.y, va.z, va.w};
                const float bv[4] = {vb.x, vb.y, vb.z, vb.w};
#pragma unroll
                for (int j = 0; j < 4; ++j) {
                    const int row = p4 * 4 + j;
                    *reinterpret_cast<u32*>(&sB[row * KP + col]) = pack2(av[j], bv[j]);
                }
            }
        }
        __syncthreads();

#pragma unroll
        for (int ks = 0; ks < 3; ++ks) {
            const int kof = ks * 32 + hk * 8;
            const u16* pA = &sA[r * KP + kof];
            const int rowb = wave * 32 + r;
            const int colr = (((kof >> 3) ^ ((rowb >> 2) & 3)) << 3);
            const u16* pB = &sB[rowb * KP + colr];
            const short8 a0 = *reinterpret_cast<const short8*>(pA);
            const short8 a1 = *reinterpret_cast<const short8*>(pA + 16 * KP);
            const short8 a2 = *reinterpret_cast<const short8*>(pA + 32 * KP);
            const short8 a3 = *reinterpret_cast<const short8*>(pA + 48 * KP);
            const short8 b0 = *reinterpret_cast<const short8*>(pB);
            const short8 b1 = *reinterpret_cast<const short8*>(pB + 16 * KP);  // same swizzle: (rowb+16)>>2 & 3 == rowb>>2 & 3
            acc[0][0] = __builtin_amdgcn_mfma_f32_16x16x32_bf16(a0, b0, acc[0][0], 0, 0, 0);
            acc[1][0] = __builtin_amdgcn_mfma_f32_16x16x32_bf16(a1, b0, acc[1][0], 0, 0, 0);
            acc[2][0] = __builtin_amdgcn_mfma_f32_16x16x32_bf16(a2, b0, acc[2][0], 0, 0, 0);
            acc[3][0] = __builtin_amdgcn_mfma_f32_16x16x32_bf16(a3, b0, acc[3][0], 0, 0, 0);
            acc[0][1] = __builtin_amdgcn_mfma_f32_16x16x32_bf16(a0, b1, acc[0][1], 0, 0, 0);
            acc[1][1] = __builtin_amdgcn_mfma_f32_16x16x32_bf16(a1, b1, acc[1][1], 0, 0, 0);
            acc[2][1] = __builtin_amdgcn_mfma_f32_16x16x32_bf16(a2, b1, acc[2][1], 0, 0, 0);
            acc[3][1] = __builtin_amdgcn_mfma_f32_16x16x32_bf16(a3, b1, acc[3][1], 0, 0, 0);
        }
        __syncthreads();
    }

    // ---- epilogue: acc -> bf16 LDS tile [64co][128p] -> coalesced uint4 stores
    u16* sOut = sB;   // reuse (post-barrier)
#pragma unroll
    for (int mf = 0; mf < 4; ++mf) {
#pragma unroll
        for (int j = 0; j < 4; ++j) {
            const int row = mf * 16 + hk * 4 + j;
            const float bs = sBias[row];
            sOut[row * 128 + wave * 32 + r]      = f2bu(acc[mf][0][j] + bs);
            sOut[row * 128 + wave * 32 + r + 16] = f2bu(acc[mf][1][j] + bs);
        }
    }
    __syncthreads();
#pragma unroll
    for (int i = 0; i < 4; ++i) {
        const int idx = tid + i * 256;
        const int row = idx >> 4, cq = idx & 15;
        const uint4 v = *reinterpret_cast<const uint4*>(&sOut[row * 128 + cq * 8]);
        *reinterpret_cast<uint4*>(
            &Y[((size_t)b * C3 + co0 + row) * HWPIX + p0 + cq * 8]) = v;
    }
}

// ---------------------------------------------------------------------------
// proj 1x1 conv, f32 vector GEMM (unchanged).
// ---------------------------------------------------------------------------
__global__ __launch_bounds__(256) void conv_proj_f32(
    const float* __restrict__ X, const float* __restrict__ W,
    const float* __restrict__ bias, float* __restrict__ Y)
{
    __shared__ float sW[64][68];
    __shared__ float sX[64][132];

    int lin = blockIdx.x;
    lin = (lin & 7) * (6144 / 8) + (lin >> 3);
    const int co_t = lin % 3;
    const int rest = lin / 3;
    const int p_t = rest & 511;
    const int b   = rest >> 9;
    const int co0 = co_t * 64;
    const int p0  = p_t * 128;

    const int tid = threadIdx.x;
    const int tx = tid & 15, ty = tid >> 4;

    float acc[4][8] = {};

    for (int c = 0; c < 3; ++c) {
        {
            int idx = tid;
#pragma unroll
            for (int i = 0; i < 4; ++i, idx += 256) {
                const int co_l = idx >> 4, kq = idx & 15;
                const float4 v = *reinterpret_cast<const float4*>(
                    &W[(size_t)(co0 + co_l) * CDIM + c * 64 + kq * 4]);
                sW[kq * 4 + 0][co_l] = v.x;
                sW[kq * 4 + 1][co_l] = v.y;
                sW[kq * 4 + 2][co_l] = v.z;
                sW[kq * 4 + 3][co_l] = v.w;
            }
        }
        {
            int idx = tid;
#pragma unroll
            for (int i = 0; i < 8; ++i, idx += 256) {
                const int row = idx >> 5, cq = idx & 31;
                const float4 v = *reinterpret_cast<const float4*>(
                    &X[((size_t)b * CDIM + c * 64 + row) * HWPIX + p0 + cq * 4]);
                *reinterpret_cast<float4*>(&sX[row][cq * 4]) = v;
            }
        }
        __syncthreads();

#pragma unroll 4
        for (int k = 0; k < 64; ++k) {
            const float4 w4 = *reinterpret_cast<const float4*>(&sW[k][ty * 4]);
            const float4 xa = *reinterpret_cast<const float4*>(&sX[k][tx * 4]);
            const float4 xb = *reinterpret_cast<const float4*>(&sX[k][64 + tx * 4]);
            const float wv[4] = {w4.x, w4.y, w4.z, w4.w};
            const float xv[8] = {xa.x, xa.y, xa.z, xa.w, xb.x, xb.y, xb.z, xb.w};
#pragma unroll
            for (int i = 0; i < 4; ++i)
#pragma unroll
                for (int j = 0; j < 8; ++j) acc[i][j] = fmaf(wv[i], xv[j], acc[i][j]);
        }
        __syncthreads();
    }

#pragma unroll
    for (int i = 0; i < 4; ++i) {
        const int co = co0 + ty * 4 + i;
        const float bs = bias[co];
        const size_t base = ((size_t)b * CDIM + co) * HWPIX + p0;
        float4 o0 = {acc[i][0] + bs, acc[i][1] + bs, acc[i][2] + bs, acc[i][3] + bs};
        float4 o1 = {acc[i][4] + bs, acc[i][5] + bs, acc[i][6] + bs, acc[i][7] + bs};
        *reinterpret_cast<float4*>(&Y[base + tx * 4]) = o0;
        *reinterpret_cast<float4*>(&Y[base + 64 + tx * 4]) = o1;
    }
}

// ---------------------------------------------------------------------------
// Depthwise 3x3 SAME conv — vectorized.
// ---------------------------------------------------------------------------
__global__ __launch_bounds__(256) void dwconv_kernel(
    const bf16* __restrict__ In, const float* __restrict__ Wd,
    const float* __restrict__ bd, bf16* __restrict__ Out)
{
    __shared__ alignas(16) u16 sIn[10 * 256];
    const int bc = blockIdx.y;            // b*576 + c
    const int c = bc % C3;
    const size_t base = (size_t)bc * HWPIX;
    const int r0 = blockIdx.x * 8;
    const int tid = threadIdx.x;

    for (int idx = tid; idx < 320; idx += 256) {
        const int lr = idx >> 5, ch = idx & 31;
        const int gr = r0 + lr - 1;
        uint4 v = {0u, 0u, 0u, 0u};
        if ((unsigned)gr < IMGW)
            v = *reinterpret_cast<const uint4*>(&In[base + (size_t)gr * IMGW + ch * 8]);
        *reinterpret_cast<uint4*>(&sIn[lr * 256 + ch * 8]) = v;
    }
    __syncthreads();

    float wg[9];
#pragma unroll
    for (int t = 0; t < 9; ++t) wg[t] = Wd[c * 9 + t];

    const int rr = tid >> 5;
    const int px0 = (tid & 31) * 8;
    const float bias = bd[c];
    float acc[8];
#pragma unroll
    for (int j = 0; j < 8; ++j) acc[j] = bias;

#pragma unroll
    for (int dy = 0; dy < 3; ++dy) {
        const int row = rr + dy;
        const u16* rp = &sIn[row * 256];
        const short8 mv = *reinterpret_cast<const short8*>(&rp[px0]);
        float m[8];
#pragma unroll
        for (int j = 0; j < 8; ++j) m[j] = bu2f((u16)mv[j]);
        const float lft = (px0 > 0) ? bu2f(rp[px0 - 1]) : 0.f;
        const float rgt = (px0 + 8 < 256) ? bu2f(rp[px0 + 8]) : 0.f;
        const float w0 = wg[dy * 3], w1 = wg[dy * 3 + 1], w2 = wg[dy * 3 + 2];

        acc[0] = fmaf(w0, lft, acc[0]);
        acc[0] = fmaf(w1, m[0], acc[0]);
        acc[0] = fmaf(w2, m[1], acc[0]);
#pragma unroll
        for (int j = 1; j < 7; ++j) {
            acc[j] = fmaf(w0, m[j - 1], acc[j]);
            acc[j] = fmaf(w1, m[j], acc[j]);
            acc[j] = fmaf(w2, m[j + 1], acc[j]);
        }
        acc[7] = fmaf(w0, m[6], acc[7]);
        acc[7] = fmaf(w1, m[7], acc[7]);
        acc[7] = fmaf(w2, rgt, acc[7]);
    }

    uint4 ov;
    ov.x = pack2(acc[0], acc[1]);
    ov.y = pack2(acc[2], acc[3]);
    ov.z = pack2(acc[4], acc[5]);
    ov.w = pack2(acc[6], acc[7]);
    *reinterpret_cast<uint4*>(&Out[base + (size_t)(r0 + rr) * IMGW + px0]) = ov;
}

// ---------------------------------------------------------------------------
// Local (windowed 8x8) channel attention — MFMA version.
// ---------------------------------------------------------------------------
#define CS 328          // c-row stride (u16) for sQ/sK/sV
#define PS 40           // row stride (u16) for sP

__global__ __launch_bounds__(256) void local_attn_kernel(
    const bf16* __restrict__ QKV, const float* __restrict__ temp,
    float* __restrict__ Osum)
{
    __shared__ alignas(16) u16 sQ[32 * CS];
    __shared__ alignas(16) u16 sK[32 * CS];
    __shared__ alignas(16) u16 sV[32 * CS];
    __shared__ alignas(16) u16 sP[4 * 32 * PS];
    __shared__ float snq[4 * 32], snk[4 * 32];

    const int wy    = blockIdx.x >> 3;     // window row 0..31
    const int strip = blockIdx.x & 7;      // 4-window strip 0..7
    const int head  = blockIdx.y;
    const int b     = blockIdx.z;
    const int x0    = strip * 32;
    const int tid   = threadIdx.x;
    const int w     = tid >> 6;            // wave = window 0..3
    const int lane  = tid & 63;
    const int r     = lane & 15;
    const int hk    = lane >> 4;

#pragma unroll
    for (int i = 0; i < 9; ++i) {
        const int idx = tid + i * 256;       // 0..2303
        const int tensor = idx / 768;
        const int rem = idx - tensor * 768;
        const int c  = rem >> 5;
        const int rw = (rem >> 2) & 7;
        const int ch = rem & 3;
        const size_t g = ((size_t)b * C3 + tensor * CDIM + head * CPH + c) * HWPIX
                       + (size_t)(wy * 8 + rw) * IMGW + x0 + ch * 8;
        const uint4 v = *reinterpret_cast<const uint4*>(&QKV[g]);
        u16* dst = (tensor == 0) ? sQ : ((tensor == 1) ? sK : sV);
        *reinterpret_cast<uint4*>(&dst[c * CS + rw * 40 + ch * 8]) = v;
    }
    __syncthreads();

    if (tid < 192) {
        const int qk = tid / 96;
        const int rem = tid - qk * 96;
        const int ww = rem / 24, c = rem % 24;
        const u16* sT = qk ? sK : sQ;
        const int off = c * CS + ww * 8;
        float s = 0.f;
#pragma unroll
        for (int rw = 0; rw < 8; ++rw) {
            const short8 v = *reinterpret_cast<const short8*>(&sT[off + rw * 40]);
#pragma unroll
            for (int j = 0; j < 8; ++j) {
                const float f = bu2f((u16)v[j]);
                s = fmaf(f, f, s);
            }
        }
        const float inv = 1.f / fmaxf(sqrtf(s), 1e-12f);
        if (qk) snk[ww * 32 + c] = inv; else snq[ww * 32 + c] = inv;
    }
    __syncthreads();

    f32x4 accg[2][2];
#pragma unroll
    for (int i = 0; i < 2; ++i)
#pragma unroll
        for (int j = 0; j < 2; ++j) accg[i][j] = (f32x4){0.f, 0.f, 0.f, 0.f};

#pragma unroll
    for (int kk = 0; kk < 2; ++kk) {
        const int colA = (kk * 4 + hk) * 40 + w * 8;
        const short8 aq0 = *reinterpret_cast<const short8*>(&sQ[(r     ) * CS + colA]);
        const short8 aq1 = *reinterpret_cast<const short8*>(&sQ[(16 + r) * CS + colA]);
        const short8 bk0 = *reinterpret_cast<const short8*>(&sK[(r     ) * CS + colA]);
        const short8 bk1 = *reinterpret_cast<const short8*>(&sK[(16 + r) * CS + colA]);
        accg[0][0] = __builtin_amdgcn_mfma_f32_16x16x32_bf16(aq0, bk0, accg[0][0], 0, 0, 0);
        accg[0][1] = __builtin_amdgcn_mfma_f32_16x16x32_bf16(aq0, bk1, accg[0][1], 0, 0, 0);
        accg[1][0] = __builtin_amdgcn_mfma_f32_16x16x32_bf16(aq1, bk0, accg[1][0], 0, 0, 0);
        accg[1][1] = __builtin_amdgcn_mfma_f32_16x16x32_bf16(aq1, bk1, accg[1][1], 0, 0, 0);
    }

    const float t = temp[head];
    const int e0 = lane & 15;
    const bool v1 = e0 < 8;
    const float ink0 = snk[w * 32 + e0];
    const float ink1 = snk[w * 32 + 16 + e0];

#pragma unroll
    for (int ct = 0; ct < 2; ++ct) {
#pragma unroll
        for (int j = 0; j < 4; ++j) {
            const int cidx = ct * 16 + hk * 4 + j;
            const float inq = snq[w * 32 + cidx];
            const float g0 = accg[ct][0][j] * inq * ink0 * t;
            const float g1 = v1 ? accg[ct][1][j] * inq * ink1 * t : -1e30f;
            float m = fmaxf(g0, g1);
#pragma unroll
            for (int mk = 8; mk >= 1; mk >>= 1) m = fmaxf(m, __shfl_xor(m, mk));
            const float p0 = __expf(g0 - m);
            const float p1 = v1 ? __expf(g1 - m) : 0.f;
            float s = p0 + p1;
#pragma unroll
            for (int mk = 8; mk >= 1; mk >>= 1) s += __shfl_xor(s, mk);
            const float inv = 1.f / s;
            if (cidx < CPH) {
                sP[w * 32 * PS + cidx * PS + e0] = f2bu(p0 * inv);
                if (v1) sP[w * 32 * PS + cidx * PS + 16 + e0] = f2bu(p1 * inv);
            }
        }
    }
    __syncthreads();

    f32x4 acco[2][4];
#pragma unroll
    for (int i = 0; i < 2; ++i)
#pragma unroll
        for (int j = 0; j < 4; ++j) acco[i][j] = (f32x4){0.f, 0.f, 0.f, 0.f};

    short8 afr[2];
#pragma unroll
    for (int ct = 0; ct < 2; ++ct) {
        if (hk < 3)
            afr[ct] = *reinterpret_cast<const short8*>(
                &sP[w * 32 * PS + (ct * 16 + r) * PS + hk * 8]);
        else
            afr[ct] = (short8){0, 0, 0, 0, 0, 0, 0, 0};
    }
#pragma unroll
    for (int nt = 0; nt < 4; ++nt) {
        const int px = nt * 16 + r;
        const int colV = (px >> 3) * 40 + w * 8 + (px & 7);
        short8 bfr;
        if (hk < 3) {
#pragma unroll
            for (int j = 0; j < 8; ++j)
                bfr[j] = (short)sV[(hk * 8 + j) * CS + colV];
        } else {
            bfr = (short8){0, 0, 0, 0, 0, 0, 0, 0};
        }
        acco[0][nt] = __builtin_amdgcn_mfma_f32_16x16x32_bf16(afr[0], bfr, acco[0][nt], 0, 0, 0);
        acco[1][nt] = __builtin_amdgcn_mfma_f32_16x16x32_bf16(afr[1], bfr, acco[1][nt], 0, 0, 0);
    }

    const size_t ob = ((size_t)b * CDIM + head * CPH) * HWPIX;
#pragma unroll
    for (int ct = 0; ct < 2; ++ct) {
#pragma unroll
        for (int j = 0; j < 4; ++j) {
            const int cidx = ct * 16 + hk * 4 + j;
            if (cidx >= CPH) continue;
#pragma unroll
            for (int nt = 0; nt < 4; ++nt) {
                const int px = nt * 16 + r;
                const int rpx = px >> 3, pxl = px & 7;
                Osum[ob + (size_t)cidx * HWPIX
                     + (size_t)(wy * 8 + rpx) * IMGW + x0 + w * 8 + pxl] = acco[ct][nt][j];
            }
        }
    }
}

// ---------------------------------------------------------------------------
// Global branch stats (staging vectorized).
// ---------------------------------------------------------------------------
__global__ __launch_bounds__(256) void gstats_kernel(
    const bf16* __restrict__ QKV, float* __restrict__ Gp)
{
    __shared__ float sq[CPH][260];
    __shared__ float sk[CPH][260];
    const int chunk = blockIdx.x;
    const int bh = blockIdx.y;
    const int b = bh >> 3, head = bh & 7;
    const int tid = threadIdx.x;
    const size_t qb = ((size_t)b * C3 + head * CPH) * HWPIX;
    const size_t kb = qb + (size_t)CDIM * HWPIX;

    float a00 = 0.f, a01 = 0.f, a10 = 0.f, a11 = 0.f;

    for (int sub = 0; sub < 8; ++sub) {
        const int d0 = chunk * 2048 + sub * 256;
        for (int idx = tid; idx < 768; idx += 256) {
            const int c = idx >> 5, ch = idx & 31;
            const uint4 vq = *reinterpret_cast<const uint4*>(&QKV[qb + (size_t)c * HWPIX + d0 + ch * 8]);
            const uint4 vk = *reinterpret_cast<const uint4*>(&QKV[kb + (size_t)c * HWPIX + d0 + ch * 8]);
            float4 q0 = {bu2f((u16)(vq.x & 0xffff)), bu2f((u16)(vq.x >> 16)),
                         bu2f((u16)(vq.y & 0xffff)), bu2f((u16)(vq.y >> 16))};
            float4 q1 = {bu2f((u16)(vq.z & 0xffff)), bu2f((u16)(vq.z >> 16)),
                         bu2f((u16)(vq.w & 0xffff)), bu2f((u16)(vq.w >> 16))};
            float4 k0 = {bu2f((u16)(vk.x & 0xffff)), bu2f((u16)(vk.x >> 16)),
                         bu2f((u16)(vk.y & 0xffff)), bu2f((u16)(vk.y >> 16))};
            float4 k1 = {bu2f((u16)(vk.z & 0xffff)), bu2f((u16)(vk.z >> 16)),
                         bu2f((u16)(vk.w & 0xffff)), bu2f((u16)(vk.w >> 16))};
            *reinterpret_cast<float4*>(&sq[c][ch * 8]) = q0;
            *reinterpret_cast<float4*>(&sq[c][ch * 8 + 4]) = q1;
            *reinterpret_cast<float4*>(&sk[c][ch * 8]) = k0;
            *reinterpret_cast<float4*>(&sk[c][ch * 8 + 4]) = k1;
        }
        __syncthreads();

        if (tid < 144) {
            const int c0 = (tid / 12) * 2, e0 = (tid % 12) * 2;
            const float* q0 = sq[c0]; const float* q1 = sq[c0 + 1];
            const float* k0 = sk[e0]; const float* k1 = sk[e0 + 1];
#pragma unroll 4
            for (int dd = 0; dd < 256; ++dd) {
                const float x0 = q0[dd], x1 = q1[dd];
                const float y0 = k0[dd], y1 = k1[dd];
                a00 = fmaf(x0, y0, a00); a01 = fmaf(x0, y1, a01);
                a10 = fmaf(x1, y0, a10); a11 = fmaf(x1, y1, a11);
            }
        } else if (tid < 168) {
            const float* rr = sq[tid - 144];
#pragma unroll 4
            for (int dd = 0; dd < 256; ++dd) a00 = fmaf(rr[dd], rr[dd], a00);
        } else if (tid < 192) {
            const float* rr = sk[tid - 168];
#pragma unroll 4
            for (int dd = 0; dd < 256; ++dd) a00 = fmaf(rr[dd], rr[dd], a00);
        }
        __syncthreads();
    }

    float* dst = Gp + ((size_t)bh * 32 + chunk) * 624;
    if (tid < 144) {
        const int c0 = (tid / 12) * 2, e0 = (tid % 12) * 2;
        dst[(c0    ) * CPH + e0    ] = a00;
        dst[(c0    ) * CPH + e0 + 1] = a01;
        dst[(c0 + 1) * CPH + e0    ] = a10;
        dst[(c0 + 1) * CPH + e0 + 1] = a11;
    } else if (tid < 168) {
        dst[576 + (tid - 144)] = a00;
    } else if (tid < 192) {
        dst[600 + (tid - 168)] = a00;
    }
}

// ---------------------------------------------------------------------------
__global__ __launch_bounds__(64) void gsoftmax_kernel(
    const float* __restrict__ Gp, const float* __restrict__ temp,
    float* __restrict__ A)
{
    __shared__ float red[624];
    const int bh = blockIdx.x, head = bh & 7;
    const int tid = threadIdx.x;

    for (int jj = tid; jj < 624; jj += 64) {
        float s = 0.f;
        for (int ch = 0; ch < 32; ++ch) s += Gp[((size_t)bh * 32 + ch) * 624 + jj];
        red[jj] = s;
    }
    __syncthreads();

    if (tid < CPH) {
        const int c = tid;
        const float t = temp[head];
        const float inq = 1.f / fmaxf(sqrtf(red[576 + c]), 1e-12f);
        float l[CPH]; float m = -1e30f;
        for (int e = 0; e < CPH; ++e) {
            const float ink = 1.f / fmaxf(sqrtf(red[600 + e]), 1e-12f);
            l[e] = red[c * CPH + e] * inq * ink * t;
            m = fmaxf(m, l[e]);
        }
        float s = 0.f;
        for (int e = 0; e < CPH; ++e) { l[e] = expf(l[e] - m); s += l[e]; }
        const float inv = 1.f / s;
        for (int e = 0; e < CPH; ++e) A[(size_t)bh * 576 + c * CPH + e] = l[e] * inv;
    }
}

// ---------------------------------------------------------------------------
__global__ __launch_bounds__(256) void gapply_kernel(
    const bf16* __restrict__ QKV, const float* __restrict__ A,
    float* __restrict__ Osum)
{
    __shared__ float sA[576];
    const int bh = blockIdx.y;
    const int b = bh >> 3, head = bh & 7;
    const int d = blockIdx.x * 256 + threadIdx.x;

    for (int idx = threadIdx.x; idx < 576; idx += 256) sA[idx] = A[(size_t)bh * 576 + idx];
    __syncthreads();

    const size_t vb = ((size_t)b * C3 + 2 * CDIM + head * CPH) * HWPIX;
    const size_t ob = ((size_t)b * CDIM + head * CPH) * HWPIX;

    float v[CPH];
#pragma unroll
    for (int e = 0; e < CPH; ++e) v[e] = b2f(QKV[vb + (size_t)e * HWPIX + d]);

#pragma unroll 4
    for (int c = 0; c < CPH; ++c) {
        float acc = Osum[ob + (size_t)c * HWPIX + d];
        const float* Ar = &sA[c * CPH];
#pragma unroll
        for (int e = 0; e < CPH; ++e) acc = fmaf(Ar[e], v[e], acc);
        Osum[ob + (size_t)c * HWPIX + d] = acc;
    }
}

// ---------------------------------------------------------------------------
extern "C" void kernel_launch(void* const* d_in, const int* in_sizes, int n_in,
                              void* d_out, int out_size, void* d_ws, size_t ws_size,
                              hipStream_t stream) {
    const float* x           = (const float*)d_in[0];
    const float* temperature = (const float*)d_in[1];
    const float* qkv_w       = (const float*)d_in[2];
    const float* qkv_b       = (const float*)d_in[3];
    const float* dw_w        = (const float*)d_in[4];
    const float* dw_b        = (const float*)d_in[5];
    const float* proj_w      = (const float*)d_in[6];
    const float* proj_b      = (const float*)d_in[7];
    float* out = (float*)d_out;

    char* ws = (char*)d_ws;
    constexpr size_t QKV_ELEMS = (size_t)NBATCH * C3 * HWPIX;
    constexpr size_t QKV_BYTES = QKV_ELEMS * sizeof(bf16);

    bf16* qkv1 = (bf16*)ws;                       // conv1x1 out (bf16)
    bf16* qkv2 = (bf16*)(ws + QKV_BYTES);         // q,k,v after depthwise (bf16)
    float* osum = (float*)ws;                     // overlays qkv1 (dead after dw)
    float* Gp   = (float*)(ws + 2 * QKV_BYTES);   // 32*32*624 f32 partials
    float* Amat = Gp + (size_t)32 * 32 * 624;     // 32*576 f32
    u16*  Wb    = (u16*)Gp;                       // bf16 weights; dead before gstats

    // 0. weights f32 -> bf16
    prep_weights<<<(C3 * CDIM + 255) / 256, 256, 0, stream>>>(qkv_w, Wb, C3 * CDIM);

    // 1. qkv = 1x1 conv via MFMA (f32 in, bf16 out)
    conv_qkv_mfma<<<9 * 512 * NBATCH, 256, 0, stream>>>(x, Wb, qkv_b, qkv1);

    // 2. depthwise 3x3 (vectorized)
    dwconv_kernel<<<dim3(32, NBATCH * C3), 256, 0, stream>>>(
        qkv1, dw_w, dw_b, qkv2);

    // 3. local windowed attention (MFMA) -> writes all of osum (o1)
    local_attn_kernel<<<dim3(256, NHEADS, NBATCH), 256, 0, stream>>>(
        qkv2, temperature, osum);

    // 4. global Gram/norm partials
    gstats_kernel<<<dim3(32, 32), 256, 0, stream>>>(qkv2, Gp);

    // 5. reduce + softmax -> A
    gsoftmax_kernel<<<32, 64, 0, stream>>>(Gp, temperature, Amat);

    // 6. apply global attention, add into osum
    gapply_kernel<<<dim3(HWPIX / 256, 32), 256, 0, stream>>>(qkv2, Amat, osum);

    // 7. proj 1x1 conv (f32 -> f32 out)
    conv_proj_f32<<<3 * 512 * NBATCH, 256, 0, stream>>>(osum, proj_w, proj_b, out);
}

// Round 6
// 969.667 us; speedup vs baseline: 4.1611x; 1.1608x over previous
//
#include <hip/hip_runtime.h>
#include <hip/hip_bf16.h>
#include <cstdint>
#include <cstddef>

#define HWPIX 65536
#define IMGW 256
#define CDIM 192
#define C3 576
#define NBATCH 4
#define NHEADS 8
#define CPH 24
#define KP 104   // padded K pitch (bf16 elems) for MFMA LDS tiles

using bf16 = __hip_bfloat16;
typedef __attribute__((ext_vector_type(8))) short short8;
typedef __attribute__((ext_vector_type(4))) float f32x4;
typedef unsigned int u32;
typedef unsigned short u16;

__device__ __forceinline__ float b2f(bf16 v) { return __bfloat162float(v); }
__device__ __forceinline__ bf16 f2b(float v) { return __float2bfloat16(v); }
__device__ __forceinline__ float bu2f(u16 h) { return __uint_as_float((u32)h << 16); }
__device__ __forceinline__ u16 f2bu(float x) {
    bf16 h = __float2bfloat16(x);
    return *reinterpret_cast<u16*>(&h);
}
__device__ __forceinline__ u32 pack2(float a, float b) {
    return (u32)f2bu(a) | ((u32)f2bu(b) << 16);
}

// ---------------------------------------------------------------------------
// Convert weights f32 -> bf16 (u16).
// ---------------------------------------------------------------------------
__global__ __launch_bounds__(256) void prep_weights(
    const float* __restrict__ W, u16* __restrict__ Wb, int n)
{
    int i = blockIdx.x * 256 + threadIdx.x;
    if (i < n) Wb[i] = f2bu(W[i]);
}

// ---------------------------------------------------------------------------
// X f32 [b][k][p] -> Xt bf16 [b][p][k]  (one-time transpose+convert).
// Block: (p-tile 64) x b.  LDS f32 [192][68] staged coalesced, column reads
// (~4-way banks, LDS not the bottleneck), packed uint4 row writes.
// ---------------------------------------------------------------------------
__global__ __launch_bounds__(256) void xprep_kernel(
    const float* __restrict__ X, u16* __restrict__ Xt)
{
    __shared__ float sX[CDIM * 68];
    const int b  = blockIdx.y;
    const int p0 = blockIdx.x * 64;
    const int tid = threadIdx.x;

#pragma unroll
    for (int i = 0; i < 12; ++i) {
        const int idx = tid + i * 256;        // 0..3071 float4s
        const int p4 = idx & 15, k = idx >> 4;
        const float4 v = *reinterpret_cast<const float4*>(
            X + ((size_t)b * CDIM + k) * HWPIX + p0 + p4 * 4);
        *reinterpret_cast<float4*>(&sX[k * 68 + p4 * 4]) = v;
    }
    __syncthreads();

    const int p = tid >> 2;          // 0..63
    const int seg = tid & 3;         // 0..3 (6 k-blocks each)
    u16* dst = Xt + ((size_t)b * HWPIX + p0 + p) * CDIM;
#pragma unroll
    for (int s = 0; s < 6; ++s) {
        const int blk = seg * 6 + s; // 0..23, 8 k each
        float f[8];
#pragma unroll
        for (int j = 0; j < 8; ++j) f[j] = sX[(blk * 8 + j) * 68 + p];
        uint4 ov;
        ov.x = pack2(f[0], f[1]);
        ov.y = pack2(f[2], f[3]);
        ov.z = pack2(f[4], f[5]);
        ov.w = pack2(f[6], f[7]);
        *reinterpret_cast<uint4*>(dst + blk * 8) = ov;
    }
}

// ---------------------------------------------------------------------------
// qkv 1x1 conv as bf16 MFMA GEMM, reading pre-transposed Xt.
// Staging = pure uint4 copies (no VALU pack, no swizzle needed).
// ---------------------------------------------------------------------------
__global__ __launch_bounds__(256, 4) void conv_qkv_mfma(
    const u16* __restrict__ Xt, const u16* __restrict__ Wb,
    const float* __restrict__ bias, bf16* __restrict__ Y)
{
    __shared__ alignas(16) u16 sA[64 * KP];
    __shared__ alignas(16) u16 sB[128 * KP];
    __shared__ float sBias[64];

    int lin = blockIdx.x;
    lin = (lin & 7) * (18432 / 8) + (lin >> 3);
    const int co_t = lin % 9;
    const int rest = lin / 9;
    const int p_t = rest & 511;
    const int b   = rest >> 9;
    const int co0 = co_t * 64;
    const int p0  = p_t * 128;

    const int tid  = threadIdx.x;
    const int wave = tid >> 6;
    const int lane = tid & 63;
    const int r  = lane & 15;
    const int hk = lane >> 4;

    if (tid < 64) sBias[tid] = bias[co0 + tid];

    f32x4 acc[4][2];
#pragma unroll
    for (int i = 0; i < 4; ++i)
#pragma unroll
        for (int j = 0; j < 2; ++j) acc[i][j] = (f32x4){0.f, 0.f, 0.f, 0.f};

#pragma unroll
    for (int c = 0; c < 2; ++c) {
        // ---- stage A: 64 co-rows x 96 k  (768 uint4, 3/thread)
        {
            int idx = tid;
#pragma unroll
            for (int i = 0; i < 3; ++i, idx += 256) {
                const int row = idx / 12, cv = idx % 12;
                const uint4 v = *reinterpret_cast<const uint4*>(
                    Wb + (size_t)(co0 + row) * CDIM + c * 96 + cv * 8);
                *reinterpret_cast<uint4*>(&sA[row * KP + cv * 8]) = v;
            }
        }
        // ---- stage B: 128 p-rows x 96 k (1536 uint4, 6/thread) — pure copy
        {
            int idx = tid;
#pragma unroll
            for (int i = 0; i < 6; ++i, idx += 256) {
                const int row = idx / 12, cv = idx % 12;
                const uint4 v = *reinterpret_cast<const uint4*>(
                    Xt + ((size_t)b * HWPIX + p0 + row) * CDIM + c * 96 + cv * 8);
                *reinterpret_cast<uint4*>(&sB[row * KP + cv * 8]) = v;
            }
        }
        __syncthreads();

#pragma unroll
        for (int ks = 0; ks < 3; ++ks) {
            const int kof = ks * 32 + hk * 8;
            const u16* pA = &sA[r * KP + kof];
            const u16* pB = &sB[(wave * 32 + r) * KP + kof];
            const short8 a0 = *reinterpret_cast<const short8*>(pA);
            const short8 a1 = *reinterpret_cast<const short8*>(pA + 16 * KP);
            const short8 a2 = *reinterpret_cast<const short8*>(pA + 32 * KP);
            const short8 a3 = *reinterpret_cast<const short8*>(pA + 48 * KP);
            const short8 b0 = *reinterpret_cast<const short8*>(pB);
            const short8 b1 = *reinterpret_cast<const short8*>(pB + 16 * KP);
            acc[0][0] = __builtin_amdgcn_mfma_f32_16x16x32_bf16(a0, b0, acc[0][0], 0, 0, 0);
            acc[1][0] = __builtin_amdgcn_mfma_f32_16x16x32_bf16(a1, b0, acc[1][0], 0, 0, 0);
            acc[2][0] = __builtin_amdgcn_mfma_f32_16x16x32_bf16(a2, b0, acc[2][0], 0, 0, 0);
            acc[3][0] = __builtin_amdgcn_mfma_f32_16x16x32_bf16(a3, b0, acc[3][0], 0, 0, 0);
            acc[0][1] = __builtin_amdgcn_mfma_f32_16x16x32_bf16(a0, b1, acc[0][1], 0, 0, 0);
            acc[1][1] = __builtin_amdgcn_mfma_f32_16x16x32_bf16(a1, b1, acc[1][1], 0, 0, 0);
            acc[2][1] = __builtin_amdgcn_mfma_f32_16x16x32_bf16(a2, b1, acc[2][1], 0, 0, 0);
            acc[3][1] = __builtin_amdgcn_mfma_f32_16x16x32_bf16(a3, b1, acc[3][1], 0, 0, 0);
        }
        __syncthreads();
    }

    // ---- epilogue: acc -> bf16 LDS tile [64co][128p] -> coalesced uint4 stores
    u16* sOut = sB;   // reuse (post-barrier)
#pragma unroll
    for (int mf = 0; mf < 4; ++mf) {
#pragma unroll
        for (int j = 0; j < 4; ++j) {
            const int row = mf * 16 + hk * 4 + j;
            const float bs = sBias[row];
            sOut[row * 128 + wave * 32 + r]      = f2bu(acc[mf][0][j] + bs);
            sOut[row * 128 + wave * 32 + r + 16] = f2bu(acc[mf][1][j] + bs);
        }
    }
    __syncthreads();
#pragma unroll
    for (int i = 0; i < 4; ++i) {
        const int idx = tid + i * 256;
        const int row = idx >> 4, cq = idx & 15;
        const uint4 v = *reinterpret_cast<const uint4*>(&sOut[row * 128 + cq * 8]);
        *reinterpret_cast<uint4*>(
            &Y[((size_t)b * C3 + co0 + row) * HWPIX + p0 + cq * 8]) = v;
    }
}

// ---------------------------------------------------------------------------
// proj 1x1 conv as bf16 MFMA GEMM (R4-qkv structure: f32 osum staged with
// pack2 + XOR-swizzled sB).  Output f32 direct stores (64B segments).
// Accuracy: bf16 rounding of osum/W adds ~1e-5 absmax (output scale ~0.01).
// ---------------------------------------------------------------------------
__global__ __launch_bounds__(256, 4) void conv_proj_mfma(
    const float* __restrict__ X, const u16* __restrict__ Wb,
    const float* __restrict__ bias, float* __restrict__ Y)
{
    __shared__ alignas(16) u16 sA[64 * KP];
    __shared__ alignas(16) u16 sB[128 * KP];
    __shared__ float sBias[64];

    int lin = blockIdx.x;                       // nwg = 6144
    lin = (lin & 7) * (6144 / 8) + (lin >> 3);
    const int co_t = lin % 3;
    const int rest = lin / 3;
    const int p_t = rest & 511;
    const int b   = rest >> 9;
    const int co0 = co_t * 64;
    const int p0  = p_t * 128;

    const int tid  = threadIdx.x;
    const int wave = tid >> 6;
    const int lane = tid & 63;
    const int r  = lane & 15;
    const int hk = lane >> 4;

    if (tid < 64) sBias[tid] = bias[co0 + tid];

    f32x4 acc[4][2];
#pragma unroll
    for (int i = 0; i < 4; ++i)
#pragma unroll
        for (int j = 0; j < 2; ++j) acc[i][j] = (f32x4){0.f, 0.f, 0.f, 0.f};

    const int kp_lane = tid & 7;
    const int p4      = tid >> 3;

#pragma unroll
    for (int c = 0; c < 2; ++c) {
        {
            int idx = tid;
#pragma unroll
            for (int i = 0; i < 3; ++i, idx += 256) {
                const int row = idx / 12, cv = idx % 12;
                const uint4 v = *reinterpret_cast<const uint4*>(
                    Wb + (size_t)(co0 + row) * CDIM + c * 96 + cv * 8);
                *reinterpret_cast<uint4*>(&sA[row * KP + cv * 8]) = v;
            }
        }
        {
            const float* Xc = X + ((size_t)b * CDIM + c * 96) * HWPIX + p0;
#pragma unroll
            for (int i = 0; i < 6; ++i) {
                const int kp = kp_lane + i * 8;
                const int k  = kp * 2;
                const float4 va = *reinterpret_cast<const float4*>(
                    Xc + (size_t)k * HWPIX + p4 * 4);
                const float4 vb = *reinterpret_cast<const float4*>(
                    Xc + (size_t)(k + 1) * HWPIX + p4 * 4);
                const int col = (((k >> 3) ^ (p4 & 3)) << 3) | (k & 7);
                const float av[4] = {va.x, va.y, va.z, va.w};
                const float bv[4] = {vb.x, vb.y, vb.z, vb.w};
#pragma unroll
                for (int j = 0; j < 4; ++j) {
                    const int row = p4 * 4 + j;
                    *reinterpret_cast<u32*>(&sB[row * KP + col]) = pack2(av[j], bv[j]);
                }
            }
        }
        __syncthreads();

#pragma unroll
        for (int ks = 0; ks < 3; ++ks) {
            const int kof = ks * 32 + hk * 8;
            const u16* pA = &sA[r * KP + kof];
            const int rowb = wave * 32 + r;
            const int colr = (((kof >> 3) ^ ((rowb >> 2) & 3)) << 3);
            const u16* pB = &sB[rowb * KP + colr];
            const short8 a0 = *reinterpret_cast<const short8*>(pA);
            const short8 a1 = *reinterpret_cast<const short8*>(pA + 16 * KP);
            const short8 a2 = *reinterpret_cast<const short8*>(pA + 32 * KP);
            const short8 a3 = *reinterpret_cast<const short8*>(pA + 48 * KP);
            const short8 b0 = *reinterpret_cast<const short8*>(pB);
            const short8 b1 = *reinterpret_cast<const short8*>(pB + 16 * KP);
            acc[0][0] = __builtin_amdgcn_mfma_f32_16x16x32_bf16(a0, b0, acc[0][0], 0, 0, 0);
            acc[1][0] = __builtin_amdgcn_mfma_f32_16x16x32_bf16(a1, b0, acc[1][0], 0, 0, 0);
            acc[2][0] = __builtin_amdgcn_mfma_f32_16x16x32_bf16(a2, b0, acc[2][0], 0, 0, 0);
            acc[3][0] = __builtin_amdgcn_mfma_f32_16x16x32_bf16(a3, b0, acc[3][0], 0, 0, 0);
            acc[0][1] = __builtin_amdgcn_mfma_f32_16x16x32_bf16(a0, b1, acc[0][1], 0, 0, 0);
            acc[1][1] = __builtin_amdgcn_mfma_f32_16x16x32_bf16(a1, b1, acc[1][1], 0, 0, 0);
            acc[2][1] = __builtin_amdgcn_mfma_f32_16x16x32_bf16(a2, b1, acc[2][1], 0, 0, 0);
            acc[3][1] = __builtin_amdgcn_mfma_f32_16x16x32_bf16(a3, b1, acc[3][1], 0, 0, 0);
        }
        __syncthreads();
    }

    // ---- epilogue: f32 stores, 16-lane groups are 64B contiguous
#pragma unroll
    for (int mf = 0; mf < 4; ++mf) {
#pragma unroll
        for (int j = 0; j < 4; ++j) {
            const int co = co0 + mf * 16 + hk * 4 + j;
            const float bs = sBias[mf * 16 + hk * 4 + j];
            const size_t base = ((size_t)b * CDIM + co) * HWPIX + p0 + wave * 32 + r;
            Y[base]      = acc[mf][0][j] + bs;
            Y[base + 16] = acc[mf][1][j] + bs;
        }
    }
}

// ---------------------------------------------------------------------------
// Depthwise 3x3 SAME conv — vectorized.
// ---------------------------------------------------------------------------
__global__ __launch_bounds__(256) void dwconv_kernel(
    const bf16* __restrict__ In, const float* __restrict__ Wd,
    const float* __restrict__ bd, bf16* __restrict__ Out)
{
    __shared__ alignas(16) u16 sIn[10 * 256];
    const int bc = blockIdx.y;            // b*576 + c
    const int c = bc % C3;
    const size_t base = (size_t)bc * HWPIX;
    const int r0 = blockIdx.x * 8;
    const int tid = threadIdx.x;

    for (int idx = tid; idx < 320; idx += 256) {
        const int lr = idx >> 5, ch = idx & 31;
        const int gr = r0 + lr - 1;
        uint4 v = {0u, 0u, 0u, 0u};
        if ((unsigned)gr < IMGW)
            v = *reinterpret_cast<const uint4*>(&In[base + (size_t)gr * IMGW + ch * 8]);
        *reinterpret_cast<uint4*>(&sIn[lr * 256 + ch * 8]) = v;
    }
    __syncthreads();

    float wg[9];
#pragma unroll
    for (int t = 0; t < 9; ++t) wg[t] = Wd[c * 9 + t];

    const int rr = tid >> 5;
    const int px0 = (tid & 31) * 8;
    const float bias = bd[c];
    float acc[8];
#pragma unroll
    for (int j = 0; j < 8; ++j) acc[j] = bias;

#pragma unroll
    for (int dy = 0; dy < 3; ++dy) {
        const int row = rr + dy;
        const u16* rp = &sIn[row * 256];
        const short8 mv = *reinterpret_cast<const short8*>(&rp[px0]);
        float m[8];
#pragma unroll
        for (int j = 0; j < 8; ++j) m[j] = bu2f((u16)mv[j]);
        const float lft = (px0 > 0) ? bu2f(rp[px0 - 1]) : 0.f;
        const float rgt = (px0 + 8 < 256) ? bu2f(rp[px0 + 8]) : 0.f;
        const float w0 = wg[dy * 3], w1 = wg[dy * 3 + 1], w2 = wg[dy * 3 + 2];

        acc[0] = fmaf(w0, lft, acc[0]);
        acc[0] = fmaf(w1, m[0], acc[0]);
        acc[0] = fmaf(w2, m[1], acc[0]);
#pragma unroll
        for (int j = 1; j < 7; ++j) {
            acc[j] = fmaf(w0, m[j - 1], acc[j]);
            acc[j] = fmaf(w1, m[j], acc[j]);
            acc[j] = fmaf(w2, m[j + 1], acc[j]);
        }
        acc[7] = fmaf(w0, m[6], acc[7]);
        acc[7] = fmaf(w1, m[7], acc[7]);
        acc[7] = fmaf(w2, rgt, acc[7]);
    }

    uint4 ov;
    ov.x = pack2(acc[0], acc[1]);
    ov.y = pack2(acc[2], acc[3]);
    ov.z = pack2(acc[4], acc[5]);
    ov.w = pack2(acc[6], acc[7]);
    *reinterpret_cast<uint4*>(&Out[base + (size_t)(r0 + rr) * IMGW + px0]) = ov;
}

// ---------------------------------------------------------------------------
// Local (windowed 8x8) channel attention — MFMA version.
// ---------------------------------------------------------------------------
#define CS 328          // c-row stride (u16) for sQ/sK/sV
#define PS 40           // row stride (u16) for sP

__global__ __launch_bounds__(256) void local_attn_kernel(
    const bf16* __restrict__ QKV, const float* __restrict__ temp,
    float* __restrict__ Osum)
{
    __shared__ alignas(16) u16 sQ[32 * CS];
    __shared__ alignas(16) u16 sK[32 * CS];
    __shared__ alignas(16) u16 sV[32 * CS];
    __shared__ alignas(16) u16 sP[4 * 32 * PS];
    __shared__ float snq[4 * 32], snk[4 * 32];

    const int wy    = blockIdx.x >> 3;
    const int strip = blockIdx.x & 7;
    const int head  = blockIdx.y;
    const int b     = blockIdx.z;
    const int x0    = strip * 32;
    const int tid   = threadIdx.x;
    const int w     = tid >> 6;
    const int lane  = tid & 63;
    const int r     = lane & 15;
    const int hk    = lane >> 4;

#pragma unroll
    for (int i = 0; i < 9; ++i) {
        const int idx = tid + i * 256;
        const int tensor = idx / 768;
        const int rem = idx - tensor * 768;
        const int c  = rem >> 5;
        const int rw = (rem >> 2) & 7;
        const int ch = rem & 3;
        const size_t g = ((size_t)b * C3 + tensor * CDIM + head * CPH + c) * HWPIX
                       + (size_t)(wy * 8 + rw) * IMGW + x0 + ch * 8;
        const uint4 v = *reinterpret_cast<const uint4*>(&QKV[g]);
        u16* dst = (tensor == 0) ? sQ : ((tensor == 1) ? sK : sV);
        *reinterpret_cast<uint4*>(&dst[c * CS + rw * 40 + ch * 8]) = v;
    }
    __syncthreads();

    if (tid < 192) {
        const int qk = tid / 96;
        const int rem = tid - qk * 96;
        const int ww = rem / 24, c = rem % 24;
        const u16* sT = qk ? sK : sQ;
        const int off = c * CS + ww * 8;
        float s = 0.f;
#pragma unroll
        for (int rw = 0; rw < 8; ++rw) {
            const short8 v = *reinterpret_cast<const short8*>(&sT[off + rw * 40]);
#pragma unroll
            for (int j = 0; j < 8; ++j) {
                const float f = bu2f((u16)v[j]);
                s = fmaf(f, f, s);
            }
        }
        const float inv = 1.f / fmaxf(sqrtf(s), 1e-12f);
        if (qk) snk[ww * 32 + c] = inv; else snq[ww * 32 + c] = inv;
    }
    __syncthreads();

    f32x4 accg[2][2];
#pragma unroll
    for (int i = 0; i < 2; ++i)
#pragma unroll
        for (int j = 0; j < 2; ++j) accg[i][j] = (f32x4){0.f, 0.f, 0.f, 0.f};

#pragma unroll
    for (int kk = 0; kk < 2; ++kk) {
        const int colA = (kk * 4 + hk) * 40 + w * 8;
        const short8 aq0 = *reinterpret_cast<const short8*>(&sQ[(r     ) * CS + colA]);
        const short8 aq1 = *reinterpret_cast<const short8*>(&sQ[(16 + r) * CS + colA]);
        const short8 bk0 = *reinterpret_cast<const short8*>(&sK[(r     ) * CS + colA]);
        const short8 bk1 = *reinterpret_cast<const short8*>(&sK[(16 + r) * CS + colA]);
        accg[0][0] = __builtin_amdgcn_mfma_f32_16x16x32_bf16(aq0, bk0, accg[0][0], 0, 0, 0);
        accg[0][1] = __builtin_amdgcn_mfma_f32_16x16x32_bf16(aq0, bk1, accg[0][1], 0, 0, 0);
        accg[1][0] = __builtin_amdgcn_mfma_f32_16x16x32_bf16(aq1, bk0, accg[1][0], 0, 0, 0);
        accg[1][1] = __builtin_amdgcn_mfma_f32_16x16x32_bf16(aq1, bk1, accg[1][1], 0, 0, 0);
    }

    const float t = temp[head];
    const int e0 = lane & 15;
    const bool v1 = e0 < 8;
    const float ink0 = snk[w * 32 + e0];
    const float ink1 = snk[w * 32 + 16 + e0];

#pragma unroll
    for (int ct = 0; ct < 2; ++ct) {
#pragma unroll
        for (int j = 0; j < 4; ++j) {
            const int cidx = ct * 16 + hk * 4 + j;
            const float inq = snq[w * 32 + cidx];
            const float g0 = accg[ct][0][j] * inq * ink0 * t;
            const float g1 = v1 ? accg[ct][1][j] * inq * ink1 * t : -1e30f;
            float m = fmaxf(g0, g1);
#pragma unroll
            for (int mk = 8; mk >= 1; mk >>= 1) m = fmaxf(m, __shfl_xor(m, mk));
            const float p0 = __expf(g0 - m);
            const float p1 = v1 ? __expf(g1 - m) : 0.f;
            float s = p0 + p1;
#pragma unroll
            for (int mk = 8; mk >= 1; mk >>= 1) s += __shfl_xor(s, mk);
            const float inv = 1.f / s;
            if (cidx < CPH) {
                sP[w * 32 * PS + cidx * PS + e0] = f2bu(p0 * inv);
                if (v1) sP[w * 32 * PS + cidx * PS + 16 + e0] = f2bu(p1 * inv);
            }
        }
    }
    __syncthreads();

    f32x4 acco[2][4];
#pragma unroll
    for (int i = 0; i < 2; ++i)
#pragma unroll
        for (int j = 0; j < 4; ++j) acco[i][j] = (f32x4){0.f, 0.f, 0.f, 0.f};

    short8 afr[2];
#pragma unroll
    for (int ct = 0; ct < 2; ++ct) {
        if (hk < 3)
            afr[ct] = *reinterpret_cast<const short8*>(
                &sP[w * 32 * PS + (ct * 16 + r) * PS + hk * 8]);
        else
            afr[ct] = (short8){0, 0, 0, 0, 0, 0, 0, 0};
    }
#pragma unroll
    for (int nt = 0; nt < 4; ++nt) {
        const int px = nt * 16 + r;
        const int colV = (px >> 3) * 40 + w * 8 + (px & 7);
        short8 bfr;
        if (hk < 3) {
#pragma unroll
            for (int j = 0; j < 8; ++j)
                bfr[j] = (short)sV[(hk * 8 + j) * CS + colV];
        } else {
            bfr = (short8){0, 0, 0, 0, 0, 0, 0, 0};
        }
        acco[0][nt] = __builtin_amdgcn_mfma_f32_16x16x32_bf16(afr[0], bfr, acco[0][nt], 0, 0, 0);
        acco[1][nt] = __builtin_amdgcn_mfma_f32_16x16x32_bf16(afr[1], bfr, acco[1][nt], 0, 0, 0);
    }

    const size_t ob = ((size_t)b * CDIM + head * CPH) * HWPIX;
#pragma unroll
    for (int ct = 0; ct < 2; ++ct) {
#pragma unroll
        for (int j = 0; j < 4; ++j) {
            const int cidx = ct * 16 + hk * 4 + j;
            if (cidx >= CPH) continue;
#pragma unroll
            for (int nt = 0; nt < 4; ++nt) {
                const int px = nt * 16 + r;
                const int rpx = px >> 3, pxl = px & 7;
                Osum[ob + (size_t)cidx * HWPIX
                     + (size_t)(wy * 8 + rpx) * IMGW + x0 + w * 8 + pxl] = acco[ct][nt][j];
            }
        }
    }
}

// ---------------------------------------------------------------------------
// Global branch stats.
// ---------------------------------------------------------------------------
__global__ __launch_bounds__(256) void gstats_kernel(
    const bf16* __restrict__ QKV, float* __restrict__ Gp)
{
    __shared__ float sq[CPH][260];
    __shared__ float sk[CPH][260];
    const int chunk = blockIdx.x;
    const int bh = blockIdx.y;
    const int b = bh >> 3, head = bh & 7;
    const int tid = threadIdx.x;
    const size_t qb = ((size_t)b * C3 + head * CPH) * HWPIX;
    const size_t kb = qb + (size_t)CDIM * HWPIX;

    float a00 = 0.f, a01 = 0.f, a10 = 0.f, a11 = 0.f;

    for (int sub = 0; sub < 8; ++sub) {
        const int d0 = chunk * 2048 + sub * 256;
        for (int idx = tid; idx < 768; idx += 256) {
            const int c = idx >> 5, ch = idx & 31;
            const uint4 vq = *reinterpret_cast<const uint4*>(&QKV[qb + (size_t)c * HWPIX + d0 + ch * 8]);
            const uint4 vk = *reinterpret_cast<const uint4*>(&QKV[kb + (size_t)c * HWPIX + d0 + ch * 8]);
            float4 q0 = {bu2f((u16)(vq.x & 0xffff)), bu2f((u16)(vq.x >> 16)),
                         bu2f((u16)(vq.y & 0xffff)), bu2f((u16)(vq.y >> 16))};
            float4 q1 = {bu2f((u16)(vq.z & 0xffff)), bu2f((u16)(vq.z >> 16)),
                         bu2f((u16)(vq.w & 0xffff)), bu2f((u16)(vq.w >> 16))};
            float4 k0 = {bu2f((u16)(vk.x & 0xffff)), bu2f((u16)(vk.x >> 16)),
                         bu2f((u16)(vk.y & 0xffff)), bu2f((u16)(vk.y >> 16))};
            float4 k1 = {bu2f((u16)(vk.z & 0xffff)), bu2f((u16)(vk.z >> 16)),
                         bu2f((u16)(vk.w & 0xffff)), bu2f((u16)(vk.w >> 16))};
            *reinterpret_cast<float4*>(&sq[c][ch * 8]) = q0;
            *reinterpret_cast<float4*>(&sq[c][ch * 8 + 4]) = q1;
            *reinterpret_cast<float4*>(&sk[c][ch * 8]) = k0;
            *reinterpret_cast<float4*>(&sk[c][ch * 8 + 4]) = k1;
        }
        __syncthreads();

        if (tid < 144) {
            const int c0 = (tid / 12) * 2, e0 = (tid % 12) * 2;
            const float* q0 = sq[c0]; const float* q1 = sq[c0 + 1];
            const float* k0 = sk[e0]; const float* k1 = sk[e0 + 1];
#pragma unroll 4
            for (int dd = 0; dd < 256; ++dd) {
                const float x0 = q0[dd], x1 = q1[dd];
                const float y0 = k0[dd], y1 = k1[dd];
                a00 = fmaf(x0, y0, a00); a01 = fmaf(x0, y1, a01);
                a10 = fmaf(x1, y0, a10); a11 = fmaf(x1, y1, a11);
            }
        } else if (tid < 168) {
            const float* rr = sq[tid - 144];
#pragma unroll 4
            for (int dd = 0; dd < 256; ++dd) a00 = fmaf(rr[dd], rr[dd], a00);
        } else if (tid < 192) {
            const float* rr = sk[tid - 168];
#pragma unroll 4
            for (int dd = 0; dd < 256; ++dd) a00 = fmaf(rr[dd], rr[dd], a00);
        }
        __syncthreads();
    }

    float* dst = Gp + ((size_t)bh * 32 + chunk) * 624;
    if (tid < 144) {
        const int c0 = (tid / 12) * 2, e0 = (tid % 12) * 2;
        dst[(c0    ) * CPH + e0    ] = a00;
        dst[(c0    ) * CPH + e0 + 1] = a01;
        dst[(c0 + 1) * CPH + e0    ] = a10;
        dst[(c0 + 1) * CPH + e0 + 1] = a11;
    } else if (tid < 168) {
        dst[576 + (tid - 144)] = a00;
    } else if (tid < 192) {
        dst[600 + (tid - 168)] = a00;
    }
}

// ---------------------------------------------------------------------------
__global__ __launch_bounds__(64) void gsoftmax_kernel(
    const float* __restrict__ Gp, const float* __restrict__ temp,
    float* __restrict__ A)
{
    __shared__ float red[624];
    const int bh = blockIdx.x, head = bh & 7;
    const int tid = threadIdx.x;

    for (int jj = tid; jj < 624; jj += 64) {
        float s = 0.f;
        for (int ch = 0; ch < 32; ++ch) s += Gp[((size_t)bh * 32 + ch) * 624 + jj];
        red[jj] = s;
    }
    __syncthreads();

    if (tid < CPH) {
        const int c = tid;
        const float t = temp[head];
        const float inq = 1.f / fmaxf(sqrtf(red[576 + c]), 1e-12f);
        float l[CPH]; float m = -1e30f;
        for (int e = 0; e < CPH; ++e) {
            const float ink = 1.f / fmaxf(sqrtf(red[600 + e]), 1e-12f);
            l[e] = red[c * CPH + e] * inq * ink * t;
            m = fmaxf(m, l[e]);
        }
        float s = 0.f;
        for (int e = 0; e < CPH; ++e) { l[e] = expf(l[e] - m); s += l[e]; }
        const float inv = 1.f / s;
        for (int e = 0; e < CPH; ++e) A[(size_t)bh * 576 + c * CPH + e] = l[e] * inv;
    }
}

// ---------------------------------------------------------------------------
__global__ __launch_bounds__(256) void gapply_kernel(
    const bf16* __restrict__ QKV, const float* __restrict__ A,
    float* __restrict__ Osum)
{
    __shared__ float sA[576];
    const int bh = blockIdx.y;
    const int b = bh >> 3, head = bh & 7;
    const int d = blockIdx.x * 256 + threadIdx.x;

    for (int idx = threadIdx.x; idx < 576; idx += 256) sA[idx] = A[(size_t)bh * 576 + idx];
    __syncthreads();

    const size_t vb = ((size_t)b * C3 + 2 * CDIM + head * CPH) * HWPIX;
    const size_t ob = ((size_t)b * CDIM + head * CPH) * HWPIX;

    float v[CPH];
#pragma unroll
    for (int e = 0; e < CPH; ++e) v[e] = b2f(QKV[vb + (size_t)e * HWPIX + d]);

#pragma unroll 4
    for (int c = 0; c < CPH; ++c) {
        float acc = Osum[ob + (size_t)c * HWPIX + d];
        const float* Ar = &sA[c * CPH];
#pragma unroll
        for (int e = 0; e < CPH; ++e) acc = fmaf(Ar[e], v[e], acc);
        Osum[ob + (size_t)c * HWPIX + d] = acc;
    }
}

// ---------------------------------------------------------------------------
extern "C" void kernel_launch(void* const* d_in, const int* in_sizes, int n_in,
                              void* d_out, int out_size, void* d_ws, size_t ws_size,
                              hipStream_t stream) {
    const float* x           = (const float*)d_in[0];
    const float* temperature = (const float*)d_in[1];
    const float* qkv_w       = (const float*)d_in[2];
    const float* qkv_b       = (const float*)d_in[3];
    const float* dw_w        = (const float*)d_in[4];
    const float* dw_b        = (const float*)d_in[5];
    const float* proj_w      = (const float*)d_in[6];
    const float* proj_b      = (const float*)d_in[7];
    float* out = (float*)d_out;

    char* ws = (char*)d_ws;
    constexpr size_t QKV_ELEMS = (size_t)NBATCH * C3 * HWPIX;
    constexpr size_t QKV_BYTES = QKV_ELEMS * sizeof(bf16);

    bf16* qkv1 = (bf16*)ws;                       // conv1x1 out (bf16)
    bf16* qkv2 = (bf16*)(ws + QKV_BYTES);         // q,k,v after depthwise (bf16)
    float* osum = (float*)ws;                     // overlays qkv1 (dead after dw)
    float* Gp   = (float*)(ws + 2 * QKV_BYTES);   // 32*32*624 f32 partials
    float* Amat = Gp + (size_t)32 * 32 * 624;     // 32*576 f32
    u16*  Wb    = (u16*)Gp;                       // qkv weights bf16; dead before gstats
    u16*  Wpb   = (u16*)(Amat + 32 * 576);        // proj weights bf16 (outside Gp/Amat)
    // Xt (bf16 [b][p][k], 100.7 MB) overlays qkv2's head: written by xprep,
    // read by conv_qkv, then dwconv overwrites qkv2 (Xt dead by then).
    u16*  Xt    = (u16*)qkv2;

    // 0. weights f32 -> bf16
    prep_weights<<<(C3 * CDIM + 255) / 256, 256, 0, stream>>>(qkv_w, Wb, C3 * CDIM);
    prep_weights<<<(CDIM * CDIM + 255) / 256, 256, 0, stream>>>(proj_w, Wpb, CDIM * CDIM);

    // 0b. X transpose+convert -> Xt
    xprep_kernel<<<dim3(HWPIX / 64, NBATCH), 256, 0, stream>>>(x, Xt);

    // 1. qkv = 1x1 conv via MFMA (bf16 Xt in, bf16 out)
    conv_qkv_mfma<<<9 * 512 * NBATCH, 256, 0, stream>>>(Xt, Wb, qkv_b, qkv1);

    // 2. depthwise 3x3 (overwrites Xt region with qkv2 — Xt dead)
    dwconv_kernel<<<dim3(32, NBATCH * C3), 256, 0, stream>>>(
        qkv1, dw_w, dw_b, qkv2);

    // 3. local windowed attention (MFMA) -> writes all of osum (o1)
    local_attn_kernel<<<dim3(256, NHEADS, NBATCH), 256, 0, stream>>>(
        qkv2, temperature, osum);

    // 4. global Gram/norm partials (overwrites Wb — dead)
    gstats_kernel<<<dim3(32, 32), 256, 0, stream>>>(qkv2, Gp);

    // 5. reduce + softmax -> A
    gsoftmax_kernel<<<32, 64, 0, stream>>>(Gp, temperature, Amat);

    // 6. apply global attention, add into osum
    gapply_kernel<<<dim3(HWPIX / 256, 32), 256, 0, stream>>>(qkv2, Amat, osum);

    // 7. proj 1x1 conv via MFMA (f32 osum staged->bf16, f32 out)
    conv_proj_mfma<<<3 * 512 * NBATCH, 256, 0, stream>>>(osum, Wpb, proj_b, out);
}

// Round 7
// 679.061 us; speedup vs baseline: 5.9419x; 1.4280x over previous
//
#include <hip/hip_runtime.h>
#include <hip/hip_bf16.h>
#include <cstdint>
#include <cstddef>

#define HWPIX 65536
#define IMGW 256
#define CDIM 192
#define C3 576
#define NBATCH 4
#define NHEADS 8
#define CPH 24
#define KP 104   // padded K pitch (bf16 elems) for MFMA LDS tiles

using bf16 = __hip_bfloat16;
typedef __attribute__((ext_vector_type(8))) short short8;
typedef __attribute__((ext_vector_type(4))) float f32x4;
typedef unsigned int u32;
typedef unsigned short u16;

__device__ __forceinline__ float b2f(bf16 v) { return __bfloat162float(v); }
__device__ __forceinline__ bf16 f2b(float v) { return __float2bfloat16(v); }
__device__ __forceinline__ float bu2f(u16 h) { return __uint_as_float((u32)h << 16); }
__device__ __forceinline__ u16 f2bu(float x) {
    bf16 h = __float2bfloat16(x);
    return *reinterpret_cast<u16*>(&h);
}
__device__ __forceinline__ u32 pack2(float a, float b) {
    return (u32)f2bu(a) | ((u32)f2bu(b) << 16);
}

// ---------------------------------------------------------------------------
// Convert weights f32 -> bf16 (u16).
// ---------------------------------------------------------------------------
__global__ __launch_bounds__(256) void prep_weights(
    const float* __restrict__ W, u16* __restrict__ Wb, int n)
{
    int i = blockIdx.x * 256 + threadIdx.x;
    if (i < n) Wb[i] = f2bu(W[i]);
}

// ---------------------------------------------------------------------------
// X f32 [b][k][p] -> Xt bf16 [b][p][k]  (one-time transpose+convert).
// ---------------------------------------------------------------------------
__global__ __launch_bounds__(256) void xprep_kernel(
    const float* __restrict__ X, u16* __restrict__ Xt)
{
    __shared__ float sX[CDIM * 68];
    const int b  = blockIdx.y;
    const int p0 = blockIdx.x * 64;
    const int tid = threadIdx.x;

#pragma unroll
    for (int i = 0; i < 12; ++i) {
        const int idx = tid + i * 256;        // 0..3071 float4s
        const int p4 = idx & 15, k = idx >> 4;
        const float4 v = *reinterpret_cast<const float4*>(
            X + ((size_t)b * CDIM + k) * HWPIX + p0 + p4 * 4);
        *reinterpret_cast<float4*>(&sX[k * 68 + p4 * 4]) = v;
    }
    __syncthreads();

    const int p = tid >> 2;          // 0..63
    const int seg = tid & 3;         // 0..3 (6 k-blocks each)
    u16* dst = Xt + ((size_t)b * HWPIX + p0 + p) * CDIM;
#pragma unroll
    for (int s = 0; s < 6; ++s) {
        const int blk = seg * 6 + s; // 0..23, 8 k each
        float f[8];
#pragma unroll
        for (int j = 0; j < 8; ++j) f[j] = sX[(blk * 8 + j) * 68 + p];
        uint4 ov;
        ov.x = pack2(f[0], f[1]);
        ov.y = pack2(f[2], f[3]);
        ov.z = pack2(f[4], f[5]);
        ov.w = pack2(f[6], f[7]);
        *reinterpret_cast<uint4*>(dst + blk * 8) = ov;
    }
}

// ---------------------------------------------------------------------------
// qkv 1x1 conv as bf16 MFMA GEMM, reading pre-transposed Xt. (unchanged)
// ---------------------------------------------------------------------------
__global__ __launch_bounds__(256, 4) void conv_qkv_mfma(
    const u16* __restrict__ Xt, const u16* __restrict__ Wb,
    const float* __restrict__ bias, bf16* __restrict__ Y)
{
    __shared__ alignas(16) u16 sA[64 * KP];
    __shared__ alignas(16) u16 sB[128 * KP];
    __shared__ float sBias[64];

    int lin = blockIdx.x;
    lin = (lin & 7) * (18432 / 8) + (lin >> 3);
    const int co_t = lin % 9;
    const int rest = lin / 9;
    const int p_t = rest & 511;
    const int b   = rest >> 9;
    const int co0 = co_t * 64;
    const int p0  = p_t * 128;

    const int tid  = threadIdx.x;
    const int wave = tid >> 6;
    const int lane = tid & 63;
    const int r  = lane & 15;
    const int hk = lane >> 4;

    if (tid < 64) sBias[tid] = bias[co0 + tid];

    f32x4 acc[4][2];
#pragma unroll
    for (int i = 0; i < 4; ++i)
#pragma unroll
        for (int j = 0; j < 2; ++j) acc[i][j] = (f32x4){0.f, 0.f, 0.f, 0.f};

#pragma unroll
    for (int c = 0; c < 2; ++c) {
        {
            int idx = tid;
#pragma unroll
            for (int i = 0; i < 3; ++i, idx += 256) {
                const int row = idx / 12, cv = idx % 12;
                const uint4 v = *reinterpret_cast<const uint4*>(
                    Wb + (size_t)(co0 + row) * CDIM + c * 96 + cv * 8);
                *reinterpret_cast<uint4*>(&sA[row * KP + cv * 8]) = v;
            }
        }
        {
            int idx = tid;
#pragma unroll
            for (int i = 0; i < 6; ++i, idx += 256) {
                const int row = idx / 12, cv = idx % 12;
                const uint4 v = *reinterpret_cast<const uint4*>(
                    Xt + ((size_t)b * HWPIX + p0 + row) * CDIM + c * 96 + cv * 8);
                *reinterpret_cast<uint4*>(&sB[row * KP + cv * 8]) = v;
            }
        }
        __syncthreads();

#pragma unroll
        for (int ks = 0; ks < 3; ++ks) {
            const int kof = ks * 32 + hk * 8;
            const u16* pA = &sA[r * KP + kof];
            const u16* pB = &sB[(wave * 32 + r) * KP + kof];
            const short8 a0 = *reinterpret_cast<const short8*>(pA);
            const short8 a1 = *reinterpret_cast<const short8*>(pA + 16 * KP);
            const short8 a2 = *reinterpret_cast<const short8*>(pA + 32 * KP);
            const short8 a3 = *reinterpret_cast<const short8*>(pA + 48 * KP);
            const short8 b0 = *reinterpret_cast<const short8*>(pB);
            const short8 b1 = *reinterpret_cast<const short8*>(pB + 16 * KP);
            acc[0][0] = __builtin_amdgcn_mfma_f32_16x16x32_bf16(a0, b0, acc[0][0], 0, 0, 0);
            acc[1][0] = __builtin_amdgcn_mfma_f32_16x16x32_bf16(a1, b0, acc[1][0], 0, 0, 0);
            acc[2][0] = __builtin_amdgcn_mfma_f32_16x16x32_bf16(a2, b0, acc[2][0], 0, 0, 0);
            acc[3][0] = __builtin_amdgcn_mfma_f32_16x16x32_bf16(a3, b0, acc[3][0], 0, 0, 0);
            acc[0][1] = __builtin_amdgcn_mfma_f32_16x16x32_bf16(a0, b1, acc[0][1], 0, 0, 0);
            acc[1][1] = __builtin_amdgcn_mfma_f32_16x16x32_bf16(a1, b1, acc[1][1], 0, 0, 0);
            acc[2][1] = __builtin_amdgcn_mfma_f32_16x16x32_bf16(a2, b1, acc[2][1], 0, 0, 0);
            acc[3][1] = __builtin_amdgcn_mfma_f32_16x16x32_bf16(a3, b1, acc[3][1], 0, 0, 0);
        }
        __syncthreads();
    }

    u16* sOut = sB;
#pragma unroll
    for (int mf = 0; mf < 4; ++mf) {
#pragma unroll
        for (int j = 0; j < 4; ++j) {
            const int row = mf * 16 + hk * 4 + j;
            const float bs = sBias[row];
            sOut[row * 128 + wave * 32 + r]      = f2bu(acc[mf][0][j] + bs);
            sOut[row * 128 + wave * 32 + r + 16] = f2bu(acc[mf][1][j] + bs);
        }
    }
    __syncthreads();
#pragma unroll
    for (int i = 0; i < 4; ++i) {
        const int idx = tid + i * 256;
        const int row = idx >> 4, cq = idx & 15;
        const uint4 v = *reinterpret_cast<const uint4*>(&sOut[row * 128 + cq * 8]);
        *reinterpret_cast<uint4*>(
            &Y[((size_t)b * C3 + co0 + row) * HWPIX + p0 + cq * 8]) = v;
    }
}

// ---------------------------------------------------------------------------
// proj 1x1 conv as bf16 MFMA GEMM (unchanged).
// ---------------------------------------------------------------------------
__global__ __launch_bounds__(256, 4) void conv_proj_mfma(
    const float* __restrict__ X, const u16* __restrict__ Wb,
    const float* __restrict__ bias, float* __restrict__ Y)
{
    __shared__ alignas(16) u16 sA[64 * KP];
    __shared__ alignas(16) u16 sB[128 * KP];
    __shared__ float sBias[64];

    int lin = blockIdx.x;                       // nwg = 6144
    lin = (lin & 7) * (6144 / 8) + (lin >> 3);
    const int co_t = lin % 3;
    const int rest = lin / 3;
    const int p_t = rest & 511;
    const int b   = rest >> 9;
    const int co0 = co_t * 64;
    const int p0  = p_t * 128;

    const int tid  = threadIdx.x;
    const int wave = tid >> 6;
    const int lane = tid & 63;
    const int r  = lane & 15;
    const int hk = lane >> 4;

    if (tid < 64) sBias[tid] = bias[co0 + tid];

    f32x4 acc[4][2];
#pragma unroll
    for (int i = 0; i < 4; ++i)
#pragma unroll
        for (int j = 0; j < 2; ++j) acc[i][j] = (f32x4){0.f, 0.f, 0.f, 0.f};

    const int kp_lane = tid & 7;
    const int p4      = tid >> 3;

#pragma unroll
    for (int c = 0; c < 2; ++c) {
        {
            int idx = tid;
#pragma unroll
            for (int i = 0; i < 3; ++i, idx += 256) {
                const int row = idx / 12, cv = idx % 12;
                const uint4 v = *reinterpret_cast<const uint4*>(
                    Wb + (size_t)(co0 + row) * CDIM + c * 96 + cv * 8);
                *reinterpret_cast<uint4*>(&sA[row * KP + cv * 8]) = v;
            }
        }
        {
            const float* Xc = X + ((size_t)b * CDIM + c * 96) * HWPIX + p0;
#pragma unroll
            for (int i = 0; i < 6; ++i) {
                const int kp = kp_lane + i * 8;
                const int k  = kp * 2;
                const float4 va = *reinterpret_cast<const float4*>(
                    Xc + (size_t)k * HWPIX + p4 * 4);
                const float4 vb = *reinterpret_cast<const float4*>(
                    Xc + (size_t)(k + 1) * HWPIX + p4 * 4);
                const int col = (((k >> 3) ^ (p4 & 3)) << 3) | (k & 7);
                const float av[4] = {va.x, va.y, va.z, va.w};
                const float bv[4] = {vb.x, vb.y, vb.z, vb.w};
#pragma unroll
                for (int j = 0; j < 4; ++j) {
                    const int row = p4 * 4 + j;
                    *reinterpret_cast<u32*>(&sB[row * KP + col]) = pack2(av[j], bv[j]);
                }
            }
        }
        __syncthreads();

#pragma unroll
        for (int ks = 0; ks < 3; ++ks) {
            const int kof = ks * 32 + hk * 8;
            const u16* pA = &sA[r * KP + kof];
            const int rowb = wave * 32 + r;
            const int colr = (((kof >> 3) ^ ((rowb >> 2) & 3)) << 3);
            const u16* pB = &sB[rowb * KP + colr];
            const short8 a0 = *reinterpret_cast<const short8*>(pA);
            const short8 a1 = *reinterpret_cast<const short8*>(pA + 16 * KP);
            const short8 a2 = *reinterpret_cast<const short8*>(pA + 32 * KP);
            const short8 a3 = *reinterpret_cast<const short8*>(pA + 48 * KP);
            const short8 b0 = *reinterpret_cast<const short8*>(pB);
            const short8 b1 = *reinterpret_cast<const short8*>(pB + 16 * KP);
            acc[0][0] = __builtin_amdgcn_mfma_f32_16x16x32_bf16(a0, b0, acc[0][0], 0, 0, 0);
            acc[1][0] = __builtin_amdgcn_mfma_f32_16x16x32_bf16(a1, b0, acc[1][0], 0, 0, 0);
            acc[2][0] = __builtin_amdgcn_mfma_f32_16x16x32_bf16(a2, b0, acc[2][0], 0, 0, 0);
            acc[3][0] = __builtin_amdgcn_mfma_f32_16x16x32_bf16(a3, b0, acc[3][0], 0, 0, 0);
            acc[0][1] = __builtin_amdgcn_mfma_f32_16x16x32_bf16(a0, b1, acc[0][1], 0, 0, 0);
            acc[1][1] = __builtin_amdgcn_mfma_f32_16x16x32_bf16(a1, b1, acc[1][1], 0, 0, 0);
            acc[2][1] = __builtin_amdgcn_mfma_f32_16x16x32_bf16(a2, b1, acc[2][1], 0, 0, 0);
            acc[3][1] = __builtin_amdgcn_mfma_f32_16x16x32_bf16(a3, b1, acc[3][1], 0, 0, 0);
        }
        __syncthreads();
    }

#pragma unroll
    for (int mf = 0; mf < 4; ++mf) {
#pragma unroll
        for (int j = 0; j < 4; ++j) {
            const int co = co0 + mf * 16 + hk * 4 + j;
            const float bs = sBias[mf * 16 + hk * 4 + j];
            const size_t base = ((size_t)b * CDIM + co) * HWPIX + p0 + wave * 32 + r;
            Y[base]      = acc[mf][0][j] + bs;
            Y[base + 16] = acc[mf][1][j] + bs;
        }
    }
}

// ---------------------------------------------------------------------------
// Depthwise 3x3 SAME conv — vectorized (unchanged).
// ---------------------------------------------------------------------------
__global__ __launch_bounds__(256) void dwconv_kernel(
    const bf16* __restrict__ In, const float* __restrict__ Wd,
    const float* __restrict__ bd, bf16* __restrict__ Out)
{
    __shared__ alignas(16) u16 sIn[10 * 256];
    const int bc = blockIdx.y;            // b*576 + c
    const int c = bc % C3;
    const size_t base = (size_t)bc * HWPIX;
    const int r0 = blockIdx.x * 8;
    const int tid = threadIdx.x;

    for (int idx = tid; idx < 320; idx += 256) {
        const int lr = idx >> 5, ch = idx & 31;
        const int gr = r0 + lr - 1;
        uint4 v = {0u, 0u, 0u, 0u};
        if ((unsigned)gr < IMGW)
            v = *reinterpret_cast<const uint4*>(&In[base + (size_t)gr * IMGW + ch * 8]);
        *reinterpret_cast<uint4*>(&sIn[lr * 256 + ch * 8]) = v;
    }
    __syncthreads();

    float wg[9];
#pragma unroll
    for (int t = 0; t < 9; ++t) wg[t] = Wd[c * 9 + t];

    const int rr = tid >> 5;
    const int px0 = (tid & 31) * 8;
    const float bias = bd[c];
    float acc[8];
#pragma unroll
    for (int j = 0; j < 8; ++j) acc[j] = bias;

#pragma unroll
    for (int dy = 0; dy < 3; ++dy) {
        const int row = rr + dy;
        const u16* rp = &sIn[row * 256];
        const short8 mv = *reinterpret_cast<const short8*>(&rp[px0]);
        float m[8];
#pragma unroll
        for (int j = 0; j < 8; ++j) m[j] = bu2f((u16)mv[j]);
        const float lft = (px0 > 0) ? bu2f(rp[px0 - 1]) : 0.f;
        const float rgt = (px0 + 8 < 256) ? bu2f(rp[px0 + 8]) : 0.f;
        const float w0 = wg[dy * 3], w1 = wg[dy * 3 + 1], w2 = wg[dy * 3 + 2];

        acc[0] = fmaf(w0, lft, acc[0]);
        acc[0] = fmaf(w1, m[0], acc[0]);
        acc[0] = fmaf(w2, m[1], acc[0]);
#pragma unroll
        for (int j = 1; j < 7; ++j) {
            acc[j] = fmaf(w0, m[j - 1], acc[j]);
            acc[j] = fmaf(w1, m[j], acc[j]);
            acc[j] = fmaf(w2, m[j + 1], acc[j]);
        }
        acc[7] = fmaf(w0, m[6], acc[7]);
        acc[7] = fmaf(w1, m[7], acc[7]);
        acc[7] = fmaf(w2, rgt, acc[7]);
    }

    uint4 ov;
    ov.x = pack2(acc[0], acc[1]);
    ov.y = pack2(acc[2], acc[3]);
    ov.z = pack2(acc[4], acc[5]);
    ov.w = pack2(acc[6], acc[7]);
    *reinterpret_cast<uint4*>(&Out[base + (size_t)(r0 + rr) * IMGW + px0]) = ov;
}

// ---------------------------------------------------------------------------
// Local (windowed 8x8) channel attention + FUSED global branch apply.
// o1+o2 = (softmax_local(P) + A_global) · v_window  (attention is channelwise,
// so the global PV restricted to a window only needs v at that window).
// ---------------------------------------------------------------------------
#define CS 328          // c-row stride (u16) for sQ/sK/sV
#define PS 40           // row stride (u16) for sP

__global__ __launch_bounds__(256) void local_attn_kernel(
    const bf16* __restrict__ QKV, const float* __restrict__ temp,
    const float* __restrict__ Ag, float* __restrict__ Osum)
{
    __shared__ alignas(16) u16 sQ[32 * CS];
    __shared__ alignas(16) u16 sK[32 * CS];
    __shared__ alignas(16) u16 sV[32 * CS];
    __shared__ alignas(16) u16 sP[4 * 32 * PS];
    __shared__ float snq[4 * 32], snk[4 * 32];
    __shared__ float sAg[576];

    const int wy    = blockIdx.x >> 3;
    const int strip = blockIdx.x & 7;
    const int head  = blockIdx.y;
    const int b     = blockIdx.z;
    const int x0    = strip * 32;
    const int tid   = threadIdx.x;
    const int w     = tid >> 6;
    const int lane  = tid & 63;
    const int r     = lane & 15;
    const int hk    = lane >> 4;

    // stage global-branch attention matrix for this (b,head)
    {
        const float* Asrc = Ag + ((size_t)(b * NHEADS + head)) * 576;
        for (int idx = tid; idx < 576; idx += 256) sAg[idx] = Asrc[idx];
    }

#pragma unroll
    for (int i = 0; i < 9; ++i) {
        const int idx = tid + i * 256;
        const int tensor = idx / 768;
        const int rem = idx - tensor * 768;
        const int c  = rem >> 5;
        const int rw = (rem >> 2) & 7;
        const int ch = rem & 3;
        const size_t g = ((size_t)b * C3 + tensor * CDIM + head * CPH + c) * HWPIX
                       + (size_t)(wy * 8 + rw) * IMGW + x0 + ch * 8;
        const uint4 v = *reinterpret_cast<const uint4*>(&QKV[g]);
        u16* dst = (tensor == 0) ? sQ : ((tensor == 1) ? sK : sV);
        *reinterpret_cast<uint4*>(&dst[c * CS + rw * 40 + ch * 8]) = v;
    }
    __syncthreads();

    if (tid < 192) {
        const int qk = tid / 96;
        const int rem = tid - qk * 96;
        const int ww = rem / 24, c = rem % 24;
        const u16* sT = qk ? sK : sQ;
        const int off = c * CS + ww * 8;
        float s = 0.f;
#pragma unroll
        for (int rw = 0; rw < 8; ++rw) {
            const short8 v = *reinterpret_cast<const short8*>(&sT[off + rw * 40]);
#pragma unroll
            for (int j = 0; j < 8; ++j) {
                const float f = bu2f((u16)v[j]);
                s = fmaf(f, f, s);
            }
        }
        const float inv = 1.f / fmaxf(sqrtf(s), 1e-12f);
        if (qk) snk[ww * 32 + c] = inv; else snq[ww * 32 + c] = inv;
    }
    __syncthreads();

    f32x4 accg[2][2];
#pragma unroll
    for (int i = 0; i < 2; ++i)
#pragma unroll
        for (int j = 0; j < 2; ++j) accg[i][j] = (f32x4){0.f, 0.f, 0.f, 0.f};

#pragma unroll
    for (int kk = 0; kk < 2; ++kk) {
        const int colA = (kk * 4 + hk) * 40 + w * 8;
        const short8 aq0 = *reinterpret_cast<const short8*>(&sQ[(r     ) * CS + colA]);
        const short8 aq1 = *reinterpret_cast<const short8*>(&sQ[(16 + r) * CS + colA]);
        const short8 bk0 = *reinterpret_cast<const short8*>(&sK[(r     ) * CS + colA]);
        const short8 bk1 = *reinterpret_cast<const short8*>(&sK[(16 + r) * CS + colA]);
        accg[0][0] = __builtin_amdgcn_mfma_f32_16x16x32_bf16(aq0, bk0, accg[0][0], 0, 0, 0);
        accg[0][1] = __builtin_amdgcn_mfma_f32_16x16x32_bf16(aq0, bk1, accg[0][1], 0, 0, 0);
        accg[1][0] = __builtin_amdgcn_mfma_f32_16x16x32_bf16(aq1, bk0, accg[1][0], 0, 0, 0);
        accg[1][1] = __builtin_amdgcn_mfma_f32_16x16x32_bf16(aq1, bk1, accg[1][1], 0, 0, 0);
    }

    const float t = temp[head];
    const int e0 = lane & 15;
    const bool v1 = e0 < 8;
    const float ink0 = snk[w * 32 + e0];
    const float ink1 = snk[w * 32 + 16 + e0];

#pragma unroll
    for (int ct = 0; ct < 2; ++ct) {
#pragma unroll
        for (int j = 0; j < 4; ++j) {
            const int cidx = ct * 16 + hk * 4 + j;
            const float inq = snq[w * 32 + cidx];
            const float g0 = accg[ct][0][j] * inq * ink0 * t;
            const float g1 = v1 ? accg[ct][1][j] * inq * ink1 * t : -1e30f;
            float m = fmaxf(g0, g1);
#pragma unroll
            for (int mk = 8; mk >= 1; mk >>= 1) m = fmaxf(m, __shfl_xor(m, mk));
            const float p0 = __expf(g0 - m);
            const float p1 = v1 ? __expf(g1 - m) : 0.f;
            float s = p0 + p1;
#pragma unroll
            for (int mk = 8; mk >= 1; mk >>= 1) s += __shfl_xor(s, mk);
            const float inv = 1.f / s;
            if (cidx < CPH) {
                sP[w * 32 * PS + cidx * PS + e0] = f2bu(p0 * inv + sAg[cidx * CPH + e0]);
                if (v1) sP[w * 32 * PS + cidx * PS + 16 + e0]
                    = f2bu(p1 * inv + sAg[cidx * CPH + 16 + e0]);
            }
        }
    }
    __syncthreads();

    f32x4 acco[2][4];
#pragma unroll
    for (int i = 0; i < 2; ++i)
#pragma unroll
        for (int j = 0; j < 4; ++j) acco[i][j] = (f32x4){0.f, 0.f, 0.f, 0.f};

    short8 afr[2];
#pragma unroll
    for (int ct = 0; ct < 2; ++ct) {
        if (hk < 3)
            afr[ct] = *reinterpret_cast<const short8*>(
                &sP[w * 32 * PS + (ct * 16 + r) * PS + hk * 8]);
        else
            afr[ct] = (short8){0, 0, 0, 0, 0, 0, 0, 0};
    }
#pragma unroll
    for (int nt = 0; nt < 4; ++nt) {
        const int px = nt * 16 + r;
        const int colV = (px >> 3) * 40 + w * 8 + (px & 7);
        short8 bfr;
        if (hk < 3) {
#pragma unroll
            for (int j = 0; j < 8; ++j)
                bfr[j] = (short)sV[(hk * 8 + j) * CS + colV];
        } else {
            bfr = (short8){0, 0, 0, 0, 0, 0, 0, 0};
        }
        acco[0][nt] = __builtin_amdgcn_mfma_f32_16x16x32_bf16(afr[0], bfr, acco[0][nt], 0, 0, 0);
        acco[1][nt] = __builtin_amdgcn_mfma_f32_16x16x32_bf16(afr[1], bfr, acco[1][nt], 0, 0, 0);
    }

    const size_t ob = ((size_t)b * CDIM + head * CPH) * HWPIX;
#pragma unroll
    for (int ct = 0; ct < 2; ++ct) {
#pragma unroll
        for (int j = 0; j < 4; ++j) {
            const int cidx = ct * 16 + hk * 4 + j;
            if (cidx >= CPH) continue;
#pragma unroll
            for (int nt = 0; nt < 4; ++nt) {
                const int px = nt * 16 + r;
                const int rpx = px >> 3, pxl = px & 7;
                Osum[ob + (size_t)cidx * HWPIX
                     + (size_t)(wy * 8 + rpx) * IMGW + x0 + w * 8 + pxl] = acco[ct][nt][j];
            }
        }
    }
}

// ---------------------------------------------------------------------------
// Global branch stats — MFMA rewrite.
// Grid (chunk=16, bh=32). Chunk = 4096 d, staged in 8 x 512-d subtiles.
// Gram G[c][e] = sum_d q[c][d] k[e][d] via mfma_16x16x32_bf16, 2x2 frag tiles
// (rows 24..31 zero-padded). 4 waves split each 512-d subtile (128 d each),
// LDS-reduce partials. Norms |q|^2,|k|^2 via VALU side loop (threads 0..191).
// ---------------------------------------------------------------------------
#define GRS 520          // LDS row stride (u16) for gstats tiles

__global__ __launch_bounds__(256) void gstats_kernel(
    const bf16* __restrict__ QKV, float* __restrict__ Gp)
{
    __shared__ alignas(16) u16 sq[32 * GRS];
    __shared__ alignas(16) u16 sk[32 * GRS];

    const int chunk = blockIdx.x;        // 0..15
    const int bh = blockIdx.y;           // 0..31
    const int b = bh >> 3, head = bh & 7;
    const int tid = threadIdx.x;
    const int w = tid >> 6, lane = tid & 63;
    const int r = lane & 15, hk = lane >> 4;

    const size_t qb = ((size_t)b * C3 + head * CPH) * HWPIX;
    const size_t kb = qb + (size_t)CDIM * HWPIX;

    // zero rows 24..31 once (staging only writes rows 0..23)
    for (int idx = tid; idx < 1040; idx += 256) {
        const int t = idx >= 520;
        const int o = idx - t * 520;
        u16* d = (t ? sk : sq) + 24 * GRS + o * 8;
        *reinterpret_cast<uint4*>(d) = (uint4){0u, 0u, 0u, 0u};
    }

    f32x4 acc[2][2];
#pragma unroll
    for (int i = 0; i < 2; ++i)
#pragma unroll
        for (int j = 0; j < 2; ++j) acc[i][j] = (f32x4){0.f, 0.f, 0.f, 0.f};
    float nacc = 0.f;
    const int nrow = tid >> 2;           // 0..63 (<48 active)
    const int nq4  = tid & 3;

    for (int st = 0; st < 8; ++st) {
        const int d0 = chunk * 4096 + st * 512;
        __syncthreads();                 // prev-stage reads done before overwrite
#pragma unroll
        for (int i = 0; i < 12; ++i) {
            const int idx = tid + i * 256;        // 0..3071
            const int t = idx >= 1536;
            const int rem = idx - t * 1536;
            const int c = rem >> 6, dv = rem & 63;
            const uint4 v = *reinterpret_cast<const uint4*>(
                &QKV[(t ? kb : qb) + (size_t)c * HWPIX + d0 + dv * 8]);
            u16* dst = (t ? sk : sq) + c * GRS + dv * 8;
            *reinterpret_cast<uint4*>(dst) = v;
        }
        __syncthreads();

        // Gram MFMA on this wave's 128-d slice
#pragma unroll
        for (int ks = 0; ks < 4; ++ks) {
            const int kof = w * 128 + ks * 32 + hk * 8;
            const short8 aq0 = *reinterpret_cast<const short8*>(&sq[(r     ) * GRS + kof]);
            const short8 aq1 = *reinterpret_cast<const short8*>(&sq[(16 + r) * GRS + kof]);
            const short8 bk0 = *reinterpret_cast<const short8*>(&sk[(r     ) * GRS + kof]);
            const short8 bk1 = *reinterpret_cast<const short8*>(&sk[(16 + r) * GRS + kof]);
            acc[0][0] = __builtin_amdgcn_mfma_f32_16x16x32_bf16(aq0, bk0, acc[0][0], 0, 0, 0);
            acc[0][1] = __builtin_amdgcn_mfma_f32_16x16x32_bf16(aq0, bk1, acc[0][1], 0, 0, 0);
            acc[1][0] = __builtin_amdgcn_mfma_f32_16x16x32_bf16(aq1, bk0, acc[1][0], 0, 0, 0);
            acc[1][1] = __builtin_amdgcn_mfma_f32_16x16x32_bf16(aq1, bk1, acc[1][1], 0, 0, 0);
        }

        // norms (threads 0..191: 48 rows x 4 lanes x 128 d)
        if (nrow < 48) {
            const u16* rp = (nrow < 24 ? &sq[nrow * GRS] : &sk[(nrow - 24) * GRS]) + nq4 * 128;
#pragma unroll
            for (int i = 0; i < 16; ++i) {
                const short8 v = *reinterpret_cast<const short8*>(&rp[i * 8]);
#pragma unroll
                for (int j = 0; j < 8; ++j) {
                    const float f = bu2f((u16)v[j]);
                    nacc = fmaf(f, f, nacc);
                }
            }
        }
    }
    __syncthreads();

    // reduce 4 wave-partials via LDS (reuse sq as f32 [4][24][25])
    float* red = reinterpret_cast<float*>(sq);
#pragma unroll
    for (int ct = 0; ct < 2; ++ct) {
#pragma unroll
        for (int et = 0; et < 2; ++et) {
#pragma unroll
            for (int j = 0; j < 4; ++j) {
                const int c = ct * 16 + hk * 4 + j;
                const int e = et * 16 + r;
                if (c < CPH && e < CPH)
                    red[(w * 24 + c) * 25 + e] = acc[ct][et][j];
            }
        }
    }
    __syncthreads();

    float* dst = Gp + ((size_t)bh * 32 + chunk) * 624;
    for (int idx = tid; idx < 576; idx += 256) {
        const int c = idx / 24, e = idx % 24;
        const int o = c * 25 + e;
        dst[idx] = red[o] + red[600 + o] + red[1200 + o] + red[1800 + o];
    }

    // norm reduce over 4 lanes and write
    float ns = nacc;
    ns += __shfl_xor(ns, 1);
    ns += __shfl_xor(ns, 2);
    if (nrow < 48 && nq4 == 0) {
        if (nrow < 24) dst[576 + nrow] = ns;
        else           dst[600 + (nrow - 24)] = ns;
    }
}

// ---------------------------------------------------------------------------
// Reduce 16 chunk partials, build softmax matrices A[bh][24][24].
// ---------------------------------------------------------------------------
__global__ __launch_bounds__(64) void gsoftmax_kernel(
    const float* __restrict__ Gp, const float* __restrict__ temp,
    float* __restrict__ A)
{
    __shared__ float red[624];
    const int bh = blockIdx.x, head = bh & 7;
    const int tid = threadIdx.x;

    for (int jj = tid; jj < 624; jj += 64) {
        float s = 0.f;
        for (int ch = 0; ch < 16; ++ch) s += Gp[((size_t)bh * 32 + ch) * 624 + jj];
        red[jj] = s;
    }
    __syncthreads();

    if (tid < CPH) {
        const int c = tid;
        const float t = temp[head];
        const float inq = 1.f / fmaxf(sqrtf(red[576 + c]), 1e-12f);
        float l[CPH]; float m = -1e30f;
        for (int e = 0; e < CPH; ++e) {
            const float ink = 1.f / fmaxf(sqrtf(red[600 + e]), 1e-12f);
            l[e] = red[c * CPH + e] * inq * ink * t;
            m = fmaxf(m, l[e]);
        }
        float s = 0.f;
        for (int e = 0; e < CPH; ++e) { l[e] = expf(l[e] - m); s += l[e]; }
        const float inv = 1.f / s;
        for (int e = 0; e < CPH; ++e) A[(size_t)bh * 576 + c * CPH + e] = l[e] * inv;
    }
}

// ---------------------------------------------------------------------------
extern "C" void kernel_launch(void* const* d_in, const int* in_sizes, int n_in,
                              void* d_out, int out_size, void* d_ws, size_t ws_size,
                              hipStream_t stream) {
    const float* x           = (const float*)d_in[0];
    const float* temperature = (const float*)d_in[1];
    const float* qkv_w       = (const float*)d_in[2];
    const float* qkv_b       = (const float*)d_in[3];
    const float* dw_w        = (const float*)d_in[4];
    const float* dw_b        = (const float*)d_in[5];
    const float* proj_w      = (const float*)d_in[6];
    const float* proj_b      = (const float*)d_in[7];
    float* out = (float*)d_out;

    char* ws = (char*)d_ws;
    constexpr size_t QKV_ELEMS = (size_t)NBATCH * C3 * HWPIX;
    constexpr size_t QKV_BYTES = QKV_ELEMS * sizeof(bf16);

    bf16* qkv1 = (bf16*)ws;                       // conv1x1 out (bf16)
    bf16* qkv2 = (bf16*)(ws + QKV_BYTES);         // q,k,v after depthwise (bf16)
    float* osum = (float*)ws;                     // overlays qkv1 (dead after dw)
    float* Gp   = (float*)(ws + 2 * QKV_BYTES);   // 32*32*624 f32 partials
    float* Amat = Gp + (size_t)32 * 32 * 624;     // 32*576 f32
    u16*  Wb    = (u16*)Gp;                       // qkv weights bf16; dead before gstats
    u16*  Wpb   = (u16*)(Amat + 32 * 576);        // proj weights bf16
    u16*  Xt    = (u16*)qkv2;                     // Xt overlays qkv2 head (dead after conv_qkv)

    // 0. weights f32 -> bf16
    prep_weights<<<(C3 * CDIM + 255) / 256, 256, 0, stream>>>(qkv_w, Wb, C3 * CDIM);
    prep_weights<<<(CDIM * CDIM + 255) / 256, 256, 0, stream>>>(proj_w, Wpb, CDIM * CDIM);

    // 0b. X transpose+convert -> Xt
    xprep_kernel<<<dim3(HWPIX / 64, NBATCH), 256, 0, stream>>>(x, Xt);

    // 1. qkv = 1x1 conv via MFMA
    conv_qkv_mfma<<<9 * 512 * NBATCH, 256, 0, stream>>>(Xt, Wb, qkv_b, qkv1);

    // 2. depthwise 3x3 (overwrites Xt region — Xt dead)
    dwconv_kernel<<<dim3(32, NBATCH * C3), 256, 0, stream>>>(
        qkv1, dw_w, dw_b, qkv2);

    // 3. global Gram/norm partials via MFMA (overwrites Wb — dead)
    gstats_kernel<<<dim3(16, 32), 256, 0, stream>>>(qkv2, Gp);

    // 4. reduce + softmax -> A
    gsoftmax_kernel<<<32, 64, 0, stream>>>(Gp, temperature, Amat);

    // 5. local attention + fused global apply -> osum = o1 + o2
    local_attn_kernel<<<dim3(256, NHEADS, NBATCH), 256, 0, stream>>>(
        qkv2, temperature, Amat, osum);

    // 6. proj 1x1 conv via MFMA (f32 osum staged->bf16, f32 out)
    conv_proj_mfma<<<3 * 512 * NBATCH, 256, 0, stream>>>(osum, Wpb, proj_b, out);
}

// Round 8
// 616.755 us; speedup vs baseline: 6.5421x; 1.1010x over previous
//
#include <hip/hip_runtime.h>
#include <hip/hip_bf16.h>
#include <cstdint>
#include <cstddef>

#define HWPIX 65536
#define IMGW 256
#define CDIM 192
#define C3 576
#define NBATCH 4
#define NHEADS 8
#define CPH 24
#define KP 104   // padded K pitch (bf16 elems) for MFMA LDS tiles

using bf16 = __hip_bfloat16;
typedef __attribute__((ext_vector_type(8))) short short8;
typedef __attribute__((ext_vector_type(4))) float f32x4;
typedef unsigned int u32;
typedef unsigned short u16;

__device__ __forceinline__ float b2f(bf16 v) { return __bfloat162float(v); }
__device__ __forceinline__ bf16 f2b(float v) { return __float2bfloat16(v); }
__device__ __forceinline__ float bu2f(u16 h) { return __uint_as_float((u32)h << 16); }
__device__ __forceinline__ u16 f2bu(float x) {
    bf16 h = __float2bfloat16(x);
    return *reinterpret_cast<u16*>(&h);
}
__device__ __forceinline__ u32 pack2(float a, float b) {
    return (u32)f2bu(a) | ((u32)f2bu(b) << 16);
}

// ---------------------------------------------------------------------------
// Convert weights f32 -> bf16 (u16).
// ---------------------------------------------------------------------------
__global__ __launch_bounds__(256) void prep_weights(
    const float* __restrict__ W, u16* __restrict__ Wb, int n)
{
    int i = blockIdx.x * 256 + threadIdx.x;
    if (i < n) Wb[i] = f2bu(W[i]);
}

// ---------------------------------------------------------------------------
// X f32 [b][k][p] -> Xt bf16 [b][p][k]  (one-time transpose+convert).
// ---------------------------------------------------------------------------
__global__ __launch_bounds__(256) void xprep_kernel(
    const float* __restrict__ X, u16* __restrict__ Xt)
{
    __shared__ float sX[CDIM * 68];
    const int b  = blockIdx.y;
    const int p0 = blockIdx.x * 64;
    const int tid = threadIdx.x;

#pragma unroll
    for (int i = 0; i < 12; ++i) {
        const int idx = tid + i * 256;        // 0..3071 float4s
        const int p4 = idx & 15, k = idx >> 4;
        const float4 v = *reinterpret_cast<const float4*>(
            X + ((size_t)b * CDIM + k) * HWPIX + p0 + p4 * 4);
        *reinterpret_cast<float4*>(&sX[k * 68 + p4 * 4]) = v;
    }
    __syncthreads();

    const int p = tid >> 2;          // 0..63
    const int seg = tid & 3;         // 0..3 (6 k-blocks each)
    u16* dst = Xt + ((size_t)b * HWPIX + p0 + p) * CDIM;
#pragma unroll
    for (int s = 0; s < 6; ++s) {
        const int blk = seg * 6 + s; // 0..23, 8 k each
        float f[8];
#pragma unroll
        for (int j = 0; j < 8; ++j) f[j] = sX[(blk * 8 + j) * 68 + p];
        uint4 ov;
        ov.x = pack2(f[0], f[1]);
        ov.y = pack2(f[2], f[3]);
        ov.z = pack2(f[4], f[5]);
        ov.w = pack2(f[6], f[7]);
        *reinterpret_cast<uint4*>(dst + blk * 8) = ov;
    }
}

// ---------------------------------------------------------------------------
// qkv 1x1 conv as bf16 MFMA GEMM, reading pre-transposed Xt. (unchanged)
// ---------------------------------------------------------------------------
__global__ __launch_bounds__(256, 4) void conv_qkv_mfma(
    const u16* __restrict__ Xt, const u16* __restrict__ Wb,
    const float* __restrict__ bias, bf16* __restrict__ Y)
{
    __shared__ alignas(16) u16 sA[64 * KP];
    __shared__ alignas(16) u16 sB[128 * KP];
    __shared__ float sBias[64];

    int lin = blockIdx.x;
    lin = (lin & 7) * (18432 / 8) + (lin >> 3);
    const int co_t = lin % 9;
    const int rest = lin / 9;
    const int p_t = rest & 511;
    const int b   = rest >> 9;
    const int co0 = co_t * 64;
    const int p0  = p_t * 128;

    const int tid  = threadIdx.x;
    const int wave = tid >> 6;
    const int lane = tid & 63;
    const int r  = lane & 15;
    const int hk = lane >> 4;

    if (tid < 64) sBias[tid] = bias[co0 + tid];

    f32x4 acc[4][2];
#pragma unroll
    for (int i = 0; i < 4; ++i)
#pragma unroll
        for (int j = 0; j < 2; ++j) acc[i][j] = (f32x4){0.f, 0.f, 0.f, 0.f};

#pragma unroll
    for (int c = 0; c < 2; ++c) {
        {
            int idx = tid;
#pragma unroll
            for (int i = 0; i < 3; ++i, idx += 256) {
                const int row = idx / 12, cv = idx % 12;
                const uint4 v = *reinterpret_cast<const uint4*>(
                    Wb + (size_t)(co0 + row) * CDIM + c * 96 + cv * 8);
                *reinterpret_cast<uint4*>(&sA[row * KP + cv * 8]) = v;
            }
        }
        {
            int idx = tid;
#pragma unroll
            for (int i = 0; i < 6; ++i, idx += 256) {
                const int row = idx / 12, cv = idx % 12;
                const uint4 v = *reinterpret_cast<const uint4*>(
                    Xt + ((size_t)b * HWPIX + p0 + row) * CDIM + c * 96 + cv * 8);
                *reinterpret_cast<uint4*>(&sB[row * KP + cv * 8]) = v;
            }
        }
        __syncthreads();

#pragma unroll
        for (int ks = 0; ks < 3; ++ks) {
            const int kof = ks * 32 + hk * 8;
            const u16* pA = &sA[r * KP + kof];
            const u16* pB = &sB[(wave * 32 + r) * KP + kof];
            const short8 a0 = *reinterpret_cast<const short8*>(pA);
            const short8 a1 = *reinterpret_cast<const short8*>(pA + 16 * KP);
            const short8 a2 = *reinterpret_cast<const short8*>(pA + 32 * KP);
            const short8 a3 = *reinterpret_cast<const short8*>(pA + 48 * KP);
            const short8 b0 = *reinterpret_cast<const short8*>(pB);
            const short8 b1 = *reinterpret_cast<const short8*>(pB + 16 * KP);
            acc[0][0] = __builtin_amdgcn_mfma_f32_16x16x32_bf16(a0, b0, acc[0][0], 0, 0, 0);
            acc[1][0] = __builtin_amdgcn_mfma_f32_16x16x32_bf16(a1, b0, acc[1][0], 0, 0, 0);
            acc[2][0] = __builtin_amdgcn_mfma_f32_16x16x32_bf16(a2, b0, acc[2][0], 0, 0, 0);
            acc[3][0] = __builtin_amdgcn_mfma_f32_16x16x32_bf16(a3, b0, acc[3][0], 0, 0, 0);
            acc[0][1] = __builtin_amdgcn_mfma_f32_16x16x32_bf16(a0, b1, acc[0][1], 0, 0, 0);
            acc[1][1] = __builtin_amdgcn_mfma_f32_16x16x32_bf16(a1, b1, acc[1][1], 0, 0, 0);
            acc[2][1] = __builtin_amdgcn_mfma_f32_16x16x32_bf16(a2, b1, acc[2][1], 0, 0, 0);
            acc[3][1] = __builtin_amdgcn_mfma_f32_16x16x32_bf16(a3, b1, acc[3][1], 0, 0, 0);
        }
        __syncthreads();
    }

    u16* sOut = sB;
#pragma unroll
    for (int mf = 0; mf < 4; ++mf) {
#pragma unroll
        for (int j = 0; j < 4; ++j) {
            const int row = mf * 16 + hk * 4 + j;
            const float bs = sBias[row];
            sOut[row * 128 + wave * 32 + r]      = f2bu(acc[mf][0][j] + bs);
            sOut[row * 128 + wave * 32 + r + 16] = f2bu(acc[mf][1][j] + bs);
        }
    }
    __syncthreads();
#pragma unroll
    for (int i = 0; i < 4; ++i) {
        const int idx = tid + i * 256;
        const int row = idx >> 4, cq = idx & 15;
        const uint4 v = *reinterpret_cast<const uint4*>(&sOut[row * 128 + cq * 8]);
        *reinterpret_cast<uint4*>(
            &Y[((size_t)b * C3 + co0 + row) * HWPIX + p0 + cq * 8]) = v;
    }
}

// ---------------------------------------------------------------------------
// proj 1x1 conv as bf16 MFMA GEMM — input is now bf16 osum [c][p].
// Staging: dual uint2 loads (4 p at channels k,k+1), bitwise lane-combine to
// packed u32, XOR-swizzled sB writes (write col (kp>>2)^(p4&3) matches read
// col (rowb>>2)&3). No f32->bf16 cvt in-kernel; read traffic halved.
// ---------------------------------------------------------------------------
__global__ __launch_bounds__(256, 4) void conv_proj_mfma(
    const u16* __restrict__ X, const u16* __restrict__ Wb,
    const float* __restrict__ bias, float* __restrict__ Y)
{
    __shared__ alignas(16) u16 sA[64 * KP];
    __shared__ alignas(16) u16 sB[128 * KP];
    __shared__ float sBias[64];

    int lin = blockIdx.x;                       // nwg = 6144
    lin = (lin & 7) * (6144 / 8) + (lin >> 3);
    const int co_t = lin % 3;
    const int rest = lin / 3;
    const int p_t = rest & 511;
    const int b   = rest >> 9;
    const int co0 = co_t * 64;
    const int p0  = p_t * 128;

    const int tid  = threadIdx.x;
    const int wave = tid >> 6;
    const int lane = tid & 63;
    const int r  = lane & 15;
    const int hk = lane >> 4;

    if (tid < 64) sBias[tid] = bias[co0 + tid];

    f32x4 acc[4][2];
#pragma unroll
    for (int i = 0; i < 4; ++i)
#pragma unroll
        for (int j = 0; j < 2; ++j) acc[i][j] = (f32x4){0.f, 0.f, 0.f, 0.f};

    const int p4 = tid & 31;        // p-quad 0..31 (4 p each)
    const int kq = tid >> 5;        // 0..7 k-pair sub-index

#pragma unroll
    for (int c = 0; c < 2; ++c) {
        {
            int idx = tid;
#pragma unroll
            for (int i = 0; i < 3; ++i, idx += 256) {
                const int row = idx / 12, cv = idx % 12;
                const uint4 v = *reinterpret_cast<const uint4*>(
                    Wb + (size_t)(co0 + row) * CDIM + c * 96 + cv * 8);
                *reinterpret_cast<uint4*>(&sA[row * KP + cv * 8]) = v;
            }
        }
        {
            const u16* Xc = X + ((size_t)b * CDIM + c * 96) * HWPIX + p0;
#pragma unroll
            for (int i = 0; i < 6; ++i) {
                const int kp = kq + i * 8;            // 0..47
                const int k  = kp * 2;                // even
                const uint2 va = *reinterpret_cast<const uint2*>(
                    Xc + (size_t)k * HWPIX + p4 * 4);
                const uint2 vb = *reinterpret_cast<const uint2*>(
                    Xc + (size_t)(k + 1) * HWPIX + p4 * 4);
                const int col = (((kp >> 2) ^ (p4 & 3)) << 3) | (k & 7);
                const u32 w0 = (va.x & 0xffffu) | (vb.x << 16);
                const u32 w1 = (va.x >> 16)     | (vb.x & 0xffff0000u);
                const u32 w2 = (va.y & 0xffffu) | (vb.y << 16);
                const u32 w3 = (va.y >> 16)     | (vb.y & 0xffff0000u);
                const int rb = p4 * 4;
                *reinterpret_cast<u32*>(&sB[(rb    ) * KP + col]) = w0;
                *reinterpret_cast<u32*>(&sB[(rb + 1) * KP + col]) = w1;
                *reinterpret_cast<u32*>(&sB[(rb + 2) * KP + col]) = w2;
                *reinterpret_cast<u32*>(&sB[(rb + 3) * KP + col]) = w3;
            }
        }
        __syncthreads();

#pragma unroll
        for (int ks = 0; ks < 3; ++ks) {
            const int kof = ks * 32 + hk * 8;
            const u16* pA = &sA[r * KP + kof];
            const int rowb = wave * 32 + r;
            const int colr = (((kof >> 3) ^ ((rowb >> 2) & 3)) << 3);
            const u16* pB = &sB[rowb * KP + colr];
            const short8 a0 = *reinterpret_cast<const short8*>(pA);
            const short8 a1 = *reinterpret_cast<const short8*>(pA + 16 * KP);
            const short8 a2 = *reinterpret_cast<const short8*>(pA + 32 * KP);
            const short8 a3 = *reinterpret_cast<const short8*>(pA + 48 * KP);
            const short8 b0 = *reinterpret_cast<const short8*>(pB);
            const short8 b1 = *reinterpret_cast<const short8*>(pB + 16 * KP);
            acc[0][0] = __builtin_amdgcn_mfma_f32_16x16x32_bf16(a0, b0, acc[0][0], 0, 0, 0);
            acc[1][0] = __builtin_amdgcn_mfma_f32_16x16x32_bf16(a1, b0, acc[1][0], 0, 0, 0);
            acc[2][0] = __builtin_amdgcn_mfma_f32_16x16x32_bf16(a2, b0, acc[2][0], 0, 0, 0);
            acc[3][0] = __builtin_amdgcn_mfma_f32_16x16x32_bf16(a3, b0, acc[3][0], 0, 0, 0);
            acc[0][1] = __builtin_amdgcn_mfma_f32_16x16x32_bf16(a0, b1, acc[0][1], 0, 0, 0);
            acc[1][1] = __builtin_amdgcn_mfma_f32_16x16x32_bf16(a1, b1, acc[1][1], 0, 0, 0);
            acc[2][1] = __builtin_amdgcn_mfma_f32_16x16x32_bf16(a2, b1, acc[2][1], 0, 0, 0);
            acc[3][1] = __builtin_amdgcn_mfma_f32_16x16x32_bf16(a3, b1, acc[3][1], 0, 0, 0);
        }
        __syncthreads();
    }

#pragma unroll
    for (int mf = 0; mf < 4; ++mf) {
#pragma unroll
        for (int j = 0; j < 4; ++j) {
            const int co = co0 + mf * 16 + hk * 4 + j;
            const float bs = sBias[mf * 16 + hk * 4 + j];
            const size_t base = ((size_t)b * CDIM + co) * HWPIX + p0 + wave * 32 + r;
            Y[base]      = acc[mf][0][j] + bs;
            Y[base + 16] = acc[mf][1][j] + bs;
        }
    }
}

// ---------------------------------------------------------------------------
// Depthwise 3x3 SAME conv — vectorized (unchanged).
// ---------------------------------------------------------------------------
__global__ __launch_bounds__(256) void dwconv_kernel(
    const bf16* __restrict__ In, const float* __restrict__ Wd,
    const float* __restrict__ bd, bf16* __restrict__ Out)
{
    __shared__ alignas(16) u16 sIn[10 * 256];
    const int bc = blockIdx.y;            // b*576 + c
    const int c = bc % C3;
    const size_t base = (size_t)bc * HWPIX;
    const int r0 = blockIdx.x * 8;
    const int tid = threadIdx.x;

    for (int idx = tid; idx < 320; idx += 256) {
        const int lr = idx >> 5, ch = idx & 31;
        const int gr = r0 + lr - 1;
        uint4 v = {0u, 0u, 0u, 0u};
        if ((unsigned)gr < IMGW)
            v = *reinterpret_cast<const uint4*>(&In[base + (size_t)gr * IMGW + ch * 8]);
        *reinterpret_cast<uint4*>(&sIn[lr * 256 + ch * 8]) = v;
    }
    __syncthreads();

    float wg[9];
#pragma unroll
    for (int t = 0; t < 9; ++t) wg[t] = Wd[c * 9 + t];

    const int rr = tid >> 5;
    const int px0 = (tid & 31) * 8;
    const float bias = bd[c];
    float acc[8];
#pragma unroll
    for (int j = 0; j < 8; ++j) acc[j] = bias;

#pragma unroll
    for (int dy = 0; dy < 3; ++dy) {
        const int row = rr + dy;
        const u16* rp = &sIn[row * 256];
        const short8 mv = *reinterpret_cast<const short8*>(&rp[px0]);
        float m[8];
#pragma unroll
        for (int j = 0; j < 8; ++j) m[j] = bu2f((u16)mv[j]);
        const float lft = (px0 > 0) ? bu2f(rp[px0 - 1]) : 0.f;
        const float rgt = (px0 + 8 < 256) ? bu2f(rp[px0 + 8]) : 0.f;
        const float w0 = wg[dy * 3], w1 = wg[dy * 3 + 1], w2 = wg[dy * 3 + 2];

        acc[0] = fmaf(w0, lft, acc[0]);
        acc[0] = fmaf(w1, m[0], acc[0]);
        acc[0] = fmaf(w2, m[1], acc[0]);
#pragma unroll
        for (int j = 1; j < 7; ++j) {
            acc[j] = fmaf(w0, m[j - 1], acc[j]);
            acc[j] = fmaf(w1, m[j], acc[j]);
            acc[j] = fmaf(w2, m[j + 1], acc[j]);
        }
        acc[7] = fmaf(w0, m[6], acc[7]);
        acc[7] = fmaf(w1, m[7], acc[7]);
        acc[7] = fmaf(w2, rgt, acc[7]);
    }

    uint4 ov;
    ov.x = pack2(acc[0], acc[1]);
    ov.y = pack2(acc[2], acc[3]);
    ov.z = pack2(acc[4], acc[5]);
    ov.w = pack2(acc[6], acc[7]);
    *reinterpret_cast<uint4*>(&Out[base + (size_t)(r0 + rr) * IMGW + px0]) = ov;
}

// ---------------------------------------------------------------------------
// Local (windowed 8x8) channel attention + fused global apply.
// R7 fixes (latency-bound at 21% occupancy, 76.8KB LDS):
//  - Single 72-row LDS arena (Q,K,V 24 rows each; MFMA row-16..31 reads land
//    in the next tensor's defined data, outputs masked). sP overlays dead sQ
//    (barrier after Gram); out-tile overlays dead sK. 50.6KB -> 3 blocks/CU.
//  - osum written as bf16 via LDS transpose + coalesced uint4 stores (halves
//    write traffic; no extra rounding — proj staging rounded to bf16 anyway).
//  - norm loop rw-rotation by c to spread LDS bank aliasing.
// ---------------------------------------------------------------------------
#define CS 328          // c-row stride (u16)
#define PS 40           // row stride (u16) for sP
#define OS 36           // row stride (u16) for out-tile

__global__ __launch_bounds__(256, 3) void local_attn_kernel(
    const bf16* __restrict__ QKV, const float* __restrict__ temp,
    const float* __restrict__ Ag, u16* __restrict__ Osum)
{
    __shared__ alignas(16) u16 sMem[3 * 24 * CS];
    __shared__ float snq[4 * 32], snk[4 * 32];
    __shared__ float sAg[576];
    u16* const sQ = sMem;
    u16* const sK = sMem + 24 * CS;
    u16* const sV = sMem + 48 * CS;
    u16* const sP = sQ;     // overlay: sQ dead after Gram (barrier-protected)
    u16* const sO = sK;     // overlay: sK dead after Gram

    const int wy    = blockIdx.x >> 3;
    const int strip = blockIdx.x & 7;
    const int head  = blockIdx.y;
    const int b     = blockIdx.z;
    const int x0    = strip * 32;
    const int tid   = threadIdx.x;
    const int w     = tid >> 6;
    const int lane  = tid & 63;
    const int r     = lane & 15;
    const int hk    = lane >> 4;

    // stage global-branch attention matrix for this (b,head)
    {
        const float* Asrc = Ag + ((size_t)(b * NHEADS + head)) * 576;
        for (int idx = tid; idx < 576; idx += 256) sAg[idx] = Asrc[idx];
    }

#pragma unroll
    for (int i = 0; i < 9; ++i) {
        const int idx = tid + i * 256;
        const int tensor = idx / 768;
        const int rem = idx - tensor * 768;
        const int c  = rem >> 5;
        const int rw = (rem >> 2) & 7;
        const int ch = rem & 3;
        const size_t g = ((size_t)b * C3 + tensor * CDIM + head * CPH + c) * HWPIX
                       + (size_t)(wy * 8 + rw) * IMGW + x0 + ch * 8;
        const uint4 v = *reinterpret_cast<const uint4*>(&QKV[g]);
        u16* dst = sMem + tensor * (24 * CS);
        *reinterpret_cast<uint4*>(&dst[c * CS + rw * 40 + ch * 8]) = v;
    }
    __syncthreads();

    if (tid < 192) {
        const int qk = tid / 96;
        const int rem = tid - qk * 96;
        const int ww = rem / 24, c = rem % 24;
        const u16* sT = qk ? sK : sQ;
        const int off = c * CS + ww * 8;
        float s = 0.f;
#pragma unroll
        for (int rw = 0; rw < 8; ++rw) {
            const int rw2 = (rw + c) & 7;     // rotate start: spreads banks
            const short8 v = *reinterpret_cast<const short8*>(&sT[off + rw2 * 40]);
#pragma unroll
            for (int j = 0; j < 8; ++j) {
                const float f = bu2f((u16)v[j]);
                s = fmaf(f, f, s);
            }
        }
        const float inv = 1.f / fmaxf(sqrtf(s), 1e-12f);
        if (qk) snk[ww * 32 + c] = inv; else snq[ww * 32 + c] = inv;
    }
    __syncthreads();

    f32x4 accg[2][2];
#pragma unroll
    for (int i = 0; i < 2; ++i)
#pragma unroll
        for (int j = 0; j < 2; ++j) accg[i][j] = (f32x4){0.f, 0.f, 0.f, 0.f};

#pragma unroll
    for (int kk = 0; kk < 2; ++kk) {
        const int colA = (kk * 4 + hk) * 40 + w * 8;
        const short8 aq0 = *reinterpret_cast<const short8*>(&sQ[(r     ) * CS + colA]);
        const short8 aq1 = *reinterpret_cast<const short8*>(&sQ[(16 + r) * CS + colA]);
        const short8 bk0 = *reinterpret_cast<const short8*>(&sK[(r     ) * CS + colA]);
        const short8 bk1 = *reinterpret_cast<const short8*>(&sK[(16 + r) * CS + colA]);
        accg[0][0] = __builtin_amdgcn_mfma_f32_16x16x32_bf16(aq0, bk0, accg[0][0], 0, 0, 0);
        accg[0][1] = __builtin_amdgcn_mfma_f32_16x16x32_bf16(aq0, bk1, accg[0][1], 0, 0, 0);
        accg[1][0] = __builtin_amdgcn_mfma_f32_16x16x32_bf16(aq1, bk0, accg[1][0], 0, 0, 0);
        accg[1][1] = __builtin_amdgcn_mfma_f32_16x16x32_bf16(aq1, bk1, accg[1][1], 0, 0, 0);
    }
    __syncthreads();   // all Gram reads done before sP (=sQ) writes

    const float t = temp[head];
    const int e0 = lane & 15;
    const bool v1 = e0 < 8;
    const float ink0 = snk[w * 32 + e0];
    const float ink1 = snk[w * 32 + 16 + e0];

#pragma unroll
    for (int ct = 0; ct < 2; ++ct) {
#pragma unroll
        for (int j = 0; j < 4; ++j) {
            const int cidx = ct * 16 + hk * 4 + j;
            const float inq = snq[w * 32 + (cidx < CPH ? cidx : 0)];
            const float g0 = accg[ct][0][j] * inq * ink0 * t;
            const float g1 = v1 ? accg[ct][1][j] * inq * ink1 * t : -1e30f;
            float m = fmaxf(g0, g1);
#pragma unroll
            for (int mk = 8; mk >= 1; mk >>= 1) m = fmaxf(m, __shfl_xor(m, mk));
            const float p0 = __expf(g0 - m);
            const float p1 = v1 ? __expf(g1 - m) : 0.f;
            float s = p0 + p1;
#pragma unroll
            for (int mk = 8; mk >= 1; mk >>= 1) s += __shfl_xor(s, mk);
            const float inv = 1.f / s;
            if (cidx < CPH) {
                sP[w * 32 * PS + cidx * PS + e0] = f2bu(p0 * inv + sAg[cidx * CPH + e0]);
                if (v1) sP[w * 32 * PS + cidx * PS + 16 + e0]
                    = f2bu(p1 * inv + sAg[cidx * CPH + 16 + e0]);
            }
        }
    }
    __syncthreads();

    f32x4 acco[2][4];
#pragma unroll
    for (int i = 0; i < 2; ++i)
#pragma unroll
        for (int j = 0; j < 4; ++j) acco[i][j] = (f32x4){0.f, 0.f, 0.f, 0.f};

    short8 afr[2];
#pragma unroll
    for (int ct = 0; ct < 2; ++ct) {
        if (hk < 3)
            afr[ct] = *reinterpret_cast<const short8*>(
                &sP[w * 32 * PS + (ct * 16 + r) * PS + hk * 8]);
        else
            afr[ct] = (short8){0, 0, 0, 0, 0, 0, 0, 0};
    }
#pragma unroll
    for (int nt = 0; nt < 4; ++nt) {
        const int px = nt * 16 + r;
        const int colV = (px >> 3) * 40 + w * 8 + (px & 7);
        short8 bfr;
        if (hk < 3) {
#pragma unroll
            for (int j = 0; j < 8; ++j)
                bfr[j] = (short)sV[(hk * 8 + j) * CS + colV];
        } else {
            bfr = (short8){0, 0, 0, 0, 0, 0, 0, 0};
        }
        acco[0][nt] = __builtin_amdgcn_mfma_f32_16x16x32_bf16(afr[0], bfr, acco[0][nt], 0, 0, 0);
        acco[1][nt] = __builtin_amdgcn_mfma_f32_16x16x32_bf16(afr[1], bfr, acco[1][nt], 0, 0, 0);
    }

    // ---- epilogue: acc -> bf16 LDS tile [rpx*24+c][OS] -> coalesced stores
#pragma unroll
    for (int ct = 0; ct < 2; ++ct) {
#pragma unroll
        for (int j = 0; j < 4; ++j) {
            const int cidx = ct * 16 + hk * 4 + j;
            if (cidx >= CPH) continue;
#pragma unroll
            for (int nt = 0; nt < 4; ++nt) {
                const int px = nt * 16 + r;
                const int rpx = px >> 3, pxl = px & 7;
                sO[(rpx * 24 + cidx) * OS + w * 8 + pxl] = f2bu(acco[ct][nt][j]);
            }
        }
    }
    __syncthreads();

#pragma unroll
    for (int i = 0; i < 3; ++i) {
        const int idx = tid + i * 256;     // 0..767
        const int q4 = idx & 3;
        const int row = idx >> 2;          // rpx*24 + c
        const int c = row % 24, rw = row / 24;
        const u16* src = &sO[row * OS + q4 * 8];
        const uint2 lo = *reinterpret_cast<const uint2*>(src);
        const uint2 hi = *reinterpret_cast<const uint2*>(src + 4);
        uint4 v = {lo.x, lo.y, hi.x, hi.y};
        *reinterpret_cast<uint4*>(
            &Osum[((size_t)b * CDIM + head * CPH + c) * HWPIX
                  + (size_t)(wy * 8 + rw) * IMGW + x0 + q4 * 8]) = v;
    }
}

// ---------------------------------------------------------------------------
// Global branch stats — MFMA (unchanged).
// ---------------------------------------------------------------------------
#define GRS 520

__global__ __launch_bounds__(256) void gstats_kernel(
    const bf16* __restrict__ QKV, float* __restrict__ Gp)
{
    __shared__ alignas(16) u16 sq[32 * GRS];
    __shared__ alignas(16) u16 sk[32 * GRS];

    const int chunk = blockIdx.x;        // 0..15
    const int bh = blockIdx.y;           // 0..31
    const int b = bh >> 3, head = bh & 7;
    const int tid = threadIdx.x;
    const int w = tid >> 6, lane = tid & 63;
    const int r = lane & 15, hk = lane >> 4;

    const size_t qb = ((size_t)b * C3 + head * CPH) * HWPIX;
    const size_t kb = qb + (size_t)CDIM * HWPIX;

    for (int idx = tid; idx < 1040; idx += 256) {
        const int t = idx >= 520;
        const int o = idx - t * 520;
        u16* d = (t ? sk : sq) + 24 * GRS + o * 8;
        *reinterpret_cast<uint4*>(d) = (uint4){0u, 0u, 0u, 0u};
    }

    f32x4 acc[2][2];
#pragma unroll
    for (int i = 0; i < 2; ++i)
#pragma unroll
        for (int j = 0; j < 2; ++j) acc[i][j] = (f32x4){0.f, 0.f, 0.f, 0.f};
    float nacc = 0.f;
    const int nrow = tid >> 2;
    const int nq4  = tid & 3;

    for (int st = 0; st < 8; ++st) {
        const int d0 = chunk * 4096 + st * 512;
        __syncthreads();
#pragma unroll
        for (int i = 0; i < 12; ++i) {
            const int idx = tid + i * 256;
            const int t = idx >= 1536;
            const int rem = idx - t * 1536;
            const int c = rem >> 6, dv = rem & 63;
            const uint4 v = *reinterpret_cast<const uint4*>(
                &QKV[(t ? kb : qb) + (size_t)c * HWPIX + d0 + dv * 8]);
            u16* dst = (t ? sk : sq) + c * GRS + dv * 8;
            *reinterpret_cast<uint4*>(dst) = v;
        }
        __syncthreads();

#pragma unroll
        for (int ks = 0; ks < 4; ++ks) {
            const int kof = w * 128 + ks * 32 + hk * 8;
            const short8 aq0 = *reinterpret_cast<const short8*>(&sq[(r     ) * GRS + kof]);
            const short8 aq1 = *reinterpret_cast<const short8*>(&sq[(16 + r) * GRS + kof]);
            const short8 bk0 = *reinterpret_cast<const short8*>(&sk[(r     ) * GRS + kof]);
            const short8 bk1 = *reinterpret_cast<const short8*>(&sk[(16 + r) * GRS + kof]);
            acc[0][0] = __builtin_amdgcn_mfma_f32_16x16x32_bf16(aq0, bk0, acc[0][0], 0, 0, 0);
            acc[0][1] = __builtin_amdgcn_mfma_f32_16x16x32_bf16(aq0, bk1, acc[0][1], 0, 0, 0);
            acc[1][0] = __builtin_amdgcn_mfma_f32_16x16x32_bf16(aq1, bk0, acc[1][0], 0, 0, 0);
            acc[1][1] = __builtin_amdgcn_mfma_f32_16x16x32_bf16(aq1, bk1, acc[1][1], 0, 0, 0);
        }

        if (nrow < 48) {
            const u16* rp = (nrow < 24 ? &sq[nrow * GRS] : &sk[(nrow - 24) * GRS]) + nq4 * 128;
#pragma unroll
            for (int i = 0; i < 16; ++i) {
                const short8 v = *reinterpret_cast<const short8*>(&rp[i * 8]);
#pragma unroll
                for (int j = 0; j < 8; ++j) {
                    const float f = bu2f((u16)v[j]);
                    nacc = fmaf(f, f, nacc);
                }
            }
        }
    }
    __syncthreads();

    float* red = reinterpret_cast<float*>(sq);
#pragma unroll
    for (int ct = 0; ct < 2; ++ct) {
#pragma unroll
        for (int et = 0; et < 2; ++et) {
#pragma unroll
            for (int j = 0; j < 4; ++j) {
                const int c = ct * 16 + hk * 4 + j;
                const int e = et * 16 + r;
                if (c < CPH && e < CPH)
                    red[(w * 24 + c) * 25 + e] = acc[ct][et][j];
            }
        }
    }
    __syncthreads();

    float* dst = Gp + ((size_t)bh * 32 + chunk) * 624;
    for (int idx = tid; idx < 576; idx += 256) {
        const int c = idx / 24, e = idx % 24;
        const int o = c * 25 + e;
        dst[idx] = red[o] + red[600 + o] + red[1200 + o] + red[1800 + o];
    }

    float ns = nacc;
    ns += __shfl_xor(ns, 1);
    ns += __shfl_xor(ns, 2);
    if (nrow < 48 && nq4 == 0) {
        if (nrow < 24) dst[576 + nrow] = ns;
        else           dst[600 + (nrow - 24)] = ns;
    }
}

// ---------------------------------------------------------------------------
__global__ __launch_bounds__(64) void gsoftmax_kernel(
    const float* __restrict__ Gp, const float* __restrict__ temp,
    float* __restrict__ A)
{
    __shared__ float red[624];
    const int bh = blockIdx.x, head = bh & 7;
    const int tid = threadIdx.x;

    for (int jj = tid; jj < 624; jj += 64) {
        float s = 0.f;
        for (int ch = 0; ch < 16; ++ch) s += Gp[((size_t)bh * 32 + ch) * 624 + jj];
        red[jj] = s;
    }
    __syncthreads();

    if (tid < CPH) {
        const int c = tid;
        const float t = temp[head];
        const float inq = 1.f / fmaxf(sqrtf(red[576 + c]), 1e-12f);
        float l[CPH]; float m = -1e30f;
        for (int e = 0; e < CPH; ++e) {
            const float ink = 1.f / fmaxf(sqrtf(red[600 + e]), 1e-12f);
            l[e] = red[c * CPH + e] * inq * ink * t;
            m = fmaxf(m, l[e]);
        }
        float s = 0.f;
        for (int e = 0; e < CPH; ++e) { l[e] = expf(l[e] - m); s += l[e]; }
        const float inv = 1.f / s;
        for (int e = 0; e < CPH; ++e) A[(size_t)bh * 576 + c * CPH + e] = l[e] * inv;
    }
}

// ---------------------------------------------------------------------------
extern "C" void kernel_launch(void* const* d_in, const int* in_sizes, int n_in,
                              void* d_out, int out_size, void* d_ws, size_t ws_size,
                              hipStream_t stream) {
    const float* x           = (const float*)d_in[0];
    const float* temperature = (const float*)d_in[1];
    const float* qkv_w       = (const float*)d_in[2];
    const float* qkv_b       = (const float*)d_in[3];
    const float* dw_w        = (const float*)d_in[4];
    const float* dw_b        = (const float*)d_in[5];
    const float* proj_w      = (const float*)d_in[6];
    const float* proj_b      = (const float*)d_in[7];
    float* out = (float*)d_out;

    char* ws = (char*)d_ws;
    constexpr size_t QKV_ELEMS = (size_t)NBATCH * C3 * HWPIX;
    constexpr size_t QKV_BYTES = QKV_ELEMS * sizeof(bf16);

    bf16* qkv1 = (bf16*)ws;                       // conv1x1 out (bf16)
    bf16* qkv2 = (bf16*)(ws + QKV_BYTES);         // q,k,v after depthwise (bf16)
    u16*  osum = (u16*)ws;                        // o1+o2 bf16, overlays qkv1
    float* Gp   = (float*)(ws + 2 * QKV_BYTES);   // partials
    float* Amat = Gp + (size_t)32 * 32 * 624;
    u16*  Wb    = (u16*)Gp;                       // qkv weights bf16 (dead before gstats)
    u16*  Wpb   = (u16*)(Amat + 32 * 576);        // proj weights bf16
    u16*  Xt    = (u16*)qkv2;                     // Xt overlays qkv2 (dead after conv_qkv)

    // 0. weights f32 -> bf16
    prep_weights<<<(C3 * CDIM + 255) / 256, 256, 0, stream>>>(qkv_w, Wb, C3 * CDIM);
    prep_weights<<<(CDIM * CDIM + 255) / 256, 256, 0, stream>>>(proj_w, Wpb, CDIM * CDIM);

    // 0b. X transpose+convert -> Xt
    xprep_kernel<<<dim3(HWPIX / 64, NBATCH), 256, 0, stream>>>(x, Xt);

    // 1. qkv = 1x1 conv via MFMA
    conv_qkv_mfma<<<9 * 512 * NBATCH, 256, 0, stream>>>(Xt, Wb, qkv_b, qkv1);

    // 2. depthwise 3x3 (overwrites Xt region — Xt dead)
    dwconv_kernel<<<dim3(32, NBATCH * C3), 256, 0, stream>>>(
        qkv1, dw_w, dw_b, qkv2);

    // 3. global Gram/norm partials via MFMA (overwrites Wb — dead)
    gstats_kernel<<<dim3(16, 32), 256, 0, stream>>>(qkv2, Gp);

    // 4. reduce + softmax -> A
    gsoftmax_kernel<<<32, 64, 0, stream>>>(Gp, temperature, Amat);

    // 5. local attention + fused global apply -> osum (bf16) = o1 + o2
    local_attn_kernel<<<dim3(256, NHEADS, NBATCH), 256, 0, stream>>>(
        qkv2, temperature, Amat, osum);

    // 6. proj 1x1 conv via MFMA (bf16 osum in, f32 out)
    conv_proj_mfma<<<3 * 512 * NBATCH, 256, 0, stream>>>(osum, Wpb, proj_b, out);
}